// Round 11
// baseline (861.975 us; speedup 1.0000x reference)
//
#include <hip/hip_runtime.h>

// GLAT: B=64, N=256, D=1024, H=8, DK=64, DI=2048.
// I/O dtype: float32. Internal: bf16 MFMA + f32 accum. adj/slf: int32.

typedef unsigned short u16;
typedef unsigned long long u64;
typedef __bf16 bf16_t;
typedef bf16_t bf16x8 __attribute__((ext_vector_type(8)));
typedef float  f32x4  __attribute__((ext_vector_type(4)));
typedef u16    u16x8  __attribute__((ext_vector_type(8)));
typedef u16    u16x4  __attribute__((ext_vector_type(4)));

__device__ __forceinline__ float bf2f(u16 u){
  union { unsigned int i; float f; } c; c.i = ((unsigned int)u) << 16; return c.f;
}
__device__ __forceinline__ u16 f2bf(float f){
  union { float f; unsigned int u; } c; c.f = f;
  unsigned int u = c.u;
  unsigned int r = (u + 0x7fffu + ((u >> 16) & 1u)) >> 16;  // RNE
  return (u16)r;
}

// async 16B global -> LDS (direct). LDS dest = wave-uniform base + lane*16.
__device__ __forceinline__ void gl16(const u16* g, u16* l){
  __builtin_amdgcn_global_load_lds(
      (const __attribute__((address_space(1))) void*)g,
      (__attribute__((address_space(3))) void*)l, 16, 0, 0);
}

// ---------------- diagnostic fallback: zero d_out (f32) ----------------------
__global__ __launch_bounds__(256) void zero_out(float* out, int n){
  for (int i = blockIdx.x * 256 + threadIdx.x; i < n; i += 256 * 4096) out[i] = 0.f;
}

// ---------------- f32 -> bf16 bulk convert (8 elems/thread) ------------------
__global__ __launch_bounds__(256) void cvt_bf16(
    const float* __restrict__ in, u16* __restrict__ out)
{
  const size_t i = ((size_t)blockIdx.x * 256 + threadIdx.x) * 8;
  f32x4 a = *(const f32x4*)&in[i];
  f32x4 b = *(const f32x4*)&in[i + 4];
  u16x8 o;
  #pragma unroll
  for (int j = 0; j < 4; ++j){ o[j] = f2bf(a[j]); o[4+j] = f2bf(b[j]); }
  *(u16x8*)&out[i] = o;
}

// -------- weight transpose+convert: src f32 [K][N] -> dst bf16 [(off+n)*K+k] --
__global__ __launch_bounds__(256) void transpose_w(
    const float* __restrict__ src, u16* __restrict__ dst, int K, int N, int dstOff)
{
  __shared__ u16 tile[32][33];
  const int bk = blockIdx.x * 32, bn = blockIdx.y * 32;
  const int t = threadIdx.x;
  const int r = t >> 5, c = t & 31;
  #pragma unroll
  for (int p = 0; p < 4; ++p)
    tile[r + p*8][c] = f2bf(src[(size_t)(bk + r + p*8) * N + bn + c]);
  __syncthreads();
  #pragma unroll
  for (int p = 0; p < 4; ++p)
    dst[(size_t)(dstOff + bn + r + p*8) * K + bk + c] = tile[c][r + p*8];
}

// -------- 3-source variant (QKV weights, same shape) via blockIdx.z ----------
__global__ __launch_bounds__(256) void transpose_w3(
    const float* __restrict__ sA, const float* __restrict__ sB,
    const float* __restrict__ sC, u16* __restrict__ dst, int K, int N)
{
  __shared__ u16 tile[32][33];
  const float* src = blockIdx.z == 0 ? sA : (blockIdx.z == 1 ? sB : sC);
  const int dstOff = blockIdx.z * N;
  const int bk = blockIdx.x * 32, bn = blockIdx.y * 32;
  const int t = threadIdx.x;
  const int r = t >> 5, c = t & 31;
  #pragma unroll
  for (int p = 0; p < 4; ++p)
    tile[r + p*8][c] = f2bf(src[(size_t)(bk + r + p*8) * N + bn + c]);
  __syncthreads();
  #pragma unroll
  for (int p = 0; p < 4; ++p)
    dst[(size_t)(dstOff + bn + r + p*8) * K + bk + c] = tile[c][r + p*8];
}

// ---- GEMM 256x256, BK=64, 8 waves, dbuf LDS, tile-top staged, vmcnt(8) -----
// C = A[M,K] @ BT[N,:]^T. A split at ksplit between A0/A1 (row stride Astride).
// BT row stride = Bld. ACC: out += result (pass bias=null).
// LDS per buf: A[256][64] @0, B[256][64] @16384 elems; slot sl of row r holds
// global chunk sl^(r&7) (zero-conflict frag reads, verified r8/r10); gl16 linear.
// All 4 half-tile stages issued at tile-top -> vmcnt(8) gives each load a full
// K-tile of latency cover. B frags stay resident (24 ds_reads/wave/tile).
// XCD-aware tile swizzle (T1): contiguous tile chunk per XCD for B-panel L2 reuse.
template<int RELU, int OF32, int ACC>
__global__ __launch_bounds__(512, 2) void gemm256(
    const u16* __restrict__ A0, const u16* __restrict__ A1,
    int Astride, int ksplit,
    const u16* __restrict__ BT, int Bld, int M, int N, int K,
    const float* __restrict__ bias, void* __restrict__ outv, int out_ld)
{
  __shared__ u16 lds[2*32768];           // 128 KiB
  const int tid  = threadIdx.x;
  const int lane = tid & 63;
  const int wid  = tid >> 6;             // 0..7
  const int wm = wid >> 2, wn = wid & 3; // 2M x 4N waves
  const int l15 = lane & 15, l4 = lane >> 4;

  // XCD-aware bijective tile swizzle (requires nwg % 8 == 0)
  const int gx = gridDim.x;
  int lin = blockIdx.y * gx + blockIdx.x;
  const int nwg = gx * gridDim.y;
  if ((nwg & 7) == 0)
    lin = (lin & 7) * (nwg >> 3) + (lin >> 3);
  const int m0 = (lin % gx) * 256, n0 = (lin / gx) * 256;

  f32x4 acc[8][4];
  #pragma unroll
  for (int i = 0; i < 8; ++i)
    #pragma unroll
    for (int j = 0; j < 4; ++j)
      acc[i][j] = (f32x4){0.f, 0.f, 0.f, 0.f};

  // staging: half-tile = 128 rows x 8 slots = 1024 slots; thread -> s0, s1
  const int s0 = tid, s1 = tid + 512;
  const int r0 = s0 >> 3, g0 = (s0 & 7) ^ (r0 & 7);
  const int r1 = s1 >> 3, g1 = (s1 & 7) ^ (r1 & 7);

  const int nt = K >> 6;

  auto stageA = [&](int kt, int h, int buf){
    const int kb = kt * 64;
    const u16* Ab = A0; int kl = kb;
    if (kb >= ksplit){ Ab = A1; kl = kb - ksplit; }
    u16* dst = &lds[buf*32768 + h*8192];
    gl16(&Ab[(size_t)(m0 + h*128 + r0) * Astride + kl + g0*8], &dst[s0*8]);
    gl16(&Ab[(size_t)(m0 + h*128 + r1) * Astride + kl + g1*8], &dst[s1*8]);
  };
  auto stageB = [&](int kt, int h, int buf){
    const int kb = kt * 64;
    u16* dst = &lds[buf*32768 + 16384 + h*8192];
    gl16(&BT[(size_t)(n0 + h*128 + r0) * Bld + kb + g0*8], &dst[s0*8]);
    gl16(&BT[(size_t)(n0 + h*128 + r1) * Bld + kb + g1*8], &dst[s1*8]);
  };
  auto lda = [&](int i, int kc, int buf) -> bf16x8 {
    const int r = wm*128 + i*16 + l15;
    const int c = (kc*4 + l4) ^ (r & 7);
    return *(const bf16x8*)&lds[buf*32768 + r*64 + c*8];
  };
  auto ldb = [&](int j, int kc, int buf) -> bf16x8 {
    const int r = wn*64 + j*16 + l15;
    const int c = (kc*4 + l4) ^ (r & 7);
    return *(const bf16x8*)&lds[buf*32768 + 16384 + r*64 + c*8];
  };

  // prologue: stage tile 0 fully (8 loads)
  stageA(0, 0, 0); stageA(0, 1, 0); stageB(0, 0, 0); stageB(0, 1, 0);

  for (int t = 0; t < nt; ++t){
    const int buf = t & 1, nbuf = buf ^ 1;
    if (t + 1 < nt){
      stageA(t+1, 0, nbuf); stageA(t+1, 1, nbuf);
      stageB(t+1, 0, nbuf); stageB(t+1, 1, nbuf);
      asm volatile("s_waitcnt vmcnt(8)" ::: "memory");  // tile t's 8 landed
    } else {
      asm volatile("s_waitcnt vmcnt(0)" ::: "memory");
    }
    __builtin_amdgcn_sched_barrier(0);
    __builtin_amdgcn_s_barrier();          // all waves' tile-t loads landed
    __builtin_amdgcn_sched_barrier(0);

    bf16x8 a_[4][2], b_[4][2];
    #pragma unroll
    for (int j = 0; j < 4; ++j){ b_[j][0] = ldb(j, 0, buf); b_[j][1] = ldb(j, 1, buf); }
    #pragma unroll
    for (int i = 0; i < 4; ++i){ a_[i][0] = lda(i, 0, buf); a_[i][1] = lda(i, 1, buf); }
    __builtin_amdgcn_s_setprio(1);
    #pragma unroll
    for (int i = 0; i < 4; ++i)
      #pragma unroll
      for (int j = 0; j < 4; ++j){
        acc[i][j] = __builtin_amdgcn_mfma_f32_16x16x32_bf16(a_[i][0], b_[j][0], acc[i][j], 0,0,0);
        acc[i][j] = __builtin_amdgcn_mfma_f32_16x16x32_bf16(a_[i][1], b_[j][1], acc[i][j], 0,0,0);
      }
    __builtin_amdgcn_s_setprio(0);
    #pragma unroll
    for (int i = 0; i < 4; ++i){ a_[i][0] = lda(4+i, 0, buf); a_[i][1] = lda(4+i, 1, buf); }
    __builtin_amdgcn_s_setprio(1);
    #pragma unroll
    for (int i = 0; i < 4; ++i)
      #pragma unroll
      for (int j = 0; j < 4; ++j){
        acc[4+i][j] = __builtin_amdgcn_mfma_f32_16x16x32_bf16(a_[i][0], b_[j][0], acc[4+i][j], 0,0,0);
        acc[4+i][j] = __builtin_amdgcn_mfma_f32_16x16x32_bf16(a_[i][1], b_[j][1], acc[4+i][j], 0,0,0);
      }
    __builtin_amdgcn_s_setprio(0);

    __builtin_amdgcn_sched_barrier(0);
    __builtin_amdgcn_s_barrier();          // all reads of buf done
    __builtin_amdgcn_sched_barrier(0);
  }

  // epilogue: C[row][col], row=(lane>>4)*4+r, col=lane&15 (m89-verified)
  const int rb = m0 + wm*128 + l4*4;
  const int cb = n0 + wn*64 + l15;
  #pragma unroll
  for (int i = 0; i < 8; ++i){
    #pragma unroll
    for (int j = 0; j < 4; ++j){
      const int col = cb + j*16;
      const float badd = bias ? bias[col] : 0.f;
      #pragma unroll
      for (int r = 0; r < 4; ++r){
        const int row = rb + i*16 + r;
        float y = acc[i][j][r] + badd;
        if (RELU) y = y > 0.f ? y : 0.f;
        if (OF32){
          float* po = &((float*)outv)[(size_t)row * out_ld + col];
          if (ACC) y += *po;
          *po = y;
        } else {
          u16* po = &((u16*)outv)[(size_t)row * out_ld + col];
          if (ACC) y += bf2f(*po);
          *po = f2bf(y);
        }
      }
    }
  }
}

// -------- mask pack: bit k of mb[row][c] = mask(row, c*64+k) -----------------
__global__ __launch_bounds__(256) void mask_pack(
    const int* __restrict__ slf, const int* __restrict__ adj,
    u64* __restrict__ mb_g, u64* __restrict__ mb_l)
{
  const int idx  = blockIdx.x * 4 + (threadIdx.x >> 6);  // (row, c) pair
  const int lane = threadIdx.x & 63;
  const size_t mi = (size_t)(idx >> 2) * 256 + (size_t)(idx & 3) * 64 + lane;
  const bool g = slf[mi] != 0;
  const bool l = g || (adj[mi] == 0);
  const u64 bg = __ballot(g);
  const u64 bl = __ballot(l);
  if (lane == 0){ mb_g[idx] = bg; mb_l[idx] = bl; }
}

// ---------------- MFMA flash attention ---------------------------------------
// block = (b_loc, h, qtile of 128 rows); 4 waves x 32 q-rows.
// qkv: half-local [8192][1536]; q @ h*64, k @ 512+h*64, v @ 1024+h*64.
__global__ __launch_bounds__(256) void attn_mfma(
    const u16* __restrict__ qkv, const u64* __restrict__ mb,
    int boff, u16* __restrict__ out)
{
  __shared__ u16 kbuf[64*64];     // [key][dim], swizzled col ^= (key&7)<<3
  __shared__ u16 vtbuf[64*64];    // [dim][key], swizzled col ^= (dim&7)<<3
  __shared__ u16 pbuf[4][32*64];  // per-wave P [row][key], swizzled

  const int b_loc = blockIdx.x >> 4;
  const int h     = (blockIdx.x >> 1) & 7;
  const int qt    = blockIdx.x & 1;
  const int b     = boff + b_loc;
  const int t     = threadIdx.x;
  const int w     = t >> 6, lane = t & 63;
  const int l15   = lane & 15, l4 = lane >> 4;

  bf16x8 qf[2][2];
  {
    const int rbase = b_loc*256 + qt*128 + w*32;
    #pragma unroll
    for (int i = 0; i < 2; ++i)
      #pragma unroll
      for (int kc = 0; kc < 2; ++kc)
        qf[i][kc] = *(const bf16x8*)&qkv[(size_t)(rbase + i*16 + l15)*1536 + h*64 + kc*32 + l4*8];
  }

  f32x4 acc_o[2][4];
  float m_[2][4], l_[2][4];
  #pragma unroll
  for (int i = 0; i < 2; ++i){
    #pragma unroll
    for (int j = 0; j < 4; ++j) acc_o[i][j] = (f32x4){0.f,0.f,0.f,0.f};
    #pragma unroll
    for (int r = 0; r < 4; ++r){ m_[i][r] = -1e30f; l_[i][r] = 0.f; }
  }

  for (int c = 0; c < 4; ++c){
    __syncthreads();
    {   // stage K and V^T (swizzled); thread -> key row t>>2, dim group (t&3)*16
      const int kr = t >> 2, dg = (t & 3) * 16;
      const size_t rbase = (size_t)(b_loc*256 + c*64 + kr)*1536 + h*64 + dg;
      u16x8 k0 = *(const u16x8*)&qkv[rbase + 512];
      u16x8 k1 = *(const u16x8*)&qkv[rbase + 512 + 8];
      u16x8 v0 = *(const u16x8*)&qkv[rbase + 1024];
      u16x8 v1 = *(const u16x8*)&qkv[rbase + 1024 + 8];
      const int sw = (kr & 7) << 3;
      *(u16x8*)&kbuf[kr*64 + (dg ^ sw)]       = k0;
      *(u16x8*)&kbuf[kr*64 + ((dg + 8) ^ sw)] = k1;
      #pragma unroll
      for (int e = 0; e < 8; ++e){
        const int d0 = dg + e, d1 = dg + 8 + e;
        vtbuf[d0*64 + (kr ^ ((d0 & 7) << 3))] = v0[e];
        vtbuf[d1*64 + (kr ^ ((d1 & 7) << 3))] = v1[e];
      }
    }
    __syncthreads();

    bf16x8 kfr[4][2];
    #pragma unroll
    for (int jb = 0; jb < 4; ++jb){
      const int key = jb*16 + l15;
      const int sw = (key & 7) << 3;
      #pragma unroll
      for (int kc = 0; kc < 2; ++kc)
        kfr[jb][kc] = *(const bf16x8*)&kbuf[key*64 + ((kc*32 + l4*8) ^ sw)];
    }
    f32x4 s_[2][4];
    #pragma unroll
    for (int i = 0; i < 2; ++i)
      #pragma unroll
      for (int jb = 0; jb < 4; ++jb){
        f32x4 a = (f32x4){0.f,0.f,0.f,0.f};
        a = __builtin_amdgcn_mfma_f32_16x16x32_bf16(qf[i][0], kfr[jb][0], a, 0,0,0);
        a = __builtin_amdgcn_mfma_f32_16x16x32_bf16(qf[i][1], kfr[jb][1], a, 0,0,0);
        s_[i][jb] = a;
      }

    #pragma unroll
    for (int i = 0; i < 2; ++i){
      #pragma unroll
      for (int r = 0; r < 4; ++r){
        const int prow = i*16 + l4*4 + r;
        const int qrow = qt*128 + w*32 + prow;
        const u64 bits = mb[((size_t)b*256 + qrow)*4 + c];
        float sv[4];
        #pragma unroll
        for (int jb = 0; jb < 4; ++jb){
          float xv = s_[i][jb][r] * 0.125f;
          if ((bits >> (jb*16 + l15)) & 1ull) xv = -1e9f;
          sv[jb] = xv;
        }
        float mx = fmaxf(fmaxf(sv[0], sv[1]), fmaxf(sv[2], sv[3]));
        #pragma unroll
        for (int d = 1; d < 16; d <<= 1)
          mx = fmaxf(mx, __shfl_xor(mx, d, 64));
        const float mnew = fmaxf(m_[i][r], mx);
        const float corr = __expf(m_[i][r] - mnew);
        m_[i][r] = mnew;
        float ps = 0.f;
        const int swp = (prow & 7) << 3;
        #pragma unroll
        for (int jb = 0; jb < 4; ++jb){
          const float p = __expf(sv[jb] - mnew);
          ps += p;
          pbuf[w][prow*64 + ((jb*16 + l15) ^ swp)] = f2bf(p);
        }
        #pragma unroll
        for (int d = 1; d < 16; d <<= 1)
          ps += __shfl_xor(ps, d, 64);
        l_[i][r] = l_[i][r] * corr + ps;
        #pragma unroll
        for (int j2 = 0; j2 < 4; ++j2) acc_o[i][j2][r] *= corr;
      }
    }

    bf16x8 vfr[4][2];
    #pragma unroll
    for (int j2 = 0; j2 < 4; ++j2){
      const int dim = j2*16 + l15;
      const int sw = (dim & 7) << 3;
      #pragma unroll
      for (int kc = 0; kc < 2; ++kc)
        vfr[j2][kc] = *(const bf16x8*)&vtbuf[dim*64 + ((kc*32 + l4*8) ^ sw)];
    }
    #pragma unroll
    for (int i = 0; i < 2; ++i){
      const int prow = i*16 + l15;
      const int swp = (prow & 7) << 3;
      bf16x8 pa0 = *(const bf16x8*)&pbuf[w][prow*64 + ((l4*8) ^ swp)];
      bf16x8 pa1 = *(const bf16x8*)&pbuf[w][prow*64 + ((32 + l4*8) ^ swp)];
      #pragma unroll
      for (int j2 = 0; j2 < 4; ++j2){
        acc_o[i][j2] = __builtin_amdgcn_mfma_f32_16x16x32_bf16(pa0, vfr[j2][0], acc_o[i][j2], 0,0,0);
        acc_o[i][j2] = __builtin_amdgcn_mfma_f32_16x16x32_bf16(pa1, vfr[j2][1], acc_o[i][j2], 0,0,0);
      }
    }
  }

  #pragma unroll
  for (int i = 0; i < 2; ++i){
    #pragma unroll
    for (int r = 0; r < 4; ++r){
      const int qrow = qt*128 + w*32 + i*16 + l4*4 + r;
      const float inv = 1.f / l_[i][r];
      const size_t ob = ((size_t)b*256 + qrow)*512 + h*64;
      #pragma unroll
      for (int j2 = 0; j2 < 4; ++j2)
        out[ob + j2*16 + l15] = f2bf(acc_o[i][j2][r] * inv);
    }
  }
}

// -------- fused residual + LayerNorm + npm; a bf16, res f32|bf16, out bf16 ---
template<int RF32>
__global__ __launch_bounds__(256) void ln_fused(
    const u16* a, const void* __restrict__ res,
    const float* __restrict__ sc, const float* __restrict__ bs,
    const float* __restrict__ npm, u16* out)
{
  const int row = blockIdx.x, t = threadIdx.x;
  const size_t bse = (size_t)row * 1024 + t*4;
  u16x4 av = *(const u16x4*)&a[bse];
  float rv[4];
  if (RF32){
    f32x4 q = *(const f32x4*)&((const float*)res)[bse];
    #pragma unroll
    for (int j = 0; j < 4; ++j) rv[j] = q[j];
  } else {
    u16x4 q = *(const u16x4*)&((const u16*)res)[bse];
    #pragma unroll
    for (int j = 0; j < 4; ++j) rv[j] = bf2f(q[j]);
  }
  float vv[4]; float s = 0.f, sq = 0.f;
  #pragma unroll
  for (int j = 0; j < 4; ++j){
    vv[j] = bf2f(av[j]) + rv[j];
    s += vv[j]; sq += vv[j]*vv[j];
  }
  #pragma unroll
  for (int i = 1; i < 64; i <<= 1){
    s  += __shfl_xor(s,  i, 64);
    sq += __shfl_xor(sq, i, 64);
  }
  __shared__ float red[8];
  const int wid = t >> 6, lane = t & 63;
  if (lane == 0){ red[wid] = s; red[4 + wid] = sq; }
  __syncthreads();
  s  = red[0] + red[1] + red[2] + red[3];
  sq = red[4] + red[5] + red[6] + red[7];
  const float mean = s * (1.f/1024.f);
  const float var  = sq * (1.f/1024.f) - mean*mean;
  const float rstd = rsqrtf(var + 1e-5f);
  const float nm   = npm[row];
  u16x4 ov;
  #pragma unroll
  for (int j = 0; j < 4; ++j){
    float y = (vv[j] - mean) * rstd * sc[t*4+j] + bs[t*4+j];
    ov[j] = f2bf(y * nm);
  }
  *(u16x4*)&out[bse] = ov;
}

// ---------------- launcher ---------------------------------------------------
extern "C" void kernel_launch(void* const* d_in, const int* in_sizes, int n_in,
                              void* d_out, int out_size, void* d_ws, size_t ws_size,
                              hipStream_t stream)
{
  // ws (u16 el), 112 MiB (proven):
  //  W  [0, 8388608): wqkvT|woT|w1T|w2T|fcT
  //  R1 [8388608, 25165824):  xbf (phase1) -> tmp -> xl (phase2, in-place LN)
  //  R2 [25165824, 41943040): qkvh [8192][1536] (phase1) -> ln1 (phase2)
  //  R3 [41943040, 58720256): xg  (written once, layer-0 end; nothing aliases)
  // d_out (u16): attnb0 [0,8388608) | attnb1 [8388608,16777216)
  //   phase1: mb_g/mb_l @ 16777216 | phase2: hbufA [16777216,33554432)
  const size_t NEED = 58720256ull * 2ull;
  if (ws_size < NEED){
    zero_out<<<4096, 256, 0, stream>>>((float*)d_out, out_size);
    return;
  }

  const float* x   = (const float*)d_in[0];
  const int*   adj = (const int*)d_in[1];
  const float* npm = (const float*)d_in[2];
  const int*   slf = (const int*)d_in[3];
  const float* fcw = (const float*)d_in[30];
  const float* fcb = (const float*)d_in[31];

  u16* ws    = (u16*)d_ws;
  u16* wqkvT = ws;
  u16* woT   = ws + 1572864;
  u16* w1T   = ws + 2097152;
  u16* w2T   = ws + 4194304;
  u16* fcT   = ws + 6291456;
  u16* xbf   = ws + 8388608;           // R1: [16384][1024] bf16, then tmp/xl
  u16* tmp   = ws + 8388608;
  u16* qkvh  = ws + 25165824;          // R2: [8192][1536], then ln1
  u16* ln1   = ws + 25165824;
  u16* xg    = ws + 41943040;          // R3 (exclusive)

  u16* dout16 = (u16*)d_out;
  u16* attnb0 = dout16;                // [16384][512]
  u16* attnb1 = dout16 + 8388608;      // [16384][512]
  u16* hbufA  = dout16 + 16777216;     // [16384][1024] (phase2 only)
  u64* mb_g   = (u64*)(dout16 + 16777216);   // phase1 only (hbufA window)
  u64* mb_l   = mb_g + 65536;

  cvt_bf16<<<8192, 256, 0, stream>>>(x, xbf);
  mask_pack<<<16384, 256, 0, stream>>>(slf, adj, mb_g, mb_l);
  transpose_w<<<dim3(64, 32), 256, 0, stream>>>(fcw, fcT, 2048, 1024, 0);

  // Phase 1: both layers' QKV + attention (xbf + masks live throughout)
  for (int L = 0; L < 2; ++L){
    const int bi = 4 + L*13;
    transpose_w3<<<dim3(32, 16, 3), 256, 0, stream>>>(
        (const float*)d_in[bi+0], (const float*)d_in[bi+1],
        (const float*)d_in[bi+2], wqkvT, 1024, 512);
    u16* attnb = L ? attnb1 : attnb0;
    for (int hf = 0; hf < 2; ++hf){
      const u16* xh = xbf + (size_t)hf*8192*1024;
      gemm256<0,0,0><<<dim3(32, 6), 512, 0, stream>>>(
          xh, xh, 1024, 1024, wqkvT, 1024, 8192, 1536, 1024, nullptr, qkvh, 1536);
      attn_mfma<<<512, 256, 0, stream>>>(qkvh, L ? mb_l : mb_g, hf*32, attnb);
    }
  }

  // Phase 2: layer bodies (xbf/masks dead; tmp R1, ln1 R2, hbufA in d_out)
  for (int L = 0; L < 2; ++L){
    const int bi = 4 + L*13;
    const float* bo  = (const float*)d_in[bi+4];
    const float* l1s = (const float*)d_in[bi+5];
    const float* l1b = (const float*)d_in[bi+6];
    const float* b1  = (const float*)d_in[bi+8];
    const float* b2  = (const float*)d_in[bi+10];
    const float* l2s = (const float*)d_in[bi+11];
    const float* l2b = (const float*)d_in[bi+12];

    transpose_w<<<dim3(16, 32), 256, 0, stream>>>((const float*)d_in[bi+3], woT, 512, 1024, 0);
    transpose_w<<<dim3(32, 64), 256, 0, stream>>>((const float*)d_in[bi+7], w1T, 1024, 2048, 0);
    transpose_w<<<dim3(64, 32), 256, 0, stream>>>((const float*)d_in[bi+9], w2T, 2048, 1024, 0);

    const u16* attnb = L ? attnb1 : attnb0;
    // out-proj + bo -> tmp
    gemm256<0,0,0><<<dim3(64, 4), 512, 0, stream>>>(
        attnb, attnb, 512, 512, woT, 512, 16384, 1024, 512, bo, tmp, 1024);
    // ln1 = LN(tmp + x) * npm -> R2
    ln_fused<1><<<16384, 256, 0, stream>>>(tmp, x, l1s, l1b, npm, ln1);
    // FFN: two N-halves of w1 through hbufA, K-accumulated into tmp
    for (int hh = 0; hh < 2; ++hh){
      gemm256<1,0,0><<<dim3(64, 4), 512, 0, stream>>>(
          ln1, ln1, 1024, 1024, w1T + (size_t)hh*1024*1024, 1024,
          16384, 1024, 1024, b1 + hh*1024, hbufA, 1024);
      if (hh == 0)
        gemm256<0,0,0><<<dim3(64, 4), 512, 0, stream>>>(
            hbufA, hbufA, 1024, 1024, w2T, 2048, 16384, 1024, 1024, b2, tmp, 1024);
      else
        gemm256<0,0,1><<<dim3(64, 4), 512, 0, stream>>>(
            hbufA, hbufA, 1024, 1024, w2T + 1024, 2048, 16384, 1024, 1024,
            nullptr, tmp, 1024);
    }
    // xout = LN(tmp + ln1) * npm; layer0 -> xg, layer1 -> in-place (xl = tmp)
    ln_fused<0><<<16384, 256, 0, stream>>>(tmp, ln1, l2s, l2b, npm, L ? tmp : xg);
  }

  // final: [xg | xl] @ fcT + fc_b -> d_out (f32), K split at 1024
  gemm256<0,1,0><<<dim3(64, 4), 512, 0, stream>>>(
      xg, tmp, 1024, 1024, fcT, 2048, 16384, 1024, 2048, fcb, d_out, 1024);
}

// Round 12
// 843.533 us; speedup vs baseline: 1.0219x; 1.0219x over previous
//
#include <hip/hip_runtime.h>

// GLAT: B=64, N=256, D=1024, H=8, DK=64, DI=2048.
// I/O dtype: float32. Internal: bf16 MFMA + f32 accum. adj/slf: int32.

typedef unsigned short u16;
typedef unsigned long long u64;
typedef __bf16 bf16_t;
typedef bf16_t bf16x8 __attribute__((ext_vector_type(8)));
typedef float  f32x4  __attribute__((ext_vector_type(4)));
typedef u16    u16x8  __attribute__((ext_vector_type(8)));
typedef u16    u16x4  __attribute__((ext_vector_type(4)));

__device__ __forceinline__ float bf2f(u16 u){
  union { unsigned int i; float f; } c; c.i = ((unsigned int)u) << 16; return c.f;
}
__device__ __forceinline__ u16 f2bf(float f){
  union { float f; unsigned int u; } c; c.f = f;
  unsigned int u = c.u;
  unsigned int r = (u + 0x7fffu + ((u >> 16) & 1u)) >> 16;  // RNE
  return (u16)r;
}

// async 16B global -> LDS (direct). LDS dest = wave-uniform base + lane*16.
__device__ __forceinline__ void gl16(const u16* g, u16* l){
  __builtin_amdgcn_global_load_lds(
      (const __attribute__((address_space(1))) void*)g,
      (__attribute__((address_space(3))) void*)l, 16, 0, 0);
}

// ---------------- diagnostic fallback: zero d_out (f32) ----------------------
__global__ __launch_bounds__(256) void zero_out(float* out, int n){
  for (int i = blockIdx.x * 256 + threadIdx.x; i < n; i += 256 * 4096) out[i] = 0.f;
}

// ---------------- f32 -> bf16 bulk convert (8 elems/thread) ------------------
__global__ __launch_bounds__(256) void cvt_bf16(
    const float* __restrict__ in, u16* __restrict__ out)
{
  const size_t i = ((size_t)blockIdx.x * 256 + threadIdx.x) * 8;
  f32x4 a = *(const f32x4*)&in[i];
  f32x4 b = *(const f32x4*)&in[i + 4];
  u16x8 o;
  #pragma unroll
  for (int j = 0; j < 4; ++j){ o[j] = f2bf(a[j]); o[4+j] = f2bf(b[j]); }
  *(u16x8*)&out[i] = o;
}

// -------- weight transpose+convert: src f32 [K][N] -> dst bf16 [(off+n)*K+k] --
__global__ __launch_bounds__(256) void transpose_w(
    const float* __restrict__ src, u16* __restrict__ dst, int K, int N, int dstOff)
{
  __shared__ u16 tile[32][33];
  const int bk = blockIdx.x * 32, bn = blockIdx.y * 32;
  const int t = threadIdx.x;
  const int r = t >> 5, c = t & 31;
  #pragma unroll
  for (int p = 0; p < 4; ++p)
    tile[r + p*8][c] = f2bf(src[(size_t)(bk + r + p*8) * N + bn + c]);
  __syncthreads();
  #pragma unroll
  for (int p = 0; p < 4; ++p)
    dst[(size_t)(dstOff + bn + r + p*8) * K + bk + c] = tile[c][r + p*8];
}

// -------- 3-source variant (QKV weights, same shape) via blockIdx.z ----------
__global__ __launch_bounds__(256) void transpose_w3(
    const float* __restrict__ sA, const float* __restrict__ sB,
    const float* __restrict__ sC, u16* __restrict__ dst, int K, int N)
{
  __shared__ u16 tile[32][33];
  const float* src = blockIdx.z == 0 ? sA : (blockIdx.z == 1 ? sB : sC);
  const int dstOff = blockIdx.z * N;
  const int bk = blockIdx.x * 32, bn = blockIdx.y * 32;
  const int t = threadIdx.x;
  const int r = t >> 5, c = t & 31;
  #pragma unroll
  for (int p = 0; p < 4; ++p)
    tile[r + p*8][c] = f2bf(src[(size_t)(bk + r + p*8) * N + bn + c]);
  __syncthreads();
  #pragma unroll
  for (int p = 0; p < 4; ++p)
    dst[(size_t)(dstOff + bn + r + p*8) * K + bk + c] = tile[c][r + p*8];
}

// ---- GEMM 256x256, BK=64, 8 waves, dbuf LDS, tile-top staged, vmcnt(8) -----
// C = A[M,K] @ BT[N,:]^T. A split at ksplit between A0/A1 (row stride Astride).
// BT row stride = Bld. ACC: out += result (pass bias=null).
// LDS per buf: A[256][64] @0, B[256][64] @16384 elems; slot sl of row r holds
// global chunk sl^(r&7) (zero-conflict frag reads, verified r8/r10); gl16 linear.
// All 4 half-tile stages issued at tile-top -> vmcnt(8) gives each load a full
// K-tile of latency cover. B frags stay resident (24 ds_reads/wave/tile).
// NO XCD swizzle: default round-robin already puts same-m tiles on one XCD
// (gridDim.x % 8 == 0) -> A-panel L2 reuse; r11's swizzle broke it (FETCH 2.7x).
template<int RELU, int OF32, int ACC>
__global__ __launch_bounds__(512, 2) void gemm256(
    const u16* __restrict__ A0, const u16* __restrict__ A1,
    int Astride, int ksplit,
    const u16* __restrict__ BT, int Bld, int M, int N, int K,
    const float* __restrict__ bias, void* __restrict__ outv, int out_ld)
{
  __shared__ u16 lds[2*32768];           // 128 KiB
  const int tid  = threadIdx.x;
  const int lane = tid & 63;
  const int wid  = tid >> 6;             // 0..7
  const int wm = wid >> 2, wn = wid & 3; // 2M x 4N waves
  const int l15 = lane & 15, l4 = lane >> 4;
  const int m0 = blockIdx.x * 256, n0 = blockIdx.y * 256;

  f32x4 acc[8][4];
  #pragma unroll
  for (int i = 0; i < 8; ++i)
    #pragma unroll
    for (int j = 0; j < 4; ++j)
      acc[i][j] = (f32x4){0.f, 0.f, 0.f, 0.f};

  // staging: half-tile = 128 rows x 8 slots = 1024 slots; thread -> s0, s1
  const int s0 = tid, s1 = tid + 512;
  const int r0 = s0 >> 3, g0 = (s0 & 7) ^ (r0 & 7);
  const int r1 = s1 >> 3, g1 = (s1 & 7) ^ (r1 & 7);

  const int nt = K >> 6;

  auto stageA = [&](int kt, int h, int buf){
    const int kb = kt * 64;
    const u16* Ab = A0; int kl = kb;
    if (kb >= ksplit){ Ab = A1; kl = kb - ksplit; }
    u16* dst = &lds[buf*32768 + h*8192];
    gl16(&Ab[(size_t)(m0 + h*128 + r0) * Astride + kl + g0*8], &dst[s0*8]);
    gl16(&Ab[(size_t)(m0 + h*128 + r1) * Astride + kl + g1*8], &dst[s1*8]);
  };
  auto stageB = [&](int kt, int h, int buf){
    const int kb = kt * 64;
    u16* dst = &lds[buf*32768 + 16384 + h*8192];
    gl16(&BT[(size_t)(n0 + h*128 + r0) * Bld + kb + g0*8], &dst[s0*8]);
    gl16(&BT[(size_t)(n0 + h*128 + r1) * Bld + kb + g1*8], &dst[s1*8]);
  };
  auto lda = [&](int i, int kc, int buf) -> bf16x8 {
    const int r = wm*128 + i*16 + l15;
    const int c = (kc*4 + l4) ^ (r & 7);
    return *(const bf16x8*)&lds[buf*32768 + r*64 + c*8];
  };
  auto ldb = [&](int j, int kc, int buf) -> bf16x8 {
    const int r = wn*64 + j*16 + l15;
    const int c = (kc*4 + l4) ^ (r & 7);
    return *(const bf16x8*)&lds[buf*32768 + 16384 + r*64 + c*8];
  };

  // prologue: stage tile 0 fully (8 loads)
  stageA(0, 0, 0); stageA(0, 1, 0); stageB(0, 0, 0); stageB(0, 1, 0);

  for (int t = 0; t < nt; ++t){
    const int buf = t & 1, nbuf = buf ^ 1;
    if (t + 1 < nt){
      stageA(t+1, 0, nbuf); stageA(t+1, 1, nbuf);
      stageB(t+1, 0, nbuf); stageB(t+1, 1, nbuf);
      asm volatile("s_waitcnt vmcnt(8)" ::: "memory");  // tile t's 8 landed
    } else {
      asm volatile("s_waitcnt vmcnt(0)" ::: "memory");
    }
    __builtin_amdgcn_sched_barrier(0);
    __builtin_amdgcn_s_barrier();          // all waves' tile-t loads landed
    __builtin_amdgcn_sched_barrier(0);

    bf16x8 a_[4][2], b_[4][2];
    #pragma unroll
    for (int j = 0; j < 4; ++j){ b_[j][0] = ldb(j, 0, buf); b_[j][1] = ldb(j, 1, buf); }
    #pragma unroll
    for (int i = 0; i < 4; ++i){ a_[i][0] = lda(i, 0, buf); a_[i][1] = lda(i, 1, buf); }
    __builtin_amdgcn_s_setprio(1);
    #pragma unroll
    for (int i = 0; i < 4; ++i)
      #pragma unroll
      for (int j = 0; j < 4; ++j){
        acc[i][j] = __builtin_amdgcn_mfma_f32_16x16x32_bf16(a_[i][0], b_[j][0], acc[i][j], 0,0,0);
        acc[i][j] = __builtin_amdgcn_mfma_f32_16x16x32_bf16(a_[i][1], b_[j][1], acc[i][j], 0,0,0);
      }
    __builtin_amdgcn_s_setprio(0);
    #pragma unroll
    for (int i = 0; i < 4; ++i){ a_[i][0] = lda(4+i, 0, buf); a_[i][1] = lda(4+i, 1, buf); }
    __builtin_amdgcn_s_setprio(1);
    #pragma unroll
    for (int i = 0; i < 4; ++i)
      #pragma unroll
      for (int j = 0; j < 4; ++j){
        acc[4+i][j] = __builtin_amdgcn_mfma_f32_16x16x32_bf16(a_[i][0], b_[j][0], acc[4+i][j], 0,0,0);
        acc[4+i][j] = __builtin_amdgcn_mfma_f32_16x16x32_bf16(a_[i][1], b_[j][1], acc[4+i][j], 0,0,0);
      }
    __builtin_amdgcn_s_setprio(0);

    __builtin_amdgcn_sched_barrier(0);
    __builtin_amdgcn_s_barrier();          // all reads of buf done
    __builtin_amdgcn_sched_barrier(0);
  }

  // epilogue: C[row][col], row=(lane>>4)*4+r, col=lane&15 (m89-verified)
  const int rb = m0 + wm*128 + l4*4;
  const int cb = n0 + wn*64 + l15;
  #pragma unroll
  for (int i = 0; i < 8; ++i){
    #pragma unroll
    for (int j = 0; j < 4; ++j){
      const int col = cb + j*16;
      const float badd = bias ? bias[col] : 0.f;
      #pragma unroll
      for (int r = 0; r < 4; ++r){
        const int row = rb + i*16 + r;
        float y = acc[i][j][r] + badd;
        if (RELU) y = y > 0.f ? y : 0.f;
        if (OF32){
          float* po = &((float*)outv)[(size_t)row * out_ld + col];
          if (ACC) y += *po;
          *po = y;
        } else {
          u16* po = &((u16*)outv)[(size_t)row * out_ld + col];
          if (ACC) y += bf2f(*po);
          *po = f2bf(y);
        }
      }
    }
  }
}

// -------- mask pack: bit k of mb[row][c] = mask(row, c*64+k) -----------------
__global__ __launch_bounds__(256) void mask_pack(
    const int* __restrict__ slf, const int* __restrict__ adj,
    u64* __restrict__ mb_g, u64* __restrict__ mb_l)
{
  const int idx  = blockIdx.x * 4 + (threadIdx.x >> 6);  // (row, c) pair
  const int lane = threadIdx.x & 63;
  const size_t mi = (size_t)(idx >> 2) * 256 + (size_t)(idx & 3) * 64 + lane;
  const bool g = slf[mi] != 0;
  const bool l = g || (adj[mi] == 0);
  const u64 bg = __ballot(g);
  const u64 bl = __ballot(l);
  if (lane == 0){ mb_g[idx] = bg; mb_l[idx] = bl; }
}

// ---------------- MFMA flash attention ---------------------------------------
// block = (b_loc, h, qtile of 128 rows); 4 waves x 32 q-rows.
// qkv: half-local [8192][1536]; q @ h*64, k @ 512+h*64, v @ 1024+h*64.
__global__ __launch_bounds__(256) void attn_mfma(
    const u16* __restrict__ qkv, const u64* __restrict__ mb,
    int boff, u16* __restrict__ out)
{
  __shared__ u16 kbuf[64*64];     // [key][dim], swizzled col ^= (key&7)<<3
  __shared__ u16 vtbuf[64*64];    // [dim][key], swizzled col ^= (dim&7)<<3
  __shared__ u16 pbuf[4][32*64];  // per-wave P [row][key], swizzled

  const int b_loc = blockIdx.x >> 4;
  const int h     = (blockIdx.x >> 1) & 7;
  const int qt    = blockIdx.x & 1;
  const int b     = boff + b_loc;
  const int t     = threadIdx.x;
  const int w     = t >> 6, lane = t & 63;
  const int l15   = lane & 15, l4 = lane >> 4;

  bf16x8 qf[2][2];
  {
    const int rbase = b_loc*256 + qt*128 + w*32;
    #pragma unroll
    for (int i = 0; i < 2; ++i)
      #pragma unroll
      for (int kc = 0; kc < 2; ++kc)
        qf[i][kc] = *(const bf16x8*)&qkv[(size_t)(rbase + i*16 + l15)*1536 + h*64 + kc*32 + l4*8];
  }

  f32x4 acc_o[2][4];
  float m_[2][4], l_[2][4];
  #pragma unroll
  for (int i = 0; i < 2; ++i){
    #pragma unroll
    for (int j = 0; j < 4; ++j) acc_o[i][j] = (f32x4){0.f,0.f,0.f,0.f};
    #pragma unroll
    for (int r = 0; r < 4; ++r){ m_[i][r] = -1e30f; l_[i][r] = 0.f; }
  }

  for (int c = 0; c < 4; ++c){
    __syncthreads();
    {   // stage K and V^T (swizzled); thread -> key row t>>2, dim group (t&3)*16
      const int kr = t >> 2, dg = (t & 3) * 16;
      const size_t rbase = (size_t)(b_loc*256 + c*64 + kr)*1536 + h*64 + dg;
      u16x8 k0 = *(const u16x8*)&qkv[rbase + 512];
      u16x8 k1 = *(const u16x8*)&qkv[rbase + 512 + 8];
      u16x8 v0 = *(const u16x8*)&qkv[rbase + 1024];
      u16x8 v1 = *(const u16x8*)&qkv[rbase + 1024 + 8];
      const int sw = (kr & 7) << 3;
      *(u16x8*)&kbuf[kr*64 + (dg ^ sw)]       = k0;
      *(u16x8*)&kbuf[kr*64 + ((dg + 8) ^ sw)] = k1;
      #pragma unroll
      for (int e = 0; e < 8; ++e){
        const int d0 = dg + e, d1 = dg + 8 + e;
        vtbuf[d0*64 + (kr ^ ((d0 & 7) << 3))] = v0[e];
        vtbuf[d1*64 + (kr ^ ((d1 & 7) << 3))] = v1[e];
      }
    }
    __syncthreads();

    bf16x8 kfr[4][2];
    #pragma unroll
    for (int jb = 0; jb < 4; ++jb){
      const int key = jb*16 + l15;
      const int sw = (key & 7) << 3;
      #pragma unroll
      for (int kc = 0; kc < 2; ++kc)
        kfr[jb][kc] = *(const bf16x8*)&kbuf[key*64 + ((kc*32 + l4*8) ^ sw)];
    }
    f32x4 s_[2][4];
    #pragma unroll
    for (int i = 0; i < 2; ++i)
      #pragma unroll
      for (int jb = 0; jb < 4; ++jb){
        f32x4 a = (f32x4){0.f,0.f,0.f,0.f};
        a = __builtin_amdgcn_mfma_f32_16x16x32_bf16(qf[i][0], kfr[jb][0], a, 0,0,0);
        a = __builtin_amdgcn_mfma_f32_16x16x32_bf16(qf[i][1], kfr[jb][1], a, 0,0,0);
        s_[i][jb] = a;
      }

    #pragma unroll
    for (int i = 0; i < 2; ++i){
      #pragma unroll
      for (int r = 0; r < 4; ++r){
        const int prow = i*16 + l4*4 + r;
        const int qrow = qt*128 + w*32 + prow;
        const u64 bits = mb[((size_t)b*256 + qrow)*4 + c];
        float sv[4];
        #pragma unroll
        for (int jb = 0; jb < 4; ++jb){
          float xv = s_[i][jb][r] * 0.125f;
          if ((bits >> (jb*16 + l15)) & 1ull) xv = -1e9f;
          sv[jb] = xv;
        }
        float mx = fmaxf(fmaxf(sv[0], sv[1]), fmaxf(sv[2], sv[3]));
        #pragma unroll
        for (int d = 1; d < 16; d <<= 1)
          mx = fmaxf(mx, __shfl_xor(mx, d, 64));
        const float mnew = fmaxf(m_[i][r], mx);
        const float corr = __expf(m_[i][r] - mnew);
        m_[i][r] = mnew;
        float ps = 0.f;
        const int swp = (prow & 7) << 3;
        #pragma unroll
        for (int jb = 0; jb < 4; ++jb){
          const float p = __expf(sv[jb] - mnew);
          ps += p;
          pbuf[w][prow*64 + ((jb*16 + l15) ^ swp)] = f2bf(p);
        }
        #pragma unroll
        for (int d = 1; d < 16; d <<= 1)
          ps += __shfl_xor(ps, d, 64);
        l_[i][r] = l_[i][r] * corr + ps;
        #pragma unroll
        for (int j2 = 0; j2 < 4; ++j2) acc_o[i][j2][r] *= corr;
      }
    }

    bf16x8 vfr[4][2];
    #pragma unroll
    for (int j2 = 0; j2 < 4; ++j2){
      const int dim = j2*16 + l15;
      const int sw = (dim & 7) << 3;
      #pragma unroll
      for (int kc = 0; kc < 2; ++kc)
        vfr[j2][kc] = *(const bf16x8*)&vtbuf[dim*64 + ((kc*32 + l4*8) ^ sw)];
    }
    #pragma unroll
    for (int i = 0; i < 2; ++i){
      const int prow = i*16 + l15;
      const int swp = (prow & 7) << 3;
      bf16x8 pa0 = *(const bf16x8*)&pbuf[w][prow*64 + ((l4*8) ^ swp)];
      bf16x8 pa1 = *(const bf16x8*)&pbuf[w][prow*64 + ((32 + l4*8) ^ swp)];
      #pragma unroll
      for (int j2 = 0; j2 < 4; ++j2){
        acc_o[i][j2] = __builtin_amdgcn_mfma_f32_16x16x32_bf16(pa0, vfr[j2][0], acc_o[i][j2], 0,0,0);
        acc_o[i][j2] = __builtin_amdgcn_mfma_f32_16x16x32_bf16(pa1, vfr[j2][1], acc_o[i][j2], 0,0,0);
      }
    }
  }

  #pragma unroll
  for (int i = 0; i < 2; ++i){
    #pragma unroll
    for (int r = 0; r < 4; ++r){
      const int qrow = qt*128 + w*32 + i*16 + l4*4 + r;
      const float inv = 1.f / l_[i][r];
      const size_t ob = ((size_t)b*256 + qrow)*512 + h*64;
      #pragma unroll
      for (int j2 = 0; j2 < 4; ++j2)
        out[ob + j2*16 + l15] = f2bf(acc_o[i][j2][r] * inv);
    }
  }
}

// -------- fused residual + LayerNorm + npm; a bf16, res f32|bf16, out bf16 ---
template<int RF32>
__global__ __launch_bounds__(256) void ln_fused(
    const u16* a, const void* __restrict__ res,
    const float* __restrict__ sc, const float* __restrict__ bs,
    const float* __restrict__ npm, u16* out)
{
  const int row = blockIdx.x, t = threadIdx.x;
  const size_t bse = (size_t)row * 1024 + t*4;
  u16x4 av = *(const u16x4*)&a[bse];
  float rv[4];
  if (RF32){
    f32x4 q = *(const f32x4*)&((const float*)res)[bse];
    #pragma unroll
    for (int j = 0; j < 4; ++j) rv[j] = q[j];
  } else {
    u16x4 q = *(const u16x4*)&((const u16*)res)[bse];
    #pragma unroll
    for (int j = 0; j < 4; ++j) rv[j] = bf2f(q[j]);
  }
  float vv[4]; float s = 0.f, sq = 0.f;
  #pragma unroll
  for (int j = 0; j < 4; ++j){
    vv[j] = bf2f(av[j]) + rv[j];
    s += vv[j]; sq += vv[j]*vv[j];
  }
  #pragma unroll
  for (int i = 1; i < 64; i <<= 1){
    s  += __shfl_xor(s,  i, 64);
    sq += __shfl_xor(sq, i, 64);
  }
  __shared__ float red[8];
  const int wid = t >> 6, lane = t & 63;
  if (lane == 0){ red[wid] = s; red[4 + wid] = sq; }
  __syncthreads();
  s  = red[0] + red[1] + red[2] + red[3];
  sq = red[4] + red[5] + red[6] + red[7];
  const float mean = s * (1.f/1024.f);
  const float var  = sq * (1.f/1024.f) - mean*mean;
  const float rstd = rsqrtf(var + 1e-5f);
  const float nm   = npm[row];
  u16x4 ov;
  #pragma unroll
  for (int j = 0; j < 4; ++j){
    float y = (vv[j] - mean) * rstd * sc[t*4+j] + bs[t*4+j];
    ov[j] = f2bf(y * nm);
  }
  *(u16x4*)&out[bse] = ov;
}

// ---------------- launcher ---------------------------------------------------
extern "C" void kernel_launch(void* const* d_in, const int* in_sizes, int n_in,
                              void* d_out, int out_size, void* d_ws, size_t ws_size,
                              hipStream_t stream)
{
  // ws (u16 el), 112 MiB (proven):
  //  W  [0, 8388608): wqkvT|woT|w1T|w2T|fcT
  //  R1 [8388608, 25165824):  xbf (phase1) -> tmp -> xl (phase2, in-place LN)
  //  R2 [25165824, 41943040): qkvh [8192][1536] (phase1) -> ln1 (phase2)
  //  R3 [41943040, 58720256): xg  (written once, layer-0 end; nothing aliases)
  // d_out (u16): attnb0 [0,8388608) | attnb1 [8388608,16777216)
  //   phase1: mb_g/mb_l @ 16777216 | phase2: hbufA [16777216,33554432)
  const size_t NEED = 58720256ull * 2ull;
  if (ws_size < NEED){
    zero_out<<<4096, 256, 0, stream>>>((float*)d_out, out_size);
    return;
  }

  const float* x   = (const float*)d_in[0];
  const int*   adj = (const int*)d_in[1];
  const float* npm = (const float*)d_in[2];
  const int*   slf = (const int*)d_in[3];
  const float* fcw = (const float*)d_in[30];
  const float* fcb = (const float*)d_in[31];

  u16* ws    = (u16*)d_ws;
  u16* wqkvT = ws;
  u16* woT   = ws + 1572864;
  u16* w1T   = ws + 2097152;
  u16* w2T   = ws + 4194304;
  u16* fcT   = ws + 6291456;
  u16* xbf   = ws + 8388608;           // R1: [16384][1024] bf16, then tmp/xl
  u16* tmp   = ws + 8388608;
  u16* qkvh  = ws + 25165824;          // R2: [8192][1536], then ln1
  u16* ln1   = ws + 25165824;
  u16* xg    = ws + 41943040;          // R3 (exclusive)

  u16* dout16 = (u16*)d_out;
  u16* attnb0 = dout16;                // [16384][512]
  u16* attnb1 = dout16 + 8388608;      // [16384][512]
  u16* hbufA  = dout16 + 16777216;     // [16384][1024] (phase2 only)
  u64* mb_g   = (u64*)(dout16 + 16777216);   // phase1 only (hbufA window)
  u64* mb_l   = mb_g + 65536;

  cvt_bf16<<<8192, 256, 0, stream>>>(x, xbf);
  mask_pack<<<16384, 256, 0, stream>>>(slf, adj, mb_g, mb_l);
  transpose_w<<<dim3(64, 32), 256, 0, stream>>>(fcw, fcT, 2048, 1024, 0);

  // Phase 1: both layers' QKV + attention (xbf + masks live throughout)
  for (int L = 0; L < 2; ++L){
    const int bi = 4 + L*13;
    transpose_w3<<<dim3(32, 16, 3), 256, 0, stream>>>(
        (const float*)d_in[bi+0], (const float*)d_in[bi+1],
        (const float*)d_in[bi+2], wqkvT, 1024, 512);
    u16* attnb = L ? attnb1 : attnb0;
    for (int hf = 0; hf < 2; ++hf){
      const u16* xh = xbf + (size_t)hf*8192*1024;
      gemm256<0,0,0><<<dim3(32, 6), 512, 0, stream>>>(
          xh, xh, 1024, 1024, wqkvT, 1024, 8192, 1536, 1024, nullptr, qkvh, 1536);
      attn_mfma<<<512, 256, 0, stream>>>(qkvh, L ? mb_l : mb_g, hf*32, attnb);
    }
  }

  // Phase 2: layer bodies (xbf/masks dead; tmp R1, ln1 R2, hbufA in d_out)
  for (int L = 0; L < 2; ++L){
    const int bi = 4 + L*13;
    const float* bo  = (const float*)d_in[bi+4];
    const float* l1s = (const float*)d_in[bi+5];
    const float* l1b = (const float*)d_in[bi+6];
    const float* b1  = (const float*)d_in[bi+8];
    const float* b2  = (const float*)d_in[bi+10];
    const float* l2s = (const float*)d_in[bi+11];
    const float* l2b = (const float*)d_in[bi+12];

    transpose_w<<<dim3(16, 32), 256, 0, stream>>>((const float*)d_in[bi+3], woT, 512, 1024, 0);
    transpose_w<<<dim3(32, 64), 256, 0, stream>>>((const float*)d_in[bi+7], w1T, 1024, 2048, 0);
    transpose_w<<<dim3(64, 32), 256, 0, stream>>>((const float*)d_in[bi+9], w2T, 2048, 1024, 0);

    const u16* attnb = L ? attnb1 : attnb0;
    // out-proj + bo -> tmp
    gemm256<0,0,0><<<dim3(64, 4), 512, 0, stream>>>(
        attnb, attnb, 512, 512, woT, 512, 16384, 1024, 512, bo, tmp, 1024);
    // ln1 = LN(tmp + x) * npm -> R2
    ln_fused<1><<<16384, 256, 0, stream>>>(tmp, x, l1s, l1b, npm, ln1);
    // FFN: two N-halves of w1 through hbufA, K-accumulated into tmp
    for (int hh = 0; hh < 2; ++hh){
      gemm256<1,0,0><<<dim3(64, 4), 512, 0, stream>>>(
          ln1, ln1, 1024, 1024, w1T + (size_t)hh*1024*1024, 1024,
          16384, 1024, 1024, b1 + hh*1024, hbufA, 1024);
      if (hh == 0)
        gemm256<0,0,0><<<dim3(64, 4), 512, 0, stream>>>(
            hbufA, hbufA, 1024, 1024, w2T, 2048, 16384, 1024, 1024, b2, tmp, 1024);
      else
        gemm256<0,0,1><<<dim3(64, 4), 512, 0, stream>>>(
            hbufA, hbufA, 1024, 1024, w2T + 1024, 2048, 16384, 1024, 1024,
            nullptr, tmp, 1024);
    }
    // xout = LN(tmp + ln1) * npm; layer0 -> xg, layer1 -> in-place (xl = tmp)
    ln_fused<0><<<16384, 256, 0, stream>>>(tmp, ln1, l2s, l2b, npm, L ? tmp : xg);
  }

  // final: [xg | xl] @ fcT + fc_b -> d_out (f32), K split at 1024
  gemm256<0,1,0><<<dim3(64, 4), 512, 0, stream>>>(
      xg, tmp, 1024, 1024, fcT, 2048, 16384, 1024, 2048, fcb, d_out, 1024);
}

// Round 13
// 839.841 us; speedup vs baseline: 1.0264x; 1.0044x over previous
//
#include <hip/hip_runtime.h>

// GLAT: B=64, N=256, D=1024, H=8, DK=64, DI=2048.
// I/O dtype: float32. Internal: bf16 MFMA + f32 accum. adj/slf: int32.

typedef unsigned short u16;
typedef unsigned long long u64;
typedef __bf16 bf16_t;
typedef bf16_t bf16x8 __attribute__((ext_vector_type(8)));
typedef float  f32x4  __attribute__((ext_vector_type(4)));
typedef u16    u16x8  __attribute__((ext_vector_type(8)));
typedef u16    u16x4  __attribute__((ext_vector_type(4)));

__device__ __forceinline__ float bf2f(u16 u){
  union { unsigned int i; float f; } c; c.i = ((unsigned int)u) << 16; return c.f;
}
__device__ __forceinline__ u16 f2bf(float f){
  union { float f; unsigned int u; } c; c.f = f;
  unsigned int u = c.u;
  unsigned int r = (u + 0x7fffu + ((u >> 16) & 1u)) >> 16;  // RNE
  return (u16)r;
}

// async 16B global -> LDS (direct). LDS dest = wave-uniform base + lane*16.
__device__ __forceinline__ void gl16(const u16* g, u16* l){
  __builtin_amdgcn_global_load_lds(
      (const __attribute__((address_space(1))) void*)g,
      (__attribute__((address_space(3))) void*)l, 16, 0, 0);
}

// ---------------- diagnostic fallback: zero d_out (f32) ----------------------
__global__ __launch_bounds__(256) void zero_out(float* out, int n){
  for (int i = blockIdx.x * 256 + threadIdx.x; i < n; i += 256 * 4096) out[i] = 0.f;
}

// ---------------- f32 -> bf16 bulk convert (8 elems/thread) ------------------
__global__ __launch_bounds__(256) void cvt_bf16(
    const float* __restrict__ in, u16* __restrict__ out)
{
  const size_t i = ((size_t)blockIdx.x * 256 + threadIdx.x) * 8;
  f32x4 a = *(const f32x4*)&in[i];
  f32x4 b = *(const f32x4*)&in[i + 4];
  u16x8 o;
  #pragma unroll
  for (int j = 0; j < 4; ++j){ o[j] = f2bf(a[j]); o[4+j] = f2bf(b[j]); }
  *(u16x8*)&out[i] = o;
}

// -------- weight transpose+convert: src f32 [K][N] -> dst bf16 [(off+n)*K+k] --
__global__ __launch_bounds__(256) void transpose_w(
    const float* __restrict__ src, u16* __restrict__ dst, int K, int N, int dstOff)
{
  __shared__ u16 tile[32][33];
  const int bk = blockIdx.x * 32, bn = blockIdx.y * 32;
  const int t = threadIdx.x;
  const int r = t >> 5, c = t & 31;
  #pragma unroll
  for (int p = 0; p < 4; ++p)
    tile[r + p*8][c] = f2bf(src[(size_t)(bk + r + p*8) * N + bn + c]);
  __syncthreads();
  #pragma unroll
  for (int p = 0; p < 4; ++p)
    dst[(size_t)(dstOff + bn + r + p*8) * K + bk + c] = tile[c][r + p*8];
}

// -------- 3-source variant (QKV weights, same shape) via blockIdx.z ----------
__global__ __launch_bounds__(256) void transpose_w3(
    const float* __restrict__ sA, const float* __restrict__ sB,
    const float* __restrict__ sC, u16* __restrict__ dst, int K, int N)
{
  __shared__ u16 tile[32][33];
  const float* src = blockIdx.z == 0 ? sA : (blockIdx.z == 1 ? sB : sC);
  const int dstOff = blockIdx.z * N;
  const int bk = blockIdx.x * 32, bn = blockIdx.y * 32;
  const int t = threadIdx.x;
  const int r = t >> 5, c = t & 31;
  #pragma unroll
  for (int p = 0; p < 4; ++p)
    tile[r + p*8][c] = f2bf(src[(size_t)(bk + r + p*8) * N + bn + c]);
  __syncthreads();
  #pragma unroll
  for (int p = 0; p < 4; ++p)
    dst[(size_t)(dstOff + bn + r + p*8) * K + bk + c] = tile[c][r + p*8];
}

// ---- GEMM 256x256, BK=64, 8 waves, dbuf LDS, 4-phase m201-style schedule ---
// C = A[M,K] @ BT[N,:]^T. A split at ksplit between A0/A1 (row stride Astride).
// BT row stride = Bld. ACC: out += result (pass bias=null).
// LDS per buf: A[256][64] @0, B[256][64] @16384 elems; slot sl of row r holds
// global chunk sl^(r&7) (zero-conflict frag reads, verified r8/r10); gl16 linear.
// r10's staging distribution (1 half-tile stage per phase, counted vmcnt(2))
// + m201's per-phase barrier + lgkmcnt(0) discipline (phase-locks waves: the
// T5-setprio and LDS-locality mechanisms need the role-split, m218b/m252).
template<int RELU, int OF32, int ACC>
__global__ __launch_bounds__(512, 2) void gemm256(
    const u16* __restrict__ A0, const u16* __restrict__ A1,
    int Astride, int ksplit,
    const u16* __restrict__ BT, int Bld, int M, int N, int K,
    const float* __restrict__ bias, void* __restrict__ outv, int out_ld)
{
  __shared__ u16 lds[2*32768];           // 128 KiB
  const int tid  = threadIdx.x;
  const int lane = tid & 63;
  const int wid  = tid >> 6;             // 0..7
  const int wm = wid >> 2, wn = wid & 3; // 2M x 4N waves
  const int l15 = lane & 15, l4 = lane >> 4;
  const int m0 = blockIdx.x * 256, n0 = blockIdx.y * 256;

  f32x4 acc[8][4];
  #pragma unroll
  for (int i = 0; i < 8; ++i)
    #pragma unroll
    for (int j = 0; j < 4; ++j)
      acc[i][j] = (f32x4){0.f, 0.f, 0.f, 0.f};

  // staging: half-tile = 128 rows x 8 slots = 1024 slots; thread -> s0, s1
  const int s0 = tid, s1 = tid + 512;
  const int r0 = s0 >> 3, g0 = (s0 & 7) ^ (r0 & 7);
  const int r1 = s1 >> 3, g1 = (s1 & 7) ^ (r1 & 7);

  const int nt = K >> 6;

  auto stageA = [&](int kt, int h, int buf){
    const int kb = kt * 64;
    const u16* Ab = A0; int kl = kb;
    if (kb >= ksplit){ Ab = A1; kl = kb - ksplit; }
    u16* dst = &lds[buf*32768 + h*8192];
    gl16(&Ab[(size_t)(m0 + h*128 + r0) * Astride + kl + g0*8], &dst[s0*8]);
    gl16(&Ab[(size_t)(m0 + h*128 + r1) * Astride + kl + g1*8], &dst[s1*8]);
  };
  auto stageB = [&](int kt, int h, int buf){
    const int kb = kt * 64;
    u16* dst = &lds[buf*32768 + 16384 + h*8192];
    gl16(&BT[(size_t)(n0 + h*128 + r0) * Bld + kb + g0*8], &dst[s0*8]);
    gl16(&BT[(size_t)(n0 + h*128 + r1) * Bld + kb + g1*8], &dst[s1*8]);
  };
  auto lda = [&](int i, int kc, int buf) -> bf16x8 {
    const int r = wm*128 + i*16 + l15;
    const int c = (kc*4 + l4) ^ (r & 7);
    return *(const bf16x8*)&lds[buf*32768 + r*64 + c*8];
  };
  auto ldb = [&](int j, int kc, int buf) -> bf16x8 {
    const int r = wn*64 + j*16 + l15;
    const int c = (kc*4 + l4) ^ (r & 7);
    return *(const bf16x8*)&lds[buf*32768 + 16384 + r*64 + c*8];
  };

  #define SBAR  __builtin_amdgcn_sched_barrier(0)
  #define PBAR  do{ SBAR; __builtin_amdgcn_s_barrier(); SBAR; }while(0)
  #define LGKM0 do{ asm volatile("s_waitcnt lgkmcnt(0)" ::: "memory"); SBAR; }while(0)

  // prologue: stage tile 0 fully (8 loads)
  stageA(0, 0, 0); stageA(0, 1, 0); stageB(0, 0, 0); stageB(0, 1, 0);

  for (int t = 0; t < nt; ++t){
    const int buf = t & 1, nbuf = buf ^ 1;
    const bool pf = (t + 1 < nt);
    bf16x8 a_[4][2], b_[2][2];

    // ---- P0: a_lo x b_lo ----
    if (pf){
      stageA(t+1, 0, nbuf);
      asm volatile("s_waitcnt vmcnt(2)" ::: "memory");  // tile t's 8 landed
    } else {
      asm volatile("s_waitcnt vmcnt(0)" ::: "memory");
    }
    PBAR;                                   // all waves' tile-t loads landed
    #pragma unroll
    for (int i = 0; i < 4; ++i){ a_[i][0] = lda(i, 0, buf); a_[i][1] = lda(i, 1, buf); }
    #pragma unroll
    for (int j = 0; j < 2; ++j){ b_[j][0] = ldb(j, 0, buf); b_[j][1] = ldb(j, 1, buf); }
    LGKM0;
    __builtin_amdgcn_s_setprio(1);
    #pragma unroll
    for (int i = 0; i < 4; ++i)
      #pragma unroll
      for (int j = 0; j < 2; ++j){
        acc[i][j] = __builtin_amdgcn_mfma_f32_16x16x32_bf16(a_[i][0], b_[j][0], acc[i][j], 0,0,0);
        acc[i][j] = __builtin_amdgcn_mfma_f32_16x16x32_bf16(a_[i][1], b_[j][1], acc[i][j], 0,0,0);
      }
    __builtin_amdgcn_s_setprio(0);
    PBAR;

    // ---- P1: a_lo x b_hi ----
    #pragma unroll
    for (int j = 0; j < 2; ++j){ b_[j][0] = ldb(2+j, 0, buf); b_[j][1] = ldb(2+j, 1, buf); }
    if (pf) stageA(t+1, 1, nbuf);
    LGKM0;
    __builtin_amdgcn_s_setprio(1);
    #pragma unroll
    for (int i = 0; i < 4; ++i)
      #pragma unroll
      for (int j = 0; j < 2; ++j){
        acc[i][2+j] = __builtin_amdgcn_mfma_f32_16x16x32_bf16(a_[i][0], b_[j][0], acc[i][2+j], 0,0,0);
        acc[i][2+j] = __builtin_amdgcn_mfma_f32_16x16x32_bf16(a_[i][1], b_[j][1], acc[i][2+j], 0,0,0);
      }
    __builtin_amdgcn_s_setprio(0);
    PBAR;

    // ---- P2: a_hi x b_hi ----
    #pragma unroll
    for (int i = 0; i < 4; ++i){ a_[i][0] = lda(4+i, 0, buf); a_[i][1] = lda(4+i, 1, buf); }
    if (pf) stageB(t+1, 0, nbuf);
    LGKM0;
    __builtin_amdgcn_s_setprio(1);
    #pragma unroll
    for (int i = 0; i < 4; ++i)
      #pragma unroll
      for (int j = 0; j < 2; ++j){
        acc[4+i][2+j] = __builtin_amdgcn_mfma_f32_16x16x32_bf16(a_[i][0], b_[j][0], acc[4+i][2+j], 0,0,0);
        acc[4+i][2+j] = __builtin_amdgcn_mfma_f32_16x16x32_bf16(a_[i][1], b_[j][1], acc[4+i][2+j], 0,0,0);
      }
    __builtin_amdgcn_s_setprio(0);
    PBAR;

    // ---- P3: a_hi x b_lo (re-read b_lo) ----
    #pragma unroll
    for (int j = 0; j < 2; ++j){ b_[j][0] = ldb(j, 0, buf); b_[j][1] = ldb(j, 1, buf); }
    if (pf) stageB(t+1, 1, nbuf);
    LGKM0;
    __builtin_amdgcn_s_setprio(1);
    #pragma unroll
    for (int i = 0; i < 4; ++i)
      #pragma unroll
      for (int j = 0; j < 2; ++j){
        acc[4+i][j] = __builtin_amdgcn_mfma_f32_16x16x32_bf16(a_[i][0], b_[j][0], acc[4+i][j], 0,0,0);
        acc[4+i][j] = __builtin_amdgcn_mfma_f32_16x16x32_bf16(a_[i][1], b_[j][1], acc[4+i][j], 0,0,0);
      }
    __builtin_amdgcn_s_setprio(0);
    PBAR;                                   // all reads of buf done
  }
  #undef SBAR
  #undef PBAR
  #undef LGKM0

  // epilogue: C[row][col], row=(lane>>4)*4+r, col=lane&15 (m89-verified)
  const int rb = m0 + wm*128 + l4*4;
  const int cb = n0 + wn*64 + l15;
  #pragma unroll
  for (int i = 0; i < 8; ++i){
    #pragma unroll
    for (int j = 0; j < 4; ++j){
      const int col = cb + j*16;
      const float badd = bias ? bias[col] : 0.f;
      #pragma unroll
      for (int r = 0; r < 4; ++r){
        const int row = rb + i*16 + r;
        float y = acc[i][j][r] + badd;
        if (RELU) y = y > 0.f ? y : 0.f;
        if (OF32){
          float* po = &((float*)outv)[(size_t)row * out_ld + col];
          if (ACC) y += *po;
          *po = y;
        } else {
          u16* po = &((u16*)outv)[(size_t)row * out_ld + col];
          if (ACC) y += bf2f(*po);
          *po = f2bf(y);
        }
      }
    }
  }
}

// -------- mask pack: bit k of mb[row][c] = mask(row, c*64+k) -----------------
__global__ __launch_bounds__(256) void mask_pack(
    const int* __restrict__ slf, const int* __restrict__ adj,
    u64* __restrict__ mb_g, u64* __restrict__ mb_l)
{
  const int idx  = blockIdx.x * 4 + (threadIdx.x >> 6);  // (row, c) pair
  const int lane = threadIdx.x & 63;
  const size_t mi = (size_t)(idx >> 2) * 256 + (size_t)(idx & 3) * 64 + lane;
  const bool g = slf[mi] != 0;
  const bool l = g || (adj[mi] == 0);
  const u64 bg = __ballot(g);
  const u64 bl = __ballot(l);
  if (lane == 0){ mb_g[idx] = bg; mb_l[idx] = bl; }
}

// ---------------- MFMA flash attention ---------------------------------------
// block = (b_loc, h, qtile of 128 rows); 4 waves x 32 q-rows.
// qkv: half-local [8192][1536]; q @ h*64, k @ 512+h*64, v @ 1024+h*64.
__global__ __launch_bounds__(256) void attn_mfma(
    const u16* __restrict__ qkv, const u64* __restrict__ mb,
    int boff, u16* __restrict__ out)
{
  __shared__ u16 kbuf[64*64];     // [key][dim], swizzled col ^= (key&7)<<3
  __shared__ u16 vtbuf[64*64];    // [dim][key], swizzled col ^= (dim&7)<<3
  __shared__ u16 pbuf[4][32*64];  // per-wave P [row][key], swizzled

  const int b_loc = blockIdx.x >> 4;
  const int h     = (blockIdx.x >> 1) & 7;
  const int qt    = blockIdx.x & 1;
  const int b     = boff + b_loc;
  const int t     = threadIdx.x;
  const int w     = t >> 6, lane = t & 63;
  const int l15   = lane & 15, l4 = lane >> 4;

  bf16x8 qf[2][2];
  {
    const int rbase = b_loc*256 + qt*128 + w*32;
    #pragma unroll
    for (int i = 0; i < 2; ++i)
      #pragma unroll
      for (int kc = 0; kc < 2; ++kc)
        qf[i][kc] = *(const bf16x8*)&qkv[(size_t)(rbase + i*16 + l15)*1536 + h*64 + kc*32 + l4*8];
  }

  f32x4 acc_o[2][4];
  float m_[2][4], l_[2][4];
  #pragma unroll
  for (int i = 0; i < 2; ++i){
    #pragma unroll
    for (int j = 0; j < 4; ++j) acc_o[i][j] = (f32x4){0.f,0.f,0.f,0.f};
    #pragma unroll
    for (int r = 0; r < 4; ++r){ m_[i][r] = -1e30f; l_[i][r] = 0.f; }
  }

  for (int c = 0; c < 4; ++c){
    __syncthreads();
    {   // stage K and V^T (swizzled); thread -> key row t>>2, dim group (t&3)*16
      const int kr = t >> 2, dg = (t & 3) * 16;
      const size_t rbase = (size_t)(b_loc*256 + c*64 + kr)*1536 + h*64 + dg;
      u16x8 k0 = *(const u16x8*)&qkv[rbase + 512];
      u16x8 k1 = *(const u16x8*)&qkv[rbase + 512 + 8];
      u16x8 v0 = *(const u16x8*)&qkv[rbase + 1024];
      u16x8 v1 = *(const u16x8*)&qkv[rbase + 1024 + 8];
      const int sw = (kr & 7) << 3;
      *(u16x8*)&kbuf[kr*64 + (dg ^ sw)]       = k0;
      *(u16x8*)&kbuf[kr*64 + ((dg + 8) ^ sw)] = k1;
      #pragma unroll
      for (int e = 0; e < 8; ++e){
        const int d0 = dg + e, d1 = dg + 8 + e;
        vtbuf[d0*64 + (kr ^ ((d0 & 7) << 3))] = v0[e];
        vtbuf[d1*64 + (kr ^ ((d1 & 7) << 3))] = v1[e];
      }
    }
    __syncthreads();

    bf16x8 kfr[4][2];
    #pragma unroll
    for (int jb = 0; jb < 4; ++jb){
      const int key = jb*16 + l15;
      const int sw = (key & 7) << 3;
      #pragma unroll
      for (int kc = 0; kc < 2; ++kc)
        kfr[jb][kc] = *(const bf16x8*)&kbuf[key*64 + ((kc*32 + l4*8) ^ sw)];
    }
    f32x4 s_[2][4];
    #pragma unroll
    for (int i = 0; i < 2; ++i)
      #pragma unroll
      for (int jb = 0; jb < 4; ++jb){
        f32x4 a = (f32x4){0.f,0.f,0.f,0.f};
        a = __builtin_amdgcn_mfma_f32_16x16x32_bf16(qf[i][0], kfr[jb][0], a, 0,0,0);
        a = __builtin_amdgcn_mfma_f32_16x16x32_bf16(qf[i][1], kfr[jb][1], a, 0,0,0);
        s_[i][jb] = a;
      }

    #pragma unroll
    for (int i = 0; i < 2; ++i){
      #pragma unroll
      for (int r = 0; r < 4; ++r){
        const int prow = i*16 + l4*4 + r;
        const int qrow = qt*128 + w*32 + prow;
        const u64 bits = mb[((size_t)b*256 + qrow)*4 + c];
        float sv[4];
        #pragma unroll
        for (int jb = 0; jb < 4; ++jb){
          float xv = s_[i][jb][r] * 0.125f;
          if ((bits >> (jb*16 + l15)) & 1ull) xv = -1e9f;
          sv[jb] = xv;
        }
        float mx = fmaxf(fmaxf(sv[0], sv[1]), fmaxf(sv[2], sv[3]));
        #pragma unroll
        for (int d = 1; d < 16; d <<= 1)
          mx = fmaxf(mx, __shfl_xor(mx, d, 64));
        const float mnew = fmaxf(m_[i][r], mx);
        const float corr = __expf(m_[i][r] - mnew);
        m_[i][r] = mnew;
        float ps = 0.f;
        const int swp = (prow & 7) << 3;
        #pragma unroll
        for (int jb = 0; jb < 4; ++jb){
          const float p = __expf(sv[jb] - mnew);
          ps += p;
          pbuf[w][prow*64 + ((jb*16 + l15) ^ swp)] = f2bf(p);
        }
        #pragma unroll
        for (int d = 1; d < 16; d <<= 1)
          ps += __shfl_xor(ps, d, 64);
        l_[i][r] = l_[i][r] * corr + ps;
        #pragma unroll
        for (int j2 = 0; j2 < 4; ++j2) acc_o[i][j2][r] *= corr;
      }
    }

    bf16x8 vfr[4][2];
    #pragma unroll
    for (int j2 = 0; j2 < 4; ++j2){
      const int dim = j2*16 + l15;
      const int sw = (dim & 7) << 3;
      #pragma unroll
      for (int kc = 0; kc < 2; ++kc)
        vfr[j2][kc] = *(const bf16x8*)&vtbuf[dim*64 + ((kc*32 + l4*8) ^ sw)];
    }
    #pragma unroll
    for (int i = 0; i < 2; ++i){
      const int prow = i*16 + l15;
      const int swp = (prow & 7) << 3;
      bf16x8 pa0 = *(const bf16x8*)&pbuf[w][prow*64 + ((l4*8) ^ swp)];
      bf16x8 pa1 = *(const bf16x8*)&pbuf[w][prow*64 + ((32 + l4*8) ^ swp)];
      #pragma unroll
      for (int j2 = 0; j2 < 4; ++j2){
        acc_o[i][j2] = __builtin_amdgcn_mfma_f32_16x16x32_bf16(pa0, vfr[j2][0], acc_o[i][j2], 0,0,0);
        acc_o[i][j2] = __builtin_amdgcn_mfma_f32_16x16x32_bf16(pa1, vfr[j2][1], acc_o[i][j2], 0,0,0);
      }
    }
  }

  #pragma unroll
  for (int i = 0; i < 2; ++i){
    #pragma unroll
    for (int r = 0; r < 4; ++r){
      const int qrow = qt*128 + w*32 + i*16 + l4*4 + r;
      const float inv = 1.f / l_[i][r];
      const size_t ob = ((size_t)b*256 + qrow)*512 + h*64;
      #pragma unroll
      for (int j2 = 0; j2 < 4; ++j2)
        out[ob + j2*16 + l15] = f2bf(acc_o[i][j2][r] * inv);
    }
  }
}

// -------- fused residual + LayerNorm + npm; a bf16, res f32|bf16, out bf16 ---
template<int RF32>
__global__ __launch_bounds__(256) void ln_fused(
    const u16* a, const void* __restrict__ res,
    const float* __restrict__ sc, const float* __restrict__ bs,
    const float* __restrict__ npm, u16* out)
{
  const int row = blockIdx.x, t = threadIdx.x;
  const size_t bse = (size_t)row * 1024 + t*4;
  u16x4 av = *(const u16x4*)&a[bse];
  float rv[4];
  if (RF32){
    f32x4 q = *(const f32x4*)&((const float*)res)[bse];
    #pragma unroll
    for (int j = 0; j < 4; ++j) rv[j] = q[j];
  } else {
    u16x4 q = *(const u16x4*)&((const u16*)res)[bse];
    #pragma unroll
    for (int j = 0; j < 4; ++j) rv[j] = bf2f(q[j]);
  }
  float vv[4]; float s = 0.f, sq = 0.f;
  #pragma unroll
  for (int j = 0; j < 4; ++j){
    vv[j] = bf2f(av[j]) + rv[j];
    s += vv[j]; sq += vv[j]*vv[j];
  }
  #pragma unroll
  for (int i = 1; i < 64; i <<= 1){
    s  += __shfl_xor(s,  i, 64);
    sq += __shfl_xor(sq, i, 64);
  }
  __shared__ float red[8];
  const int wid = t >> 6, lane = t & 63;
  if (lane == 0){ red[wid] = s; red[4 + wid] = sq; }
  __syncthreads();
  s  = red[0] + red[1] + red[2] + red[3];
  sq = red[4] + red[5] + red[6] + red[7];
  const float mean = s * (1.f/1024.f);
  const float var  = sq * (1.f/1024.f) - mean*mean;
  const float rstd = rsqrtf(var + 1e-5f);
  const float nm   = npm[row];
  u16x4 ov;
  #pragma unroll
  for (int j = 0; j < 4; ++j){
    float y = (vv[j] - mean) * rstd * sc[t*4+j] + bs[t*4+j];
    ov[j] = f2bf(y * nm);
  }
  *(u16x4*)&out[bse] = ov;
}

// ---------------- launcher ---------------------------------------------------
extern "C" void kernel_launch(void* const* d_in, const int* in_sizes, int n_in,
                              void* d_out, int out_size, void* d_ws, size_t ws_size,
                              hipStream_t stream)
{
  // ws (u16 el), 112 MiB (proven):
  //  W  [0, 8388608): wqkvT|woT|w1T|w2T|fcT
  //  R1 [8388608, 25165824):  xbf (phase1) -> tmp -> xl (phase2, in-place LN)
  //  R2 [25165824, 41943040): qkvh [8192][1536] (phase1) -> ln1 (phase2)
  //  R3 [41943040, 58720256): xg  (written once, layer-0 end; nothing aliases)
  // d_out (u16): attnb0 [0,8388608) | attnb1 [8388608,16777216)
  //   phase1: mb_g/mb_l @ 16777216 | phase2: hbufA [16777216,33554432)
  const size_t NEED = 58720256ull * 2ull;
  if (ws_size < NEED){
    zero_out<<<4096, 256, 0, stream>>>((float*)d_out, out_size);
    return;
  }

  const float* x   = (const float*)d_in[0];
  const int*   adj = (const int*)d_in[1];
  const float* npm = (const float*)d_in[2];
  const int*   slf = (const int*)d_in[3];
  const float* fcw = (const float*)d_in[30];
  const float* fcb = (const float*)d_in[31];

  u16* ws    = (u16*)d_ws;
  u16* wqkvT = ws;
  u16* woT   = ws + 1572864;
  u16* w1T   = ws + 2097152;
  u16* w2T   = ws + 4194304;
  u16* fcT   = ws + 6291456;
  u16* xbf   = ws + 8388608;           // R1: [16384][1024] bf16, then tmp/xl
  u16* tmp   = ws + 8388608;
  u16* qkvh  = ws + 25165824;          // R2: [8192][1536], then ln1
  u16* ln1   = ws + 25165824;
  u16* xg    = ws + 41943040;          // R3 (exclusive)

  u16* dout16 = (u16*)d_out;
  u16* attnb0 = dout16;                // [16384][512]
  u16* attnb1 = dout16 + 8388608;      // [16384][512]
  u16* hbufA  = dout16 + 16777216;     // [16384][1024] (phase2 only)
  u64* mb_g   = (u64*)(dout16 + 16777216);   // phase1 only (hbufA window)
  u64* mb_l   = mb_g + 65536;

  cvt_bf16<<<8192, 256, 0, stream>>>(x, xbf);
  mask_pack<<<16384, 256, 0, stream>>>(slf, adj, mb_g, mb_l);
  transpose_w<<<dim3(64, 32), 256, 0, stream>>>(fcw, fcT, 2048, 1024, 0);

  // Phase 1: both layers' QKV + attention (xbf + masks live throughout)
  for (int L = 0; L < 2; ++L){
    const int bi = 4 + L*13;
    transpose_w3<<<dim3(32, 16, 3), 256, 0, stream>>>(
        (const float*)d_in[bi+0], (const float*)d_in[bi+1],
        (const float*)d_in[bi+2], wqkvT, 1024, 512);
    u16* attnb = L ? attnb1 : attnb0;
    for (int hf = 0; hf < 2; ++hf){
      const u16* xh = xbf + (size_t)hf*8192*1024;
      gemm256<0,0,0><<<dim3(32, 6), 512, 0, stream>>>(
          xh, xh, 1024, 1024, wqkvT, 1024, 8192, 1536, 1024, nullptr, qkvh, 1536);
      attn_mfma<<<512, 256, 0, stream>>>(qkvh, L ? mb_l : mb_g, hf*32, attnb);
    }
  }

  // Phase 2: layer bodies (xbf/masks dead; tmp R1, ln1 R2, hbufA in d_out)
  for (int L = 0; L < 2; ++L){
    const int bi = 4 + L*13;
    const float* bo  = (const float*)d_in[bi+4];
    const float* l1s = (const float*)d_in[bi+5];
    const float* l1b = (const float*)d_in[bi+6];
    const float* b1  = (const float*)d_in[bi+8];
    const float* b2  = (const float*)d_in[bi+10];
    const float* l2s = (const float*)d_in[bi+11];
    const float* l2b = (const float*)d_in[bi+12];

    transpose_w<<<dim3(16, 32), 256, 0, stream>>>((const float*)d_in[bi+3], woT, 512, 1024, 0);
    transpose_w<<<dim3(32, 64), 256, 0, stream>>>((const float*)d_in[bi+7], w1T, 1024, 2048, 0);
    transpose_w<<<dim3(64, 32), 256, 0, stream>>>((const float*)d_in[bi+9], w2T, 2048, 1024, 0);

    const u16* attnb = L ? attnb1 : attnb0;
    // out-proj + bo -> tmp
    gemm256<0,0,0><<<dim3(64, 4), 512, 0, stream>>>(
        attnb, attnb, 512, 512, woT, 512, 16384, 1024, 512, bo, tmp, 1024);
    // ln1 = LN(tmp + x) * npm -> R2
    ln_fused<1><<<16384, 256, 0, stream>>>(tmp, x, l1s, l1b, npm, ln1);
    // FFN: two N-halves of w1 through hbufA, K-accumulated into tmp
    for (int hh = 0; hh < 2; ++hh){
      gemm256<1,0,0><<<dim3(64, 4), 512, 0, stream>>>(
          ln1, ln1, 1024, 1024, w1T + (size_t)hh*1024*1024, 1024,
          16384, 1024, 1024, b1 + hh*1024, hbufA, 1024);
      if (hh == 0)
        gemm256<0,0,0><<<dim3(64, 4), 512, 0, stream>>>(
            hbufA, hbufA, 1024, 1024, w2T, 2048, 16384, 1024, 1024, b2, tmp, 1024);
      else
        gemm256<0,0,1><<<dim3(64, 4), 512, 0, stream>>>(
            hbufA, hbufA, 1024, 1024, w2T + 1024, 2048, 16384, 1024, 1024,
            nullptr, tmp, 1024);
    }
    // xout = LN(tmp + ln1) * npm; layer0 -> xg, layer1 -> in-place (xl = tmp)
    ln_fused<0><<<16384, 256, 0, stream>>>(tmp, ln1, l2s, l2b, npm, L ? tmp : xg);
  }

  // final: [xg | xl] @ fcT + fc_b -> d_out (f32), K split at 1024
  gemm256<0,1,0><<<dim3(64, 4), 512, 0, stream>>>(
      xg, tmp, 1024, 1024, fcT, 2048, 16384, 1024, 2048, fcb, d_out, 1024);
}

// Round 14
// 796.207 us; speedup vs baseline: 1.0826x; 1.0548x over previous
//
#include <hip/hip_runtime.h>

// GLAT: B=64, N=256, D=1024, H=8, DK=64, DI=2048.
// I/O dtype: float32. Internal: bf16 MFMA + f32 accum. adj/slf: int32.

typedef unsigned short u16;
typedef unsigned long long u64;
typedef __bf16 bf16_t;
typedef bf16_t bf16x8 __attribute__((ext_vector_type(8)));
typedef float  f32x4  __attribute__((ext_vector_type(4)));
typedef u16    u16x8  __attribute__((ext_vector_type(8)));
typedef u16    u16x4  __attribute__((ext_vector_type(4)));

__device__ __forceinline__ float bf2f(u16 u){
  union { unsigned int i; float f; } c; c.i = ((unsigned int)u) << 16; return c.f;
}
__device__ __forceinline__ u16 f2bf(float f){
  union { float f; unsigned int u; } c; c.f = f;
  unsigned int u = c.u;
  unsigned int r = (u + 0x7fffu + ((u >> 16) & 1u)) >> 16;  // RNE
  return (u16)r;
}

// async 16B global -> LDS (direct). LDS dest = wave-uniform base + lane*16.
__device__ __forceinline__ void gl16(const u16* g, u16* l){
  __builtin_amdgcn_global_load_lds(
      (const __attribute__((address_space(1))) void*)g,
      (__attribute__((address_space(3))) void*)l, 16, 0, 0);
}

// ---------------- diagnostic fallback: zero d_out (f32) ----------------------
__global__ __launch_bounds__(256) void zero_out(float* out, int n){
  for (int i = blockIdx.x * 256 + threadIdx.x; i < n; i += 256 * 4096) out[i] = 0.f;
}

// ---------------- f32 -> bf16 bulk convert (8 elems/thread) ------------------
__global__ __launch_bounds__(256) void cvt_bf16(
    const float* __restrict__ in, u16* __restrict__ out)
{
  const size_t i = ((size_t)blockIdx.x * 256 + threadIdx.x) * 8;
  f32x4 a = *(const f32x4*)&in[i];
  f32x4 b = *(const f32x4*)&in[i + 4];
  u16x8 o;
  #pragma unroll
  for (int j = 0; j < 4; ++j){ o[j] = f2bf(a[j]); o[4+j] = f2bf(b[j]); }
  *(u16x8*)&out[i] = o;
}

// -------- weight transpose+convert: src f32 [K][N] -> dst bf16 [(off+n)*K+k] --
__global__ __launch_bounds__(256) void transpose_w(
    const float* __restrict__ src, u16* __restrict__ dst, int K, int N, int dstOff)
{
  __shared__ u16 tile[32][33];
  const int bk = blockIdx.x * 32, bn = blockIdx.y * 32;
  const int t = threadIdx.x;
  const int r = t >> 5, c = t & 31;
  #pragma unroll
  for (int p = 0; p < 4; ++p)
    tile[r + p*8][c] = f2bf(src[(size_t)(bk + r + p*8) * N + bn + c]);
  __syncthreads();
  #pragma unroll
  for (int p = 0; p < 4; ++p)
    dst[(size_t)(dstOff + bn + r + p*8) * K + bk + c] = tile[c][r + p*8];
}

// -------- 3-source variant (QKV weights, same shape) via blockIdx.z ----------
__global__ __launch_bounds__(256) void transpose_w3(
    const float* __restrict__ sA, const float* __restrict__ sB,
    const float* __restrict__ sC, u16* __restrict__ dst, int K, int N)
{
  __shared__ u16 tile[32][33];
  const float* src = blockIdx.z == 0 ? sA : (blockIdx.z == 1 ? sB : sC);
  const int dstOff = blockIdx.z * N;
  const int bk = blockIdx.x * 32, bn = blockIdx.y * 32;
  const int t = threadIdx.x;
  const int r = t >> 5, c = t & 31;
  #pragma unroll
  for (int p = 0; p < 4; ++p)
    tile[r + p*8][c] = f2bf(src[(size_t)(bk + r + p*8) * N + bn + c]);
  __syncthreads();
  #pragma unroll
  for (int p = 0; p < 4; ++p)
    dst[(size_t)(dstOff + bn + r + p*8) * K + bk + c] = tile[c][r + p*8];
}

// ---- GEMM 256x256, BK=64, 8 waves, dbuf LDS, quadrant-phase schedule -------
// REVERTED to the r10 schedule (best measured: 67.4us final GEMM, MfmaUtil 40%).
// C = A[M,K] @ BT[N,:]^T. A split at ksplit between A0/A1 (row stride Astride).
// BT row stride = Bld. ACC: out += result (pass bias=null).
// LDS per buf: A[256][64] @0, B[256][64] @16384 elems; slot sl of row r holds
// global chunk sl^(r&7) (zero-conflict frag reads); gl16 dest linear.
// Per K-tile: 4 quadrant phases (frag reuse) + 1 half-tile stage per phase;
// entry wait = counted vmcnt(2) (issued one full K-tile earlier), 2 barriers.
template<int RELU, int OF32, int ACC>
__global__ __launch_bounds__(512, 2) void gemm256(
    const u16* __restrict__ A0, const u16* __restrict__ A1,
    int Astride, int ksplit,
    const u16* __restrict__ BT, int Bld, int M, int N, int K,
    const float* __restrict__ bias, void* __restrict__ outv, int out_ld)
{
  __shared__ u16 lds[2*32768];           // 128 KiB
  const int tid  = threadIdx.x;
  const int lane = tid & 63;
  const int wid  = tid >> 6;             // 0..7
  const int wm = wid >> 2, wn = wid & 3; // 2M x 4N waves
  const int l15 = lane & 15, l4 = lane >> 4;
  const int m0 = blockIdx.x * 256, n0 = blockIdx.y * 256;

  f32x4 acc[8][4];
  #pragma unroll
  for (int i = 0; i < 8; ++i)
    #pragma unroll
    for (int j = 0; j < 4; ++j)
      acc[i][j] = (f32x4){0.f, 0.f, 0.f, 0.f};

  // staging: half-tile = 128 rows x 8 slots = 1024 slots; thread -> s0, s1
  const int s0 = tid, s1 = tid + 512;
  const int r0 = s0 >> 3, g0 = (s0 & 7) ^ (r0 & 7);
  const int r1 = s1 >> 3, g1 = (s1 & 7) ^ (r1 & 7);

  const int nt = K >> 6;

  auto stageA = [&](int kt, int h, int buf){
    const int kb = kt * 64;
    const u16* Ab = A0; int kl = kb;
    if (kb >= ksplit){ Ab = A1; kl = kb - ksplit; }
    u16* dst = &lds[buf*32768 + h*8192];
    gl16(&Ab[(size_t)(m0 + h*128 + r0) * Astride + kl + g0*8], &dst[s0*8]);
    gl16(&Ab[(size_t)(m0 + h*128 + r1) * Astride + kl + g1*8], &dst[s1*8]);
  };
  auto stageB = [&](int kt, int h, int buf){
    const int kb = kt * 64;
    u16* dst = &lds[buf*32768 + 16384 + h*8192];
    gl16(&BT[(size_t)(n0 + h*128 + r0) * Bld + kb + g0*8], &dst[s0*8]);
    gl16(&BT[(size_t)(n0 + h*128 + r1) * Bld + kb + g1*8], &dst[s1*8]);
  };
  auto lda = [&](int i, int kc, int buf) -> bf16x8 {
    const int r = wm*128 + i*16 + l15;
    const int c = (kc*4 + l4) ^ (r & 7);
    return *(const bf16x8*)&lds[buf*32768 + r*64 + c*8];
  };
  auto ldb = [&](int j, int kc, int buf) -> bf16x8 {
    const int r = wn*64 + j*16 + l15;
    const int c = (kc*4 + l4) ^ (r & 7);
    return *(const bf16x8*)&lds[buf*32768 + 16384 + r*64 + c*8];
  };

  // prologue: stage tile 0 fully (8 loads)
  stageA(0, 0, 0); stageA(0, 1, 0); stageB(0, 0, 0); stageB(0, 1, 0);

  for (int t = 0; t < nt; ++t){
    const int buf = t & 1, nbuf = buf ^ 1;
    const bool pf = (t + 1 < nt);
    if (pf){
      stageA(t+1, 0, nbuf);
      asm volatile("s_waitcnt vmcnt(2)" ::: "memory");  // tile t's 8 landed
    } else {
      asm volatile("s_waitcnt vmcnt(0)" ::: "memory");
    }
    __builtin_amdgcn_sched_barrier(0);
    __builtin_amdgcn_s_barrier();          // all waves' tile-t loads landed
    __builtin_amdgcn_sched_barrier(0);

    bf16x8 a_[4][2], b_[2][2];
    // ---- Q0: A-lo x B-lo ----
    #pragma unroll
    for (int i = 0; i < 4; ++i){ a_[i][0] = lda(i, 0, buf); a_[i][1] = lda(i, 1, buf); }
    #pragma unroll
    for (int j = 0; j < 2; ++j){ b_[j][0] = ldb(j, 0, buf); b_[j][1] = ldb(j, 1, buf); }
    if (pf) stageA(t+1, 1, nbuf);
    __builtin_amdgcn_s_setprio(1);
    #pragma unroll
    for (int i = 0; i < 4; ++i)
      #pragma unroll
      for (int j = 0; j < 2; ++j){
        acc[i][j] = __builtin_amdgcn_mfma_f32_16x16x32_bf16(a_[i][0], b_[j][0], acc[i][j], 0,0,0);
        acc[i][j] = __builtin_amdgcn_mfma_f32_16x16x32_bf16(a_[i][1], b_[j][1], acc[i][j], 0,0,0);
      }
    __builtin_amdgcn_s_setprio(0);
    // ---- Q1: A-lo x B-hi ----
    #pragma unroll
    for (int j = 0; j < 2; ++j){ b_[j][0] = ldb(2+j, 0, buf); b_[j][1] = ldb(2+j, 1, buf); }
    if (pf) stageB(t+1, 0, nbuf);
    __builtin_amdgcn_s_setprio(1);
    #pragma unroll
    for (int i = 0; i < 4; ++i)
      #pragma unroll
      for (int j = 0; j < 2; ++j){
        acc[i][2+j] = __builtin_amdgcn_mfma_f32_16x16x32_bf16(a_[i][0], b_[j][0], acc[i][2+j], 0,0,0);
        acc[i][2+j] = __builtin_amdgcn_mfma_f32_16x16x32_bf16(a_[i][1], b_[j][1], acc[i][2+j], 0,0,0);
      }
    __builtin_amdgcn_s_setprio(0);
    // ---- Q2: A-hi x B-hi ----
    #pragma unroll
    for (int i = 0; i < 4; ++i){ a_[i][0] = lda(4+i, 0, buf); a_[i][1] = lda(4+i, 1, buf); }
    if (pf) stageB(t+1, 1, nbuf);
    __builtin_amdgcn_s_setprio(1);
    #pragma unroll
    for (int i = 0; i < 4; ++i)
      #pragma unroll
      for (int j = 0; j < 2; ++j){
        acc[4+i][2+j] = __builtin_amdgcn_mfma_f32_16x16x32_bf16(a_[i][0], b_[j][0], acc[4+i][2+j], 0,0,0);
        acc[4+i][2+j] = __builtin_amdgcn_mfma_f32_16x16x32_bf16(a_[i][1], b_[j][1], acc[4+i][2+j], 0,0,0);
      }
    __builtin_amdgcn_s_setprio(0);
    // ---- Q3: A-hi x B-lo (re-read b_lo) ----
    #pragma unroll
    for (int j = 0; j < 2; ++j){ b_[j][0] = ldb(j, 0, buf); b_[j][1] = ldb(j, 1, buf); }
    __builtin_amdgcn_s_setprio(1);
    #pragma unroll
    for (int i = 0; i < 4; ++i)
      #pragma unroll
      for (int j = 0; j < 2; ++j){
        acc[4+i][j] = __builtin_amdgcn_mfma_f32_16x16x32_bf16(a_[i][0], b_[j][0], acc[4+i][j], 0,0,0);
        acc[4+i][j] = __builtin_amdgcn_mfma_f32_16x16x32_bf16(a_[i][1], b_[j][1], acc[4+i][j], 0,0,0);
      }
    __builtin_amdgcn_s_setprio(0);

    __builtin_amdgcn_sched_barrier(0);
    __builtin_amdgcn_s_barrier();          // all reads of buf done
    __builtin_amdgcn_sched_barrier(0);
  }

  // epilogue: C[row][col], row=(lane>>4)*4+r, col=lane&15 (m89-verified)
  const int rb = m0 + wm*128 + l4*4;
  const int cb = n0 + wn*64 + l15;
  #pragma unroll
  for (int i = 0; i < 8; ++i){
    #pragma unroll
    for (int j = 0; j < 4; ++j){
      const int col = cb + j*16;
      const float badd = bias ? bias[col] : 0.f;
      #pragma unroll
      for (int r = 0; r < 4; ++r){
        const int row = rb + i*16 + r;
        float y = acc[i][j][r] + badd;
        if (RELU) y = y > 0.f ? y : 0.f;
        if (OF32){
          float* po = &((float*)outv)[(size_t)row * out_ld + col];
          if (ACC) y += *po;
          *po = y;
        } else {
          u16* po = &((u16*)outv)[(size_t)row * out_ld + col];
          if (ACC) y += bf2f(*po);
          *po = f2bf(y);
        }
      }
    }
  }
}

// -------- mask pack: bit k of mb[row][c] = mask(row, c*64+k) -----------------
__global__ __launch_bounds__(256) void mask_pack(
    const int* __restrict__ slf, const int* __restrict__ adj,
    u64* __restrict__ mb_g, u64* __restrict__ mb_l)
{
  const int idx  = blockIdx.x * 4 + (threadIdx.x >> 6);  // (row, c) pair
  const int lane = threadIdx.x & 63;
  const size_t mi = (size_t)(idx >> 2) * 256 + (size_t)(idx & 3) * 64 + lane;
  const bool g = slf[mi] != 0;
  const bool l = g || (adj[mi] == 0);
  const u64 bg = __ballot(g);
  const u64 bl = __ballot(l);
  if (lane == 0){ mb_g[idx] = bg; mb_l[idx] = bl; }
}

// ---------------- MFMA flash attention ---------------------------------------
// block = (b_loc, h, qtile of 128 rows); 4 waves x 32 q-rows.
// qkv: half-local [8192][1536]; q @ h*64, k @ 512+h*64, v @ 1024+h*64.
__global__ __launch_bounds__(256) void attn_mfma(
    const u16* __restrict__ qkv, const u64* __restrict__ mb,
    int boff, u16* __restrict__ out)
{
  __shared__ u16 kbuf[64*64];     // [key][dim], swizzled col ^= (key&7)<<3
  __shared__ u16 vtbuf[64*64];    // [dim][key], swizzled col ^= (dim&7)<<3
  __shared__ u16 pbuf[4][32*64];  // per-wave P [row][key], swizzled

  const int b_loc = blockIdx.x >> 4;
  const int h     = (blockIdx.x >> 1) & 7;
  const int qt    = blockIdx.x & 1;
  const int b     = boff + b_loc;
  const int t     = threadIdx.x;
  const int w     = t >> 6, lane = t & 63;
  const int l15   = lane & 15, l4 = lane >> 4;

  bf16x8 qf[2][2];
  {
    const int rbase = b_loc*256 + qt*128 + w*32;
    #pragma unroll
    for (int i = 0; i < 2; ++i)
      #pragma unroll
      for (int kc = 0; kc < 2; ++kc)
        qf[i][kc] = *(const bf16x8*)&qkv[(size_t)(rbase + i*16 + l15)*1536 + h*64 + kc*32 + l4*8];
  }

  f32x4 acc_o[2][4];
  float m_[2][4], l_[2][4];
  #pragma unroll
  for (int i = 0; i < 2; ++i){
    #pragma unroll
    for (int j = 0; j < 4; ++j) acc_o[i][j] = (f32x4){0.f,0.f,0.f,0.f};
    #pragma unroll
    for (int r = 0; r < 4; ++r){ m_[i][r] = -1e30f; l_[i][r] = 0.f; }
  }

  for (int c = 0; c < 4; ++c){
    __syncthreads();
    {   // stage K and V^T (swizzled); thread -> key row t>>2, dim group (t&3)*16
      const int kr = t >> 2, dg = (t & 3) * 16;
      const size_t rbase = (size_t)(b_loc*256 + c*64 + kr)*1536 + h*64 + dg;
      u16x8 k0 = *(const u16x8*)&qkv[rbase + 512];
      u16x8 k1 = *(const u16x8*)&qkv[rbase + 512 + 8];
      u16x8 v0 = *(const u16x8*)&qkv[rbase + 1024];
      u16x8 v1 = *(const u16x8*)&qkv[rbase + 1024 + 8];
      const int sw = (kr & 7) << 3;
      *(u16x8*)&kbuf[kr*64 + (dg ^ sw)]       = k0;
      *(u16x8*)&kbuf[kr*64 + ((dg + 8) ^ sw)] = k1;
      #pragma unroll
      for (int e = 0; e < 8; ++e){
        const int d0 = dg + e, d1 = dg + 8 + e;
        vtbuf[d0*64 + (kr ^ ((d0 & 7) << 3))] = v0[e];
        vtbuf[d1*64 + (kr ^ ((d1 & 7) << 3))] = v1[e];
      }
    }
    __syncthreads();

    bf16x8 kfr[4][2];
    #pragma unroll
    for (int jb = 0; jb < 4; ++jb){
      const int key = jb*16 + l15;
      const int sw = (key & 7) << 3;
      #pragma unroll
      for (int kc = 0; kc < 2; ++kc)
        kfr[jb][kc] = *(const bf16x8*)&kbuf[key*64 + ((kc*32 + l4*8) ^ sw)];
    }
    f32x4 s_[2][4];
    #pragma unroll
    for (int i = 0; i < 2; ++i)
      #pragma unroll
      for (int jb = 0; jb < 4; ++jb){
        f32x4 a = (f32x4){0.f,0.f,0.f,0.f};
        a = __builtin_amdgcn_mfma_f32_16x16x32_bf16(qf[i][0], kfr[jb][0], a, 0,0,0);
        a = __builtin_amdgcn_mfma_f32_16x16x32_bf16(qf[i][1], kfr[jb][1], a, 0,0,0);
        s_[i][jb] = a;
      }

    #pragma unroll
    for (int i = 0; i < 2; ++i){
      #pragma unroll
      for (int r = 0; r < 4; ++r){
        const int prow = i*16 + l4*4 + r;
        const int qrow = qt*128 + w*32 + prow;
        const u64 bits = mb[((size_t)b*256 + qrow)*4 + c];
        float sv[4];
        #pragma unroll
        for (int jb = 0; jb < 4; ++jb){
          float xv = s_[i][jb][r] * 0.125f;
          if ((bits >> (jb*16 + l15)) & 1ull) xv = -1e9f;
          sv[jb] = xv;
        }
        float mx = fmaxf(fmaxf(sv[0], sv[1]), fmaxf(sv[2], sv[3]));
        #pragma unroll
        for (int d = 1; d < 16; d <<= 1)
          mx = fmaxf(mx, __shfl_xor(mx, d, 64));
        const float mnew = fmaxf(m_[i][r], mx);
        const float corr = __expf(m_[i][r] - mnew);
        m_[i][r] = mnew;
        float ps = 0.f;
        const int swp = (prow & 7) << 3;
        #pragma unroll
        for (int jb = 0; jb < 4; ++jb){
          const float p = __expf(sv[jb] - mnew);
          ps += p;
          pbuf[w][prow*64 + ((jb*16 + l15) ^ swp)] = f2bf(p);
        }
        #pragma unroll
        for (int d = 1; d < 16; d <<= 1)
          ps += __shfl_xor(ps, d, 64);
        l_[i][r] = l_[i][r] * corr + ps;
        #pragma unroll
        for (int j2 = 0; j2 < 4; ++j2) acc_o[i][j2][r] *= corr;
      }
    }

    bf16x8 vfr[4][2];
    #pragma unroll
    for (int j2 = 0; j2 < 4; ++j2){
      const int dim = j2*16 + l15;
      const int sw = (dim & 7) << 3;
      #pragma unroll
      for (int kc = 0; kc < 2; ++kc)
        vfr[j2][kc] = *(const bf16x8*)&vtbuf[dim*64 + ((kc*32 + l4*8) ^ sw)];
    }
    #pragma unroll
    for (int i = 0; i < 2; ++i){
      const int prow = i*16 + l15;
      const int swp = (prow & 7) << 3;
      bf16x8 pa0 = *(const bf16x8*)&pbuf[w][prow*64 + ((l4*8) ^ swp)];
      bf16x8 pa1 = *(const bf16x8*)&pbuf[w][prow*64 + ((32 + l4*8) ^ swp)];
      #pragma unroll
      for (int j2 = 0; j2 < 4; ++j2){
        acc_o[i][j2] = __builtin_amdgcn_mfma_f32_16x16x32_bf16(pa0, vfr[j2][0], acc_o[i][j2], 0,0,0);
        acc_o[i][j2] = __builtin_amdgcn_mfma_f32_16x16x32_bf16(pa1, vfr[j2][1], acc_o[i][j2], 0,0,0);
      }
    }
  }

  #pragma unroll
  for (int i = 0; i < 2; ++i){
    #pragma unroll
    for (int r = 0; r < 4; ++r){
      const int qrow = qt*128 + w*32 + i*16 + l4*4 + r;
      const float inv = 1.f / l_[i][r];
      const size_t ob = ((size_t)b*256 + qrow)*512 + h*64;
      #pragma unroll
      for (int j2 = 0; j2 < 4; ++j2)
        out[ob + j2*16 + l15] = f2bf(acc_o[i][j2][r] * inv);
    }
  }
}

// -------- fused residual + LayerNorm + npm (v2: wave-per-row, no LDS) --------
// a bf16, res f32|bf16, out bf16. 4 rows/block, 64 lanes x 16 elems each.
// In-place (out == a) safe: each lane reads its 16 elems before writing them.
template<int RF32>
__global__ __launch_bounds__(256) void ln_fused(
    const u16* a, const void* __restrict__ res,
    const float* __restrict__ sc, const float* __restrict__ bs,
    const float* __restrict__ npm, u16* out)
{
  const int w = threadIdx.x >> 6, lane = threadIdx.x & 63;
  const int row = blockIdx.x * 4 + w;
  const size_t bse = (size_t)row * 1024 + lane * 16;

  u16x8 av0 = *(const u16x8*)&a[bse];
  u16x8 av1 = *(const u16x8*)&a[bse + 8];
  float rv[16];
  if (RF32){
    const float* rp = (const float*)res + bse;
    #pragma unroll
    for (int j = 0; j < 16; j += 4){
      f32x4 q = *(const f32x4*)&rp[j];
      rv[j] = q[0]; rv[j+1] = q[1]; rv[j+2] = q[2]; rv[j+3] = q[3];
    }
  } else {
    const u16* rp = (const u16*)res + bse;
    u16x8 q0 = *(const u16x8*)rp;
    u16x8 q1 = *(const u16x8*)(rp + 8);
    #pragma unroll
    for (int j = 0; j < 8; ++j){ rv[j] = bf2f(q0[j]); rv[8+j] = bf2f(q1[j]); }
  }

  float vv[16]; float s = 0.f, sq = 0.f;
  #pragma unroll
  for (int j = 0; j < 8; ++j){
    vv[j]   = bf2f(av0[j]) + rv[j];
    vv[8+j] = bf2f(av1[j]) + rv[8+j];
  }
  #pragma unroll
  for (int j = 0; j < 16; ++j){ s += vv[j]; sq += vv[j]*vv[j]; }
  #pragma unroll
  for (int i = 1; i < 64; i <<= 1){
    s  += __shfl_xor(s,  i, 64);
    sq += __shfl_xor(sq, i, 64);
  }
  const float mean = s * (1.f/1024.f);
  const float var  = sq * (1.f/1024.f) - mean*mean;
  const float rstd = rsqrtf(var + 1e-5f);
  const float nm   = npm[row];

  u16x8 o0, o1;
  #pragma unroll
  for (int j = 0; j < 8; ++j){
    const int c0 = lane*16 + j, c1 = c0 + 8;
    o0[j] = f2bf(((vv[j]   - mean) * rstd * sc[c0] + bs[c0]) * nm);
    o1[j] = f2bf(((vv[8+j] - mean) * rstd * sc[c1] + bs[c1]) * nm);
  }
  *(u16x8*)&out[bse]     = o0;
  *(u16x8*)&out[bse + 8] = o1;
}

// ---------------- launcher ---------------------------------------------------
extern "C" void kernel_launch(void* const* d_in, const int* in_sizes, int n_in,
                              void* d_out, int out_size, void* d_ws, size_t ws_size,
                              hipStream_t stream)
{
  // ws (u16 el), 112 MiB (proven):
  //  W  [0, 8388608): wqkvT|woT|w1T|w2T|fcT
  //  R1 [8388608, 25165824):  xbf (phase1) -> tmp -> xl (phase2, in-place LN)
  //  R2 [25165824, 41943040): qkvh [8192][1536] (phase1) -> ln1 (phase2)
  //  R3 [41943040, 58720256): xg  (written once, layer-0 end; nothing aliases)
  // d_out (u16): attnb0 [0,8388608) | attnb1 [8388608,16777216)
  //   phase1: mb_g/mb_l @ 16777216 | phase2: hbufA [16777216,33554432)
  const size_t NEED = 58720256ull * 2ull;
  if (ws_size < NEED){
    zero_out<<<4096, 256, 0, stream>>>((float*)d_out, out_size);
    return;
  }

  const float* x   = (const float*)d_in[0];
  const int*   adj = (const int*)d_in[1];
  const float* npm = (const float*)d_in[2];
  const int*   slf = (const int*)d_in[3];
  const float* fcw = (const float*)d_in[30];
  const float* fcb = (const float*)d_in[31];

  u16* ws    = (u16*)d_ws;
  u16* wqkvT = ws;
  u16* woT   = ws + 1572864;
  u16* w1T   = ws + 2097152;
  u16* w2T   = ws + 4194304;
  u16* fcT   = ws + 6291456;
  u16* xbf   = ws + 8388608;           // R1: [16384][1024] bf16, then tmp/xl
  u16* tmp   = ws + 8388608;
  u16* qkvh  = ws + 25165824;          // R2: [8192][1536], then ln1
  u16* ln1   = ws + 25165824;
  u16* xg    = ws + 41943040;          // R3 (exclusive)

  u16* dout16 = (u16*)d_out;
  u16* attnb0 = dout16;                // [16384][512]
  u16* attnb1 = dout16 + 8388608;      // [16384][512]
  u16* hbufA  = dout16 + 16777216;     // [16384][1024] (phase2 only)
  u64* mb_g   = (u64*)(dout16 + 16777216);   // phase1 only (hbufA window)
  u64* mb_l   = mb_g + 65536;

  cvt_bf16<<<8192, 256, 0, stream>>>(x, xbf);
  mask_pack<<<16384, 256, 0, stream>>>(slf, adj, mb_g, mb_l);
  transpose_w<<<dim3(64, 32), 256, 0, stream>>>(fcw, fcT, 2048, 1024, 0);

  // Phase 1: both layers' QKV + attention (xbf + masks live throughout)
  for (int L = 0; L < 2; ++L){
    const int bi = 4 + L*13;
    transpose_w3<<<dim3(32, 16, 3), 256, 0, stream>>>(
        (const float*)d_in[bi+0], (const float*)d_in[bi+1],
        (const float*)d_in[bi+2], wqkvT, 1024, 512);
    u16* attnb = L ? attnb1 : attnb0;
    for (int hf = 0; hf < 2; ++hf){
      const u16* xh = xbf + (size_t)hf*8192*1024;
      gemm256<0,0,0><<<dim3(32, 6), 512, 0, stream>>>(
          xh, xh, 1024, 1024, wqkvT, 1024, 8192, 1536, 1024, nullptr, qkvh, 1536);
      attn_mfma<<<512, 256, 0, stream>>>(qkvh, L ? mb_l : mb_g, hf*32, attnb);
    }
  }

  // Phase 2: layer bodies (xbf/masks dead; tmp R1, ln1 R2, hbufA in d_out)
  for (int L = 0; L < 2; ++L){
    const int bi = 4 + L*13;
    const float* bo  = (const float*)d_in[bi+4];
    const float* l1s = (const float*)d_in[bi+5];
    const float* l1b = (const float*)d_in[bi+6];
    const float* b1  = (const float*)d_in[bi+8];
    const float* b2  = (const float*)d_in[bi+10];
    const float* l2s = (const float*)d_in[bi+11];
    const float* l2b = (const float*)d_in[bi+12];

    transpose_w<<<dim3(16, 32), 256, 0, stream>>>((const float*)d_in[bi+3], woT, 512, 1024, 0);
    transpose_w<<<dim3(32, 64), 256, 0, stream>>>((const float*)d_in[bi+7], w1T, 1024, 2048, 0);
    transpose_w<<<dim3(64, 32), 256, 0, stream>>>((const float*)d_in[bi+9], w2T, 2048, 1024, 0);

    const u16* attnb = L ? attnb1 : attnb0;
    // out-proj + bo -> tmp
    gemm256<0,0,0><<<dim3(64, 4), 512, 0, stream>>>(
        attnb, attnb, 512, 512, woT, 512, 16384, 1024, 512, bo, tmp, 1024);
    // ln1 = LN(tmp + x) * npm -> R2
    ln_fused<1><<<4096, 256, 0, stream>>>(tmp, x, l1s, l1b, npm, ln1);
    // FFN: two N-halves of w1 through hbufA, K-accumulated into tmp
    for (int hh = 0; hh < 2; ++hh){
      gemm256<1,0,0><<<dim3(64, 4), 512, 0, stream>>>(
          ln1, ln1, 1024, 1024, w1T + (size_t)hh*1024*1024, 1024,
          16384, 1024, 1024, b1 + hh*1024, hbufA, 1024);
      if (hh == 0)
        gemm256<0,0,0><<<dim3(64, 4), 512, 0, stream>>>(
            hbufA, hbufA, 1024, 1024, w2T, 2048, 16384, 1024, 1024, b2, tmp, 1024);
      else
        gemm256<0,0,1><<<dim3(64, 4), 512, 0, stream>>>(
            hbufA, hbufA, 1024, 1024, w2T + 1024, 2048, 16384, 1024, 1024,
            nullptr, tmp, 1024);
    }
    // xout = LN(tmp + ln1) * npm; layer0 -> xg, layer1 -> in-place (xl = tmp)
    ln_fused<0><<<4096, 256, 0, stream>>>(tmp, ln1, l2s, l2b, npm, L ? tmp : xg);
  }

  // final: [xg | xl] @ fcT + fc_b -> d_out (f32), K split at 1024
  gemm256<0,1,0><<<dim3(64, 4), 512, 0, stream>>>(
      xg, tmp, 1024, 1024, fcT, 2048, 16384, 1024, 2048, fcb, d_out, 1024);
}

// Round 15
// 733.217 us; speedup vs baseline: 1.1756x; 1.0859x over previous
//
#include <hip/hip_runtime.h>

// GLAT: B=64, N=256, D=1024, H=8, DK=64, DI=2048.
// I/O dtype: float32. Internal: bf16 MFMA + f32 accum. adj/slf: int32.

typedef unsigned short u16;
typedef unsigned long long u64;
typedef __bf16 bf16_t;
typedef bf16_t bf16x8 __attribute__((ext_vector_type(8)));
typedef float  f32x4  __attribute__((ext_vector_type(4)));
typedef u16    u16x8  __attribute__((ext_vector_type(8)));
typedef u16    u16x4  __attribute__((ext_vector_type(4)));

__device__ __forceinline__ float bf2f(u16 u){
  union { unsigned int i; float f; } c; c.i = ((unsigned int)u) << 16; return c.f;
}
__device__ __forceinline__ u16 f2bf(float f){
  union { float f; unsigned int u; } c; c.f = f;
  unsigned int u = c.u;
  unsigned int r = (u + 0x7fffu + ((u >> 16) & 1u)) >> 16;  // RNE
  return (u16)r;
}

// async 16B global -> LDS (direct). LDS dest = wave-uniform base + lane*16.
__device__ __forceinline__ void gl16(const u16* g, u16* l){
  __builtin_amdgcn_global_load_lds(
      (const __attribute__((address_space(1))) void*)g,
      (__attribute__((address_space(3))) void*)l, 16, 0, 0);
}

// ---------------- diagnostic fallback: zero d_out (f32) ----------------------
__global__ __launch_bounds__(256) void zero_out(float* out, int n){
  for (int i = blockIdx.x * 256 + threadIdx.x; i < n; i += 256 * 4096) out[i] = 0.f;
}

// ---------------- f32 -> bf16 bulk convert (8 elems/thread) ------------------
__global__ __launch_bounds__(256) void cvt_bf16(
    const float* __restrict__ in, u16* __restrict__ out)
{
  const size_t i = ((size_t)blockIdx.x * 256 + threadIdx.x) * 8;
  f32x4 a = *(const f32x4*)&in[i];
  f32x4 b = *(const f32x4*)&in[i + 4];
  u16x8 o;
  #pragma unroll
  for (int j = 0; j < 4; ++j){ o[j] = f2bf(a[j]); o[4+j] = f2bf(b[j]); }
  *(u16x8*)&out[i] = o;
}

// -------- weight transpose+convert: src f32 [K][N] -> dst bf16 [(off+n)*K+k] --
__global__ __launch_bounds__(256) void transpose_w(
    const float* __restrict__ src, u16* __restrict__ dst, int K, int N, int dstOff)
{
  __shared__ u16 tile[32][33];
  const int bk = blockIdx.x * 32, bn = blockIdx.y * 32;
  const int t = threadIdx.x;
  const int r = t >> 5, c = t & 31;
  #pragma unroll
  for (int p = 0; p < 4; ++p)
    tile[r + p*8][c] = f2bf(src[(size_t)(bk + r + p*8) * N + bn + c]);
  __syncthreads();
  #pragma unroll
  for (int p = 0; p < 4; ++p)
    dst[(size_t)(dstOff + bn + r + p*8) * K + bk + c] = tile[c][r + p*8];
}

// -------- 3-source variant (QKV weights, same shape) via blockIdx.z ----------
__global__ __launch_bounds__(256) void transpose_w3(
    const float* __restrict__ sA, const float* __restrict__ sB,
    const float* __restrict__ sC, u16* __restrict__ dst, int K, int N)
{
  __shared__ u16 tile[32][33];
  const float* src = blockIdx.z == 0 ? sA : (blockIdx.z == 1 ? sB : sC);
  const int dstOff = blockIdx.z * N;
  const int bk = blockIdx.x * 32, bn = blockIdx.y * 32;
  const int t = threadIdx.x;
  const int r = t >> 5, c = t & 31;
  #pragma unroll
  for (int p = 0; p < 4; ++p)
    tile[r + p*8][c] = f2bf(src[(size_t)(bk + r + p*8) * N + bn + c]);
  __syncthreads();
  #pragma unroll
  for (int p = 0; p < 4; ++p)
    dst[(size_t)(dstOff + bn + r + p*8) * K + bk + c] = tile[c][r + p*8];
}

// ---- GEMM 256x256, BK=64, 8 waves, dbuf LDS, quadrant-phase schedule -------
// r10 schedule, FROZEN (best measured: ~67-70us final GEMM, MfmaUtil ~40%).
// C = A[M,K] @ BT[N,:]^T. A split at ksplit between A0/A1 (row stride Astride).
// BT row stride = Bld. ACC: out += result (pass bias=null).
// LDS per buf: A[256][64] @0, B[256][64] @16384 elems; slot sl of row r holds
// global chunk sl^(r&7) (zero-conflict frag reads); gl16 dest linear.
template<int RELU, int OF32, int ACC>
__global__ __launch_bounds__(512, 2) void gemm256(
    const u16* __restrict__ A0, const u16* __restrict__ A1,
    int Astride, int ksplit,
    const u16* __restrict__ BT, int Bld, int M, int N, int K,
    const float* __restrict__ bias, void* __restrict__ outv, int out_ld)
{
  __shared__ u16 lds[2*32768];           // 128 KiB
  const int tid  = threadIdx.x;
  const int lane = tid & 63;
  const int wid  = tid >> 6;             // 0..7
  const int wm = wid >> 2, wn = wid & 3; // 2M x 4N waves
  const int l15 = lane & 15, l4 = lane >> 4;
  const int m0 = blockIdx.x * 256, n0 = blockIdx.y * 256;

  f32x4 acc[8][4];
  #pragma unroll
  for (int i = 0; i < 8; ++i)
    #pragma unroll
    for (int j = 0; j < 4; ++j)
      acc[i][j] = (f32x4){0.f, 0.f, 0.f, 0.f};

  const int s0 = tid, s1 = tid + 512;
  const int r0 = s0 >> 3, g0 = (s0 & 7) ^ (r0 & 7);
  const int r1 = s1 >> 3, g1 = (s1 & 7) ^ (r1 & 7);

  const int nt = K >> 6;

  auto stageA = [&](int kt, int h, int buf){
    const int kb = kt * 64;
    const u16* Ab = A0; int kl = kb;
    if (kb >= ksplit){ Ab = A1; kl = kb - ksplit; }
    u16* dst = &lds[buf*32768 + h*8192];
    gl16(&Ab[(size_t)(m0 + h*128 + r0) * Astride + kl + g0*8], &dst[s0*8]);
    gl16(&Ab[(size_t)(m0 + h*128 + r1) * Astride + kl + g1*8], &dst[s1*8]);
  };
  auto stageB = [&](int kt, int h, int buf){
    const int kb = kt * 64;
    u16* dst = &lds[buf*32768 + 16384 + h*8192];
    gl16(&BT[(size_t)(n0 + h*128 + r0) * Bld + kb + g0*8], &dst[s0*8]);
    gl16(&BT[(size_t)(n0 + h*128 + r1) * Bld + kb + g1*8], &dst[s1*8]);
  };
  auto lda = [&](int i, int kc, int buf) -> bf16x8 {
    const int r = wm*128 + i*16 + l15;
    const int c = (kc*4 + l4) ^ (r & 7);
    return *(const bf16x8*)&lds[buf*32768 + r*64 + c*8];
  };
  auto ldb = [&](int j, int kc, int buf) -> bf16x8 {
    const int r = wn*64 + j*16 + l15;
    const int c = (kc*4 + l4) ^ (r & 7);
    return *(const bf16x8*)&lds[buf*32768 + 16384 + r*64 + c*8];
  };

  // prologue: stage tile 0 fully (8 loads)
  stageA(0, 0, 0); stageA(0, 1, 0); stageB(0, 0, 0); stageB(0, 1, 0);

  for (int t = 0; t < nt; ++t){
    const int buf = t & 1, nbuf = buf ^ 1;
    const bool pf = (t + 1 < nt);
    if (pf){
      stageA(t+1, 0, nbuf);
      asm volatile("s_waitcnt vmcnt(2)" ::: "memory");  // tile t's 8 landed
    } else {
      asm volatile("s_waitcnt vmcnt(0)" ::: "memory");
    }
    __builtin_amdgcn_sched_barrier(0);
    __builtin_amdgcn_s_barrier();          // all waves' tile-t loads landed
    __builtin_amdgcn_sched_barrier(0);

    bf16x8 a_[4][2], b_[2][2];
    // ---- Q0: A-lo x B-lo ----
    #pragma unroll
    for (int i = 0; i < 4; ++i){ a_[i][0] = lda(i, 0, buf); a_[i][1] = lda(i, 1, buf); }
    #pragma unroll
    for (int j = 0; j < 2; ++j){ b_[j][0] = ldb(j, 0, buf); b_[j][1] = ldb(j, 1, buf); }
    if (pf) stageA(t+1, 1, nbuf);
    __builtin_amdgcn_s_setprio(1);
    #pragma unroll
    for (int i = 0; i < 4; ++i)
      #pragma unroll
      for (int j = 0; j < 2; ++j){
        acc[i][j] = __builtin_amdgcn_mfma_f32_16x16x32_bf16(a_[i][0], b_[j][0], acc[i][j], 0,0,0);
        acc[i][j] = __builtin_amdgcn_mfma_f32_16x16x32_bf16(a_[i][1], b_[j][1], acc[i][j], 0,0,0);
      }
    __builtin_amdgcn_s_setprio(0);
    // ---- Q1: A-lo x B-hi ----
    #pragma unroll
    for (int j = 0; j < 2; ++j){ b_[j][0] = ldb(2+j, 0, buf); b_[j][1] = ldb(2+j, 1, buf); }
    if (pf) stageB(t+1, 0, nbuf);
    __builtin_amdgcn_s_setprio(1);
    #pragma unroll
    for (int i = 0; i < 4; ++i)
      #pragma unroll
      for (int j = 0; j < 2; ++j){
        acc[i][2+j] = __builtin_amdgcn_mfma_f32_16x16x32_bf16(a_[i][0], b_[j][0], acc[i][2+j], 0,0,0);
        acc[i][2+j] = __builtin_amdgcn_mfma_f32_16x16x32_bf16(a_[i][1], b_[j][1], acc[i][2+j], 0,0,0);
      }
    __builtin_amdgcn_s_setprio(0);
    // ---- Q2: A-hi x B-hi ----
    #pragma unroll
    for (int i = 0; i < 4; ++i){ a_[i][0] = lda(4+i, 0, buf); a_[i][1] = lda(4+i, 1, buf); }
    if (pf) stageB(t+1, 1, nbuf);
    __builtin_amdgcn_s_setprio(1);
    #pragma unroll
    for (int i = 0; i < 4; ++i)
      #pragma unroll
      for (int j = 0; j < 2; ++j){
        acc[4+i][2+j] = __builtin_amdgcn_mfma_f32_16x16x32_bf16(a_[i][0], b_[j][0], acc[4+i][2+j], 0,0,0);
        acc[4+i][2+j] = __builtin_amdgcn_mfma_f32_16x16x32_bf16(a_[i][1], b_[j][1], acc[4+i][2+j], 0,0,0);
      }
    __builtin_amdgcn_s_setprio(0);
    // ---- Q3: A-hi x B-lo (re-read b_lo) ----
    #pragma unroll
    for (int j = 0; j < 2; ++j){ b_[j][0] = ldb(j, 0, buf); b_[j][1] = ldb(j, 1, buf); }
    __builtin_amdgcn_s_setprio(1);
    #pragma unroll
    for (int i = 0; i < 4; ++i)
      #pragma unroll
      for (int j = 0; j < 2; ++j){
        acc[4+i][j] = __builtin_amdgcn_mfma_f32_16x16x32_bf16(a_[i][0], b_[j][0], acc[4+i][j], 0,0,0);
        acc[4+i][j] = __builtin_amdgcn_mfma_f32_16x16x32_bf16(a_[i][1], b_[j][1], acc[4+i][j], 0,0,0);
      }
    __builtin_amdgcn_s_setprio(0);

    __builtin_amdgcn_sched_barrier(0);
    __builtin_amdgcn_s_barrier();          // all reads of buf done
    __builtin_amdgcn_sched_barrier(0);
  }

  // epilogue: C[row][col], row=(lane>>4)*4+r, col=lane&15 (m89-verified)
  const int rb = m0 + wm*128 + l4*4;
  const int cb = n0 + wn*64 + l15;
  #pragma unroll
  for (int i = 0; i < 8; ++i){
    #pragma unroll
    for (int j = 0; j < 4; ++j){
      const int col = cb + j*16;
      const float badd = bias ? bias[col] : 0.f;
      #pragma unroll
      for (int r = 0; r < 4; ++r){
        const int row = rb + i*16 + r;
        float y = acc[i][j][r] + badd;
        if (RELU) y = y > 0.f ? y : 0.f;
        if (OF32){
          float* po = &((float*)outv)[(size_t)row * out_ld + col];
          if (ACC) y += *po;
          *po = y;
        } else {
          u16* po = &((u16*)outv)[(size_t)row * out_ld + col];
          if (ACC) y += bf2f(*po);
          *po = f2bf(y);
        }
      }
    }
  }
}

// -------- mask pack: bit k of mb[row][c] = mask(row, c*64+k) -----------------
__global__ __launch_bounds__(256) void mask_pack(
    const int* __restrict__ slf, const int* __restrict__ adj,
    u64* __restrict__ mb_g, u64* __restrict__ mb_l)
{
  const int idx  = blockIdx.x * 4 + (threadIdx.x >> 6);  // (row, c) pair
  const int lane = threadIdx.x & 63;
  const size_t mi = (size_t)(idx >> 2) * 256 + (size_t)(idx & 3) * 64 + lane;
  const bool g = slf[mi] != 0;
  const bool l = g || (adj[mi] == 0);
  const u64 bg = __ballot(g);
  const u64 bl = __ballot(l);
  if (lane == 0){ mb_g[idx] = bg; mb_l[idx] = bl; }
}

// ---------------- MFMA flash attention (T13 defer-max) -----------------------
// block = (b_loc, h, qtile of 128 rows); 4 waves x 32 q-rows.
// qkv: half-local [8192][1536]; q @ h*64, k @ 512+h*64, v @ 1024+h*64.
__global__ __launch_bounds__(256) void attn_mfma(
    const u16* __restrict__ qkv, const u64* __restrict__ mb,
    int boff, u16* __restrict__ out)
{
  __shared__ u16 kbuf[64*64];     // [key][dim], swizzled col ^= (key&7)<<3
  __shared__ u16 vtbuf[64*64];    // [dim][key], swizzled col ^= (dim&7)<<3
  __shared__ u16 pbuf[4][32*64];  // per-wave P [row][key], swizzled

  const int b_loc = blockIdx.x >> 4;
  const int h     = (blockIdx.x >> 1) & 7;
  const int qt    = blockIdx.x & 1;
  const int b     = boff + b_loc;
  const int t     = threadIdx.x;
  const int w     = t >> 6, lane = t & 63;
  const int l15   = lane & 15, l4 = lane >> 4;

  bf16x8 qf[2][2];
  {
    const int rbase = b_loc*256 + qt*128 + w*32;
    #pragma unroll
    for (int i = 0; i < 2; ++i)
      #pragma unroll
      for (int kc = 0; kc < 2; ++kc)
        qf[i][kc] = *(const bf16x8*)&qkv[(size_t)(rbase + i*16 + l15)*1536 + h*64 + kc*32 + l4*8];
  }

  f32x4 acc_o[2][4];
  float m_[2][4], l_[2][4];
  #pragma unroll
  for (int i = 0; i < 2; ++i){
    #pragma unroll
    for (int j = 0; j < 4; ++j) acc_o[i][j] = (f32x4){0.f,0.f,0.f,0.f};
    #pragma unroll
    for (int r = 0; r < 4; ++r){ m_[i][r] = -1e30f; l_[i][r] = 0.f; }
  }

  for (int c = 0; c < 4; ++c){
    __syncthreads();
    {   // stage K and V^T (swizzled); thread -> key row t>>2, dim group (t&3)*16
      const int kr = t >> 2, dg = (t & 3) * 16;
      const size_t rbase = (size_t)(b_loc*256 + c*64 + kr)*1536 + h*64 + dg;
      u16x8 k0 = *(const u16x8*)&qkv[rbase + 512];
      u16x8 k1 = *(const u16x8*)&qkv[rbase + 512 + 8];
      u16x8 v0 = *(const u16x8*)&qkv[rbase + 1024];
      u16x8 v1 = *(const u16x8*)&qkv[rbase + 1024 + 8];
      const int sw = (kr & 7) << 3;
      *(u16x8*)&kbuf[kr*64 + (dg ^ sw)]       = k0;
      *(u16x8*)&kbuf[kr*64 + ((dg + 8) ^ sw)] = k1;
      #pragma unroll
      for (int e = 0; e < 8; ++e){
        const int d0 = dg + e, d1 = dg + 8 + e;
        vtbuf[d0*64 + (kr ^ ((d0 & 7) << 3))] = v0[e];
        vtbuf[d1*64 + (kr ^ ((d1 & 7) << 3))] = v1[e];
      }
    }
    __syncthreads();

    bf16x8 kfr[4][2];
    #pragma unroll
    for (int jb = 0; jb < 4; ++jb){
      const int key = jb*16 + l15;
      const int sw = (key & 7) << 3;
      #pragma unroll
      for (int kc = 0; kc < 2; ++kc)
        kfr[jb][kc] = *(const bf16x8*)&kbuf[key*64 + ((kc*32 + l4*8) ^ sw)];
    }
    f32x4 s_[2][4];
    #pragma unroll
    for (int i = 0; i < 2; ++i)
      #pragma unroll
      for (int jb = 0; jb < 4; ++jb){
        f32x4 a = (f32x4){0.f,0.f,0.f,0.f};
        a = __builtin_amdgcn_mfma_f32_16x16x32_bf16(qf[i][0], kfr[jb][0], a, 0,0,0);
        a = __builtin_amdgcn_mfma_f32_16x16x32_bf16(qf[i][1], kfr[jb][1], a, 0,0,0);
        s_[i][jb] = a;
      }

    // scale + mask in place
    #pragma unroll
    for (int i = 0; i < 2; ++i)
      #pragma unroll
      for (int r = 0; r < 4; ++r){
        const int qrow = qt*128 + w*32 + i*16 + l4*4 + r;
        const u64 bits = mb[((size_t)b*256 + qrow)*4 + c];
        #pragma unroll
        for (int jb = 0; jb < 4; ++jb){
          float xv = s_[i][jb][r] * 0.125f;
          if ((bits >> (jb*16 + l15)) & 1ull) xv = -1e9f;
          s_[i][jb][r] = xv;
        }
      }
    // row maxes + defer-max vote (T13, THR=8)
    float mxs[2][4];
    bool okall = true;
    #pragma unroll
    for (int i = 0; i < 2; ++i)
      #pragma unroll
      for (int r = 0; r < 4; ++r){
        float mx = fmaxf(fmaxf(s_[i][0][r], s_[i][1][r]),
                         fmaxf(s_[i][2][r], s_[i][3][r]));
        #pragma unroll
        for (int d = 1; d < 16; d <<= 1)
          mx = fmaxf(mx, __shfl_xor(mx, d, 64));
        mxs[i][r] = mx;
        okall = okall && (mx <= m_[i][r] + 8.f);
      }
    if (__all(okall)){
      // deferred: keep m_old, no O/l rescale (P bounded by e^8)
      #pragma unroll
      for (int i = 0; i < 2; ++i)
        #pragma unroll
        for (int r = 0; r < 4; ++r){
          const int prow = i*16 + l4*4 + r;
          const int swp = (prow & 7) << 3;
          float ps = 0.f;
          #pragma unroll
          for (int jb = 0; jb < 4; ++jb){
            const float p = __expf(s_[i][jb][r] - m_[i][r]);
            ps += p;
            pbuf[w][prow*64 + ((jb*16 + l15) ^ swp)] = f2bf(p);
          }
          #pragma unroll
          for (int d = 1; d < 16; d <<= 1)
            ps += __shfl_xor(ps, d, 64);
          l_[i][r] += ps;
        }
    } else {
      #pragma unroll
      for (int i = 0; i < 2; ++i)
        #pragma unroll
        for (int r = 0; r < 4; ++r){
          const int prow = i*16 + l4*4 + r;
          const float mnew = fmaxf(m_[i][r], mxs[i][r]);
          const float corr = __expf(m_[i][r] - mnew);
          m_[i][r] = mnew;
          float ps = 0.f;
          const int swp = (prow & 7) << 3;
          #pragma unroll
          for (int jb = 0; jb < 4; ++jb){
            const float p = __expf(s_[i][jb][r] - mnew);
            ps += p;
            pbuf[w][prow*64 + ((jb*16 + l15) ^ swp)] = f2bf(p);
          }
          #pragma unroll
          for (int d = 1; d < 16; d <<= 1)
            ps += __shfl_xor(ps, d, 64);
          l_[i][r] = l_[i][r] * corr + ps;
          #pragma unroll
          for (int j2 = 0; j2 < 4; ++j2) acc_o[i][j2][r] *= corr;
        }
    }

    bf16x8 vfr[4][2];
    #pragma unroll
    for (int j2 = 0; j2 < 4; ++j2){
      const int dim = j2*16 + l15;
      const int sw = (dim & 7) << 3;
      #pragma unroll
      for (int kc = 0; kc < 2; ++kc)
        vfr[j2][kc] = *(const bf16x8*)&vtbuf[dim*64 + ((kc*32 + l4*8) ^ sw)];
    }
    #pragma unroll
    for (int i = 0; i < 2; ++i){
      const int prow = i*16 + l15;
      const int swp = (prow & 7) << 3;
      bf16x8 pa0 = *(const bf16x8*)&pbuf[w][prow*64 + ((l4*8) ^ swp)];
      bf16x8 pa1 = *(const bf16x8*)&pbuf[w][prow*64 + ((32 + l4*8) ^ swp)];
      #pragma unroll
      for (int j2 = 0; j2 < 4; ++j2){
        acc_o[i][j2] = __builtin_amdgcn_mfma_f32_16x16x32_bf16(pa0, vfr[j2][0], acc_o[i][j2], 0,0,0);
        acc_o[i][j2] = __builtin_amdgcn_mfma_f32_16x16x32_bf16(pa1, vfr[j2][1], acc_o[i][j2], 0,0,0);
      }
    }
  }

  #pragma unroll
  for (int i = 0; i < 2; ++i){
    #pragma unroll
    for (int r = 0; r < 4; ++r){
      const int qrow = qt*128 + w*32 + i*16 + l4*4 + r;
      const float inv = 1.f / l_[i][r];
      const size_t ob = ((size_t)b*256 + qrow)*512 + h*64;
      #pragma unroll
      for (int j2 = 0; j2 < 4; ++j2)
        out[ob + j2*16 + l15] = f2bf(acc_o[i][j2][r] * inv);
    }
  }
}

// -------- fused residual + LayerNorm + npm (v2: wave-per-row, no LDS) --------
// a bf16, res f32|bf16, out bf16. 4 rows/block, 64 lanes x 16 elems each.
// In-place (out == a) safe: each lane reads its 16 elems before writing them.
template<int RF32>
__global__ __launch_bounds__(256) void ln_fused(
    const u16* a, const void* __restrict__ res,
    const float* __restrict__ sc, const float* __restrict__ bs,
    const float* __restrict__ npm, u16* out)
{
  const int w = threadIdx.x >> 6, lane = threadIdx.x & 63;
  const int row = blockIdx.x * 4 + w;
  const size_t bse = (size_t)row * 1024 + lane * 16;

  u16x8 av0 = *(const u16x8*)&a[bse];
  u16x8 av1 = *(const u16x8*)&a[bse + 8];
  float rv[16];
  if (RF32){
    const float* rp = (const float*)res + bse;
    #pragma unroll
    for (int j = 0; j < 16; j += 4){
      f32x4 q = *(const f32x4*)&rp[j];
      rv[j] = q[0]; rv[j+1] = q[1]; rv[j+2] = q[2]; rv[j+3] = q[3];
    }
  } else {
    const u16* rp = (const u16*)res + bse;
    u16x8 q0 = *(const u16x8*)rp;
    u16x8 q1 = *(const u16x8*)(rp + 8);
    #pragma unroll
    for (int j = 0; j < 8; ++j){ rv[j] = bf2f(q0[j]); rv[8+j] = bf2f(q1[j]); }
  }

  float vv[16]; float s = 0.f, sq = 0.f;
  #pragma unroll
  for (int j = 0; j < 8; ++j){
    vv[j]   = bf2f(av0[j]) + rv[j];
    vv[8+j] = bf2f(av1[j]) + rv[8+j];
  }
  #pragma unroll
  for (int j = 0; j < 16; ++j){ s += vv[j]; sq += vv[j]*vv[j]; }
  #pragma unroll
  for (int i = 1; i < 64; i <<= 1){
    s  += __shfl_xor(s,  i, 64);
    sq += __shfl_xor(sq, i, 64);
  }
  const float mean = s * (1.f/1024.f);
  const float var  = sq * (1.f/1024.f) - mean*mean;
  const float rstd = rsqrtf(var + 1e-5f);
  const float nm   = npm[row];

  u16x8 o0, o1;
  #pragma unroll
  for (int j = 0; j < 8; ++j){
    const int c0 = lane*16 + j, c1 = c0 + 8;
    o0[j] = f2bf(((vv[j]   - mean) * rstd * sc[c0] + bs[c0]) * nm);
    o1[j] = f2bf(((vv[8+j] - mean) * rstd * sc[c1] + bs[c1]) * nm);
  }
  *(u16x8*)&out[bse]     = o0;
  *(u16x8*)&out[bse + 8] = o1;
}

// ---------------- launcher ---------------------------------------------------
extern "C" void kernel_launch(void* const* d_in, const int* in_sizes, int n_in,
                              void* d_out, int out_size, void* d_ws, size_t ws_size,
                              hipStream_t stream)
{
  // ws (u16 el), 112 MiB (proven):
  //  W  [0, 8388608): wqkvT|woT|w1T|w2T|fcT
  //  R1 [8388608, 25165824):  xbf (ph1) -> tmp0 -> xg (in-place LN)
  //  R2 [25165824, 41943040): qkvh [8192][1536] (ph1) -> ln1 (per layer)
  //  R3 [41943040, 58720256): tmp1 -> xl (in-place LN)   [unused in ph1]
  // d_out (u16): ph1: attnb0 [0,8.4M) | attnb1 [8.4M,16.8M) | masks @16.8M
  //              ph2 (after both out-projs): hbuf = FULL d_out [16384][2048]
  const size_t NEED = 58720256ull * 2ull;
  if (ws_size < NEED){
    zero_out<<<4096, 256, 0, stream>>>((float*)d_out, out_size);
    return;
  }

  const float* x   = (const float*)d_in[0];
  const int*   adj = (const int*)d_in[1];
  const float* npm = (const float*)d_in[2];
  const int*   slf = (const int*)d_in[3];
  const float* fcw = (const float*)d_in[30];
  const float* fcb = (const float*)d_in[31];

  u16* ws    = (u16*)d_ws;
  u16* wqkvT = ws;
  u16* woT   = ws + 1572864;
  u16* w1T   = ws + 2097152;
  u16* w2T   = ws + 4194304;
  u16* fcT   = ws + 6291456;
  u16* xbf   = ws + 8388608;           // R1: then tmp0/xg
  u16* tmp0  = ws + 8388608;
  u16* qkvh  = ws + 25165824;          // R2: then ln1
  u16* ln1   = ws + 25165824;
  u16* tmp1  = ws + 41943040;          // R3: tmp1/xl

  u16* dout16 = (u16*)d_out;
  u16* attnb0 = dout16;                // [16384][512]
  u16* attnb1 = dout16 + 8388608;      // [16384][512]
  u16* hbuf   = dout16;                // [16384][2048] (after out-projs)
  u64* mb_g   = (u64*)(dout16 + 16777216);   // phase1 only
  u64* mb_l   = mb_g + 65536;

  cvt_bf16<<<8192, 256, 0, stream>>>(x, xbf);
  mask_pack<<<16384, 256, 0, stream>>>(slf, adj, mb_g, mb_l);
  transpose_w<<<dim3(64, 32), 256, 0, stream>>>(fcw, fcT, 2048, 1024, 0);

  // Phase 1: both layers' QKV + attention (xbf + masks live throughout)
  for (int L = 0; L < 2; ++L){
    const int bi = 4 + L*13;
    transpose_w3<<<dim3(32, 16, 3), 256, 0, stream>>>(
        (const float*)d_in[bi+0], (const float*)d_in[bi+1],
        (const float*)d_in[bi+2], wqkvT, 1024, 512);
    u16* attnb = L ? attnb1 : attnb0;
    for (int hf = 0; hf < 2; ++hf){
      const u16* xh = xbf + (size_t)hf*8192*1024;
      gemm256<0,0,0><<<dim3(32, 6), 512, 0, stream>>>(
          xh, xh, 1024, 1024, wqkvT, 1024, 8192, 1536, 1024, nullptr, qkvh, 1536);
      attn_mfma<<<512, 256, 0, stream>>>(qkvh, L ? mb_l : mb_g, hf*32, attnb);
    }
  }

  // Phase 2a: BOTH out-projections first (frees all of d_out for hbuf)
  transpose_w<<<dim3(16, 32), 256, 0, stream>>>((const float*)d_in[4+3], woT, 512, 1024, 0);
  gemm256<0,0,0><<<dim3(64, 4), 512, 0, stream>>>(
      attnb0, attnb0, 512, 512, woT, 512, 16384, 1024, 512,
      (const float*)d_in[4+4], tmp0, 1024);
  transpose_w<<<dim3(16, 32), 256, 0, stream>>>((const float*)d_in[17+3], woT, 512, 1024, 0);
  gemm256<0,0,0><<<dim3(64, 4), 512, 0, stream>>>(
      attnb1, attnb1, 512, 512, woT, 512, 16384, 1024, 512,
      (const float*)d_in[17+4], tmp1, 1024);

  // Phase 2b: layer bodies (hbuf = full d_out; FFN unsplit, 2 dispatches/layer)
  for (int L = 0; L < 2; ++L){
    const int bi = 4 + L*13;
    const float* l1s = (const float*)d_in[bi+5];
    const float* l1b = (const float*)d_in[bi+6];
    const float* b1  = (const float*)d_in[bi+8];
    const float* b2  = (const float*)d_in[bi+10];
    const float* l2s = (const float*)d_in[bi+11];
    const float* l2b = (const float*)d_in[bi+12];
    u16* tmpL = L ? tmp1 : tmp0;

    transpose_w<<<dim3(32, 64), 256, 0, stream>>>((const float*)d_in[bi+7], w1T, 1024, 2048, 0);
    transpose_w<<<dim3(64, 32), 256, 0, stream>>>((const float*)d_in[bi+9], w2T, 2048, 1024, 0);

    // ln1 = LN(tmpL + x) * npm -> R2
    ln_fused<1><<<4096, 256, 0, stream>>>(tmpL, x, l1s, l1b, npm, ln1);
    // hbuf = relu(ln1 @ w1T + b1)   [16384][2048]
    gemm256<1,0,0><<<dim3(64, 8), 512, 0, stream>>>(
        ln1, ln1, 1024, 1024, w1T, 1024, 16384, 2048, 1024, b1, hbuf, 2048);
    // tmpL = hbuf @ w2T + b2
    gemm256<0,0,0><<<dim3(64, 4), 512, 0, stream>>>(
        hbuf, hbuf, 2048, 2048, w2T, 2048, 16384, 1024, 2048, b2, tmpL, 1024);
    // xout = LN(tmpL + ln1) * npm, in-place -> tmpL (xg = R1 / xl = R3)
    ln_fused<0><<<4096, 256, 0, stream>>>(tmpL, ln1, l2s, l2b, npm, tmpL);
  }

  // final: [xg | xl] @ fcT + fc_b -> d_out (f32), K split at 1024
  gemm256<0,1,0><<<dim3(64, 4), 512, 0, stream>>>(
      tmp0, tmp1, 1024, 1024, fcT, 2048, 16384, 1024, 2048, fcb, d_out, 1024);
}

// Round 16
// 713.224 us; speedup vs baseline: 1.2086x; 1.0280x over previous
//
#include <hip/hip_runtime.h>

// GLAT: B=64, N=256, D=1024, H=8, DK=64, DI=2048.
// I/O dtype: float32. Internal: bf16 MFMA + f32 accum. adj/slf: int32.

typedef unsigned short u16;
typedef unsigned long long u64;
typedef __bf16 bf16_t;
typedef bf16_t bf16x8 __attribute__((ext_vector_type(8)));
typedef float  f32x4  __attribute__((ext_vector_type(4)));
typedef u16    u16x8  __attribute__((ext_vector_type(8)));
typedef u16    u16x4  __attribute__((ext_vector_type(4)));

__device__ __forceinline__ float bf2f(u16 u){
  union { unsigned int i; float f; } c; c.i = ((unsigned int)u) << 16; return c.f;
}
__device__ __forceinline__ u16 f2bf(float f){
  union { float f; unsigned int u; } c; c.f = f;
  unsigned int u = c.u;
  unsigned int r = (u + 0x7fffu + ((u >> 16) & 1u)) >> 16;  // RNE
  return (u16)r;
}

// async 16B global -> LDS (direct). LDS dest = wave-uniform base + lane*16.
__device__ __forceinline__ void gl16(const u16* g, u16* l){
  __builtin_amdgcn_global_load_lds(
      (const __attribute__((address_space(1))) void*)g,
      (__attribute__((address_space(3))) void*)l, 16, 0, 0);
}

// ---------------- diagnostic fallback: zero d_out (f32) ----------------------
__global__ __launch_bounds__(256) void zero_out(float* out, int n){
  for (int i = blockIdx.x * 256 + threadIdx.x; i < n; i += 256 * 4096) out[i] = 0.f;
}

// ---------------- f32 -> bf16 bulk convert (8 elems/thread) ------------------
__global__ __launch_bounds__(256) void cvt_bf16(
    const float* __restrict__ in, u16* __restrict__ out)
{
  const size_t i = ((size_t)blockIdx.x * 256 + threadIdx.x) * 8;
  f32x4 a = *(const f32x4*)&in[i];
  f32x4 b = *(const f32x4*)&in[i + 4];
  u16x8 o;
  #pragma unroll
  for (int j = 0; j < 4; ++j){ o[j] = f2bf(a[j]); o[4+j] = f2bf(b[j]); }
  *(u16x8*)&out[i] = o;
}

// -------- weight transpose+convert: src f32 [K][N] -> dst bf16 [(off+n)*K+k] --
__global__ __launch_bounds__(256) void transpose_w(
    const float* __restrict__ src, u16* __restrict__ dst, int K, int N, int dstOff)
{
  __shared__ u16 tile[32][33];
  const int bk = blockIdx.x * 32, bn = blockIdx.y * 32;
  const int t = threadIdx.x;
  const int r = t >> 5, c = t & 31;
  #pragma unroll
  for (int p = 0; p < 4; ++p)
    tile[r + p*8][c] = f2bf(src[(size_t)(bk + r + p*8) * N + bn + c]);
  __syncthreads();
  #pragma unroll
  for (int p = 0; p < 4; ++p)
    dst[(size_t)(dstOff + bn + r + p*8) * K + bk + c] = tile[c][r + p*8];
}

// -------- 6-source QKV transpose: both layers' wq/wk/wv (K=1024, N=512) ------
__global__ __launch_bounds__(256) void transpose_qkv6(
    const float* s0, const float* s1, const float* s2,
    const float* s3, const float* s4, const float* s5,
    u16* __restrict__ dst0, u16* __restrict__ dst1)
{
  __shared__ u16 tile[32][33];
  const int z = blockIdx.z;
  const float* src = z == 0 ? s0 : z == 1 ? s1 : z == 2 ? s2
                   : z == 3 ? s3 : z == 4 ? s4 : s5;
  u16* dst = (z < 3 ? dst0 : dst1);
  const int dstOff = (z % 3) * 512;
  const int K = 1024, N = 512;
  const int bk = blockIdx.x * 32, bn = blockIdx.y * 32;
  const int t = threadIdx.x;
  const int r = t >> 5, c = t & 31;
  #pragma unroll
  for (int p = 0; p < 4; ++p)
    tile[r + p*8][c] = f2bf(src[(size_t)(bk + r + p*8) * N + bn + c]);
  __syncthreads();
  #pragma unroll
  for (int p = 0; p < 4; ++p)
    dst[(size_t)(dstOff + bn + r + p*8) * K + bk + c] = tile[c][r + p*8];
}

// -------- 2-source wo transpose (K=512, N=1024) ------------------------------
__global__ __launch_bounds__(256) void transpose_wo2(
    const float* s0, const float* s1, u16* __restrict__ dst0, u16* __restrict__ dst1)
{
  __shared__ u16 tile[32][33];
  const float* src = blockIdx.z == 0 ? s0 : s1;
  u16* dst = blockIdx.z == 0 ? dst0 : dst1;
  const int K = 512, N = 1024;
  const int bk = blockIdx.x * 32, bn = blockIdx.y * 32;
  const int t = threadIdx.x;
  const int r = t >> 5, c = t & 31;
  #pragma unroll
  for (int p = 0; p < 4; ++p)
    tile[r + p*8][c] = f2bf(src[(size_t)(bk + r + p*8) * N + bn + c]);
  __syncthreads();
  #pragma unroll
  for (int p = 0; p < 4; ++p)
    dst[(size_t)(bn + r + p*8) * K + bk + c] = tile[c][r + p*8];
}

// ---- GEMM 256x256, BK=64, 8 waves, dbuf LDS, quadrant-phase schedule -------
// r10 schedule, FROZEN (best measured: ~67-70us final GEMM, MfmaUtil ~40%).
template<int RELU, int OF32, int ACC>
__global__ __launch_bounds__(512, 2) void gemm256(
    const u16* __restrict__ A0, const u16* __restrict__ A1,
    int Astride, int ksplit,
    const u16* __restrict__ BT, int Bld, int M, int N, int K,
    const float* __restrict__ bias, void* __restrict__ outv, int out_ld)
{
  __shared__ u16 lds[2*32768];           // 128 KiB
  const int tid  = threadIdx.x;
  const int lane = tid & 63;
  const int wid  = tid >> 6;             // 0..7
  const int wm = wid >> 2, wn = wid & 3; // 2M x 4N waves
  const int l15 = lane & 15, l4 = lane >> 4;
  const int m0 = blockIdx.x * 256, n0 = blockIdx.y * 256;

  f32x4 acc[8][4];
  #pragma unroll
  for (int i = 0; i < 8; ++i)
    #pragma unroll
    for (int j = 0; j < 4; ++j)
      acc[i][j] = (f32x4){0.f, 0.f, 0.f, 0.f};

  const int s0 = tid, s1 = tid + 512;
  const int r0 = s0 >> 3, g0 = (s0 & 7) ^ (r0 & 7);
  const int r1 = s1 >> 3, g1 = (s1 & 7) ^ (r1 & 7);

  const int nt = K >> 6;

  auto stageA = [&](int kt, int h, int buf){
    const int kb = kt * 64;
    const u16* Ab = A0; int kl = kb;
    if (kb >= ksplit){ Ab = A1; kl = kb - ksplit; }
    u16* dst = &lds[buf*32768 + h*8192];
    gl16(&Ab[(size_t)(m0 + h*128 + r0) * Astride + kl + g0*8], &dst[s0*8]);
    gl16(&Ab[(size_t)(m0 + h*128 + r1) * Astride + kl + g1*8], &dst[s1*8]);
  };
  auto stageB = [&](int kt, int h, int buf){
    const int kb = kt * 64;
    u16* dst = &lds[buf*32768 + 16384 + h*8192];
    gl16(&BT[(size_t)(n0 + h*128 + r0) * Bld + kb + g0*8], &dst[s0*8]);
    gl16(&BT[(size_t)(n0 + h*128 + r1) * Bld + kb + g1*8], &dst[s1*8]);
  };
  auto lda = [&](int i, int kc, int buf) -> bf16x8 {
    const int r = wm*128 + i*16 + l15;
    const int c = (kc*4 + l4) ^ (r & 7);
    return *(const bf16x8*)&lds[buf*32768 + r*64 + c*8];
  };
  auto ldb = [&](int j, int kc, int buf) -> bf16x8 {
    const int r = wn*64 + j*16 + l15;
    const int c = (kc*4 + l4) ^ (r & 7);
    return *(const bf16x8*)&lds[buf*32768 + 16384 + r*64 + c*8];
  };

  // prologue: stage tile 0 fully (8 loads)
  stageA(0, 0, 0); stageA(0, 1, 0); stageB(0, 0, 0); stageB(0, 1, 0);

  for (int t = 0; t < nt; ++t){
    const int buf = t & 1, nbuf = buf ^ 1;
    const bool pf = (t + 1 < nt);
    if (pf){
      stageA(t+1, 0, nbuf);
      asm volatile("s_waitcnt vmcnt(2)" ::: "memory");  // tile t's 8 landed
    } else {
      asm volatile("s_waitcnt vmcnt(0)" ::: "memory");
    }
    __builtin_amdgcn_sched_barrier(0);
    __builtin_amdgcn_s_barrier();          // all waves' tile-t loads landed
    __builtin_amdgcn_sched_barrier(0);

    bf16x8 a_[4][2], b_[2][2];
    // ---- Q0: A-lo x B-lo ----
    #pragma unroll
    for (int i = 0; i < 4; ++i){ a_[i][0] = lda(i, 0, buf); a_[i][1] = lda(i, 1, buf); }
    #pragma unroll
    for (int j = 0; j < 2; ++j){ b_[j][0] = ldb(j, 0, buf); b_[j][1] = ldb(j, 1, buf); }
    if (pf) stageA(t+1, 1, nbuf);
    __builtin_amdgcn_s_setprio(1);
    #pragma unroll
    for (int i = 0; i < 4; ++i)
      #pragma unroll
      for (int j = 0; j < 2; ++j){
        acc[i][j] = __builtin_amdgcn_mfma_f32_16x16x32_bf16(a_[i][0], b_[j][0], acc[i][j], 0,0,0);
        acc[i][j] = __builtin_amdgcn_mfma_f32_16x16x32_bf16(a_[i][1], b_[j][1], acc[i][j], 0,0,0);
      }
    __builtin_amdgcn_s_setprio(0);
    // ---- Q1: A-lo x B-hi ----
    #pragma unroll
    for (int j = 0; j < 2; ++j){ b_[j][0] = ldb(2+j, 0, buf); b_[j][1] = ldb(2+j, 1, buf); }
    if (pf) stageB(t+1, 0, nbuf);
    __builtin_amdgcn_s_setprio(1);
    #pragma unroll
    for (int i = 0; i < 4; ++i)
      #pragma unroll
      for (int j = 0; j < 2; ++j){
        acc[i][2+j] = __builtin_amdgcn_mfma_f32_16x16x32_bf16(a_[i][0], b_[j][0], acc[i][2+j], 0,0,0);
        acc[i][2+j] = __builtin_amdgcn_mfma_f32_16x16x32_bf16(a_[i][1], b_[j][1], acc[i][2+j], 0,0,0);
      }
    __builtin_amdgcn_s_setprio(0);
    // ---- Q2: A-hi x B-hi ----
    #pragma unroll
    for (int i = 0; i < 4; ++i){ a_[i][0] = lda(4+i, 0, buf); a_[i][1] = lda(4+i, 1, buf); }
    if (pf) stageB(t+1, 1, nbuf);
    __builtin_amdgcn_s_setprio(1);
    #pragma unroll
    for (int i = 0; i < 4; ++i)
      #pragma unroll
      for (int j = 0; j < 2; ++j){
        acc[4+i][2+j] = __builtin_amdgcn_mfma_f32_16x16x32_bf16(a_[i][0], b_[j][0], acc[4+i][2+j], 0,0,0);
        acc[4+i][2+j] = __builtin_amdgcn_mfma_f32_16x16x32_bf16(a_[i][1], b_[j][1], acc[4+i][2+j], 0,0,0);
      }
    __builtin_amdgcn_s_setprio(0);
    // ---- Q3: A-hi x B-lo (re-read b_lo) ----
    #pragma unroll
    for (int j = 0; j < 2; ++j){ b_[j][0] = ldb(j, 0, buf); b_[j][1] = ldb(j, 1, buf); }
    __builtin_amdgcn_s_setprio(1);
    #pragma unroll
    for (int i = 0; i < 4; ++i)
      #pragma unroll
      for (int j = 0; j < 2; ++j){
        acc[4+i][j] = __builtin_amdgcn_mfma_f32_16x16x32_bf16(a_[i][0], b_[j][0], acc[4+i][j], 0,0,0);
        acc[4+i][j] = __builtin_amdgcn_mfma_f32_16x16x32_bf16(a_[i][1], b_[j][1], acc[4+i][j], 0,0,0);
      }
    __builtin_amdgcn_s_setprio(0);

    __builtin_amdgcn_sched_barrier(0);
    __builtin_amdgcn_s_barrier();          // all reads of buf done
    __builtin_amdgcn_sched_barrier(0);
  }

  // epilogue: C[row][col], row=(lane>>4)*4+r, col=lane&15 (m89-verified)
  const int rb = m0 + wm*128 + l4*4;
  const int cb = n0 + wn*64 + l15;
  #pragma unroll
  for (int i = 0; i < 8; ++i){
    #pragma unroll
    for (int j = 0; j < 4; ++j){
      const int col = cb + j*16;
      const float badd = bias ? bias[col] : 0.f;
      #pragma unroll
      for (int r = 0; r < 4; ++r){
        const int row = rb + i*16 + r;
        float y = acc[i][j][r] + badd;
        if (RELU) y = y > 0.f ? y : 0.f;
        if (OF32){
          float* po = &((float*)outv)[(size_t)row * out_ld + col];
          if (ACC) y += *po;
          *po = y;
        } else {
          u16* po = &((u16*)outv)[(size_t)row * out_ld + col];
          if (ACC) y += bf2f(*po);
          *po = f2bf(y);
        }
      }
    }
  }
}

// -------- mask pack: bit k of mb[row][c] = mask(row, c*64+k) -----------------
__global__ __launch_bounds__(256) void mask_pack(
    const int* __restrict__ slf, const int* __restrict__ adj,
    u64* __restrict__ mb_g, u64* __restrict__ mb_l)
{
  const int idx  = blockIdx.x * 4 + (threadIdx.x >> 6);  // (row, c) pair
  const int lane = threadIdx.x & 63;
  const size_t mi = (size_t)(idx >> 2) * 256 + (size_t)(idx & 3) * 64 + lane;
  const bool g = slf[mi] != 0;
  const bool l = g || (adj[mi] == 0);
  const u64 bg = __ballot(g);
  const u64 bl = __ballot(l);
  if (lane == 0){ mb_g[idx] = bg; mb_l[idx] = bl; }
}

// ---------------- MFMA flash attention (T13 defer-max, full batch) -----------
// block = (b, h, qtile of 128 rows); grid 1024; 4 waves x 32 q-rows.
// qkv: full [16384][1536]; q @ h*64, k @ 512+h*64, v @ 1024+h*64.
__global__ __launch_bounds__(256) void attn_mfma(
    const u16* __restrict__ qkv, const u64* __restrict__ mb,
    u16* __restrict__ out)
{
  __shared__ u16 kbuf[64*64];     // [key][dim], swizzled col ^= (key&7)<<3
  __shared__ u16 vtbuf[64*64];    // [dim][key], swizzled col ^= (dim&7)<<3
  __shared__ u16 pbuf[4][32*64];  // per-wave P [row][key], swizzled

  const int b  = blockIdx.x >> 4;
  const int h  = (blockIdx.x >> 1) & 7;
  const int qt = blockIdx.x & 1;
  const int t  = threadIdx.x;
  const int w  = t >> 6, lane = t & 63;
  const int l15 = lane & 15, l4 = lane >> 4;

  bf16x8 qf[2][2];
  {
    const int rbase = b*256 + qt*128 + w*32;
    #pragma unroll
    for (int i = 0; i < 2; ++i)
      #pragma unroll
      for (int kc = 0; kc < 2; ++kc)
        qf[i][kc] = *(const bf16x8*)&qkv[(size_t)(rbase + i*16 + l15)*1536 + h*64 + kc*32 + l4*8];
  }

  f32x4 acc_o[2][4];
  float m_[2][4], l_[2][4];
  #pragma unroll
  for (int i = 0; i < 2; ++i){
    #pragma unroll
    for (int j = 0; j < 4; ++j) acc_o[i][j] = (f32x4){0.f,0.f,0.f,0.f};
    #pragma unroll
    for (int r = 0; r < 4; ++r){ m_[i][r] = -1e30f; l_[i][r] = 0.f; }
  }

  for (int c = 0; c < 4; ++c){
    __syncthreads();
    {   // stage K and V^T (swizzled); thread -> key row t>>2, dim group (t&3)*16
      const int kr = t >> 2, dg = (t & 3) * 16;
      const size_t rbase = (size_t)(b*256 + c*64 + kr)*1536 + h*64 + dg;
      u16x8 k0 = *(const u16x8*)&qkv[rbase + 512];
      u16x8 k1 = *(const u16x8*)&qkv[rbase + 512 + 8];
      u16x8 v0 = *(const u16x8*)&qkv[rbase + 1024];
      u16x8 v1 = *(const u16x8*)&qkv[rbase + 1024 + 8];
      const int sw = (kr & 7) << 3;
      *(u16x8*)&kbuf[kr*64 + (dg ^ sw)]       = k0;
      *(u16x8*)&kbuf[kr*64 + ((dg + 8) ^ sw)] = k1;
      #pragma unroll
      for (int e = 0; e < 8; ++e){
        const int d0 = dg + e, d1 = dg + 8 + e;
        vtbuf[d0*64 + (kr ^ ((d0 & 7) << 3))] = v0[e];
        vtbuf[d1*64 + (kr ^ ((d1 & 7) << 3))] = v1[e];
      }
    }
    __syncthreads();

    bf16x8 kfr[4][2];
    #pragma unroll
    for (int jb = 0; jb < 4; ++jb){
      const int key = jb*16 + l15;
      const int sw = (key & 7) << 3;
      #pragma unroll
      for (int kc = 0; kc < 2; ++kc)
        kfr[jb][kc] = *(const bf16x8*)&kbuf[key*64 + ((kc*32 + l4*8) ^ sw)];
    }
    f32x4 s_[2][4];
    #pragma unroll
    for (int i = 0; i < 2; ++i)
      #pragma unroll
      for (int jb = 0; jb < 4; ++jb){
        f32x4 a = (f32x4){0.f,0.f,0.f,0.f};
        a = __builtin_amdgcn_mfma_f32_16x16x32_bf16(qf[i][0], kfr[jb][0], a, 0,0,0);
        a = __builtin_amdgcn_mfma_f32_16x16x32_bf16(qf[i][1], kfr[jb][1], a, 0,0,0);
        s_[i][jb] = a;
      }

    // scale + mask in place
    #pragma unroll
    for (int i = 0; i < 2; ++i)
      #pragma unroll
      for (int r = 0; r < 4; ++r){
        const int qrow = qt*128 + w*32 + i*16 + l4*4 + r;
        const u64 bits = mb[((size_t)b*256 + qrow)*4 + c];
        #pragma unroll
        for (int jb = 0; jb < 4; ++jb){
          float xv = s_[i][jb][r] * 0.125f;
          if ((bits >> (jb*16 + l15)) & 1ull) xv = -1e9f;
          s_[i][jb][r] = xv;
        }
      }
    // row maxes + defer-max vote (T13, THR=8)
    float mxs[2][4];
    bool okall = true;
    #pragma unroll
    for (int i = 0; i < 2; ++i)
      #pragma unroll
      for (int r = 0; r < 4; ++r){
        float mx = fmaxf(fmaxf(s_[i][0][r], s_[i][1][r]),
                         fmaxf(s_[i][2][r], s_[i][3][r]));
        #pragma unroll
        for (int d = 1; d < 16; d <<= 1)
          mx = fmaxf(mx, __shfl_xor(mx, d, 64));
        mxs[i][r] = mx;
        okall = okall && (mx <= m_[i][r] + 8.f);
      }
    if (__all(okall)){
      // deferred: keep m_old, no O/l rescale (P bounded by e^8)
      #pragma unroll
      for (int i = 0; i < 2; ++i)
        #pragma unroll
        for (int r = 0; r < 4; ++r){
          const int prow = i*16 + l4*4 + r;
          const int swp = (prow & 7) << 3;
          float ps = 0.f;
          #pragma unroll
          for (int jb = 0; jb < 4; ++jb){
            const float p = __expf(s_[i][jb][r] - m_[i][r]);
            ps += p;
            pbuf[w][prow*64 + ((jb*16 + l15) ^ swp)] = f2bf(p);
          }
          #pragma unroll
          for (int d = 1; d < 16; d <<= 1)
            ps += __shfl_xor(ps, d, 64);
          l_[i][r] += ps;
        }
    } else {
      #pragma unroll
      for (int i = 0; i < 2; ++i)
        #pragma unroll
        for (int r = 0; r < 4; ++r){
          const int prow = i*16 + l4*4 + r;
          const float mnew = fmaxf(m_[i][r], mxs[i][r]);
          const float corr = __expf(m_[i][r] - mnew);
          m_[i][r] = mnew;
          float ps = 0.f;
          const int swp = (prow & 7) << 3;
          #pragma unroll
          for (int jb = 0; jb < 4; ++jb){
            const float p = __expf(s_[i][jb][r] - mnew);
            ps += p;
            pbuf[w][prow*64 + ((jb*16 + l15) ^ swp)] = f2bf(p);
          }
          #pragma unroll
          for (int d = 1; d < 16; d <<= 1)
            ps += __shfl_xor(ps, d, 64);
          l_[i][r] = l_[i][r] * corr + ps;
          #pragma unroll
          for (int j2 = 0; j2 < 4; ++j2) acc_o[i][j2][r] *= corr;
        }
    }

    bf16x8 vfr[4][2];
    #pragma unroll
    for (int j2 = 0; j2 < 4; ++j2){
      const int dim = j2*16 + l15;
      const int sw = (dim & 7) << 3;
      #pragma unroll
      for (int kc = 0; kc < 2; ++kc)
        vfr[j2][kc] = *(const bf16x8*)&vtbuf[dim*64 + ((kc*32 + l4*8) ^ sw)];
    }
    #pragma unroll
    for (int i = 0; i < 2; ++i){
      const int prow = i*16 + l15;
      const int swp = (prow & 7) << 3;
      bf16x8 pa0 = *(const bf16x8*)&pbuf[w][prow*64 + ((l4*8) ^ swp)];
      bf16x8 pa1 = *(const bf16x8*)&pbuf[w][prow*64 + ((32 + l4*8) ^ swp)];
      #pragma unroll
      for (int j2 = 0; j2 < 4; ++j2){
        acc_o[i][j2] = __builtin_amdgcn_mfma_f32_16x16x32_bf16(pa0, vfr[j2][0], acc_o[i][j2], 0,0,0);
        acc_o[i][j2] = __builtin_amdgcn_mfma_f32_16x16x32_bf16(pa1, vfr[j2][1], acc_o[i][j2], 0,0,0);
      }
    }
  }

  #pragma unroll
  for (int i = 0; i < 2; ++i){
    #pragma unroll
    for (int r = 0; r < 4; ++r){
      const int qrow = qt*128 + w*32 + i*16 + l4*4 + r;
      const float inv = 1.f / l_[i][r];
      const size_t ob = ((size_t)b*256 + qrow)*512 + h*64;
      #pragma unroll
      for (int j2 = 0; j2 < 4; ++j2)
        out[ob + j2*16 + l15] = f2bf(acc_o[i][j2][r] * inv);
    }
  }
}

// -------- fused residual + LayerNorm + npm (v2: wave-per-row, no LDS) --------
template<int RF32>
__global__ __launch_bounds__(256) void ln_fused(
    const u16* a, const void* __restrict__ res,
    const float* __restrict__ sc, const float* __restrict__ bs,
    const float* __restrict__ npm, u16* out)
{
  const int w = threadIdx.x >> 6, lane = threadIdx.x & 63;
  const int row = blockIdx.x * 4 + w;
  const size_t bse = (size_t)row * 1024 + lane * 16;

  u16x8 av0 = *(const u16x8*)&a[bse];
  u16x8 av1 = *(const u16x8*)&a[bse + 8];
  float rv[16];
  if (RF32){
    const float* rp = (const float*)res + bse;
    #pragma unroll
    for (int j = 0; j < 16; j += 4){
      f32x4 q = *(const f32x4*)&rp[j];
      rv[j] = q[0]; rv[j+1] = q[1]; rv[j+2] = q[2]; rv[j+3] = q[3];
    }
  } else {
    const u16* rp = (const u16*)res + bse;
    u16x8 q0 = *(const u16x8*)rp;
    u16x8 q1 = *(const u16x8*)(rp + 8);
    #pragma unroll
    for (int j = 0; j < 8; ++j){ rv[j] = bf2f(q0[j]); rv[8+j] = bf2f(q1[j]); }
  }

  float vv[16]; float s = 0.f, sq = 0.f;
  #pragma unroll
  for (int j = 0; j < 8; ++j){
    vv[j]   = bf2f(av0[j]) + rv[j];
    vv[8+j] = bf2f(av1[j]) + rv[8+j];
  }
  #pragma unroll
  for (int j = 0; j < 16; ++j){ s += vv[j]; sq += vv[j]*vv[j]; }
  #pragma unroll
  for (int i = 1; i < 64; i <<= 1){
    s  += __shfl_xor(s,  i, 64);
    sq += __shfl_xor(sq, i, 64);
  }
  const float mean = s * (1.f/1024.f);
  const float var  = sq * (1.f/1024.f) - mean*mean;
  const float rstd = rsqrtf(var + 1e-5f);
  const float nm   = npm[row];

  u16x8 o0, o1;
  #pragma unroll
  for (int j = 0; j < 8; ++j){
    const int c0 = lane*16 + j, c1 = c0 + 8;
    o0[j] = f2bf(((vv[j]   - mean) * rstd * sc[c0] + bs[c0]) * nm);
    o1[j] = f2bf(((vv[8+j] - mean) * rstd * sc[c1] + bs[c1]) * nm);
  }
  *(u16x8*)&out[bse]     = o0;
  *(u16x8*)&out[bse + 8] = o1;
}

// ---------------- launcher ---------------------------------------------------
extern "C" void kernel_launch(void* const* d_in, const int* in_sizes, int n_in,
                              void* d_out, int out_size, void* d_ws, size_t ws_size,
                              hipStream_t stream)
{
  // ws (u16 el), 112 MiB (proven):
  //  W  [0, 8388608): wqkvT0 @0 | wqkvT1 @1572864 | woT0 @3145728 |
  //                   woT1 @3670016 | fcT @4194304 | w1T @6291456 (ph2b)
  //                   w2T @0 (ph2b, overwrites dead wqkvT0/part of wqkvT1)
  //  R1 [8388608, 25165824):  xbf (ph1) -> tmp0 -> xg (in-place LN)
  //  R2 [25165824, 41943040): attnb0 | attnb1 (ph1) -> ln1 (ph2b)
  //  R3 [41943040, 58720256): tmp1 -> xl (in-place LN)   [free in ph1]
  // d_out (u16): ph1: qkv full [0, 25165824) | masks @25165824
  //              ph2b: hbuf = FULL d_out [16384][2048]
  const size_t NEED = 58720256ull * 2ull;
  if (ws_size < NEED){
    zero_out<<<4096, 256, 0, stream>>>((float*)d_out, out_size);
    return;
  }

  const float* x   = (const float*)d_in[0];
  const int*   adj = (const int*)d_in[1];
  const float* npm = (const float*)d_in[2];
  const int*   slf = (const int*)d_in[3];
  const float* fcw = (const float*)d_in[30];
  const float* fcb = (const float*)d_in[31];

  u16* ws     = (u16*)d_ws;
  u16* wqkvT0 = ws;
  u16* wqkvT1 = ws + 1572864;
  u16* woT0   = ws + 3145728;
  u16* woT1   = ws + 3670016;
  u16* fcT    = ws + 4194304;
  u16* w1T    = ws + 6291456;
  u16* w2T    = ws;                    // ph2b only (wqkvT dead)
  u16* xbf    = ws + 8388608;          // R1: then tmp0/xg
  u16* tmp0   = ws + 8388608;
  u16* attnb0 = ws + 25165824;         // R2
  u16* attnb1 = ws + 33554432;
  u16* ln1    = ws + 25165824;         // R2 (ph2b)
  u16* tmp1   = ws + 41943040;         // R3

  u16* dout16 = (u16*)d_out;
  u16* qkv    = dout16;                      // [16384][1536] (ph1)
  u64* mb_g   = (u64*)(dout16 + 25165824);   // ph1 only
  u64* mb_l   = mb_g + 65536;
  u16* hbuf   = dout16;                      // [16384][2048] (ph2b)

  cvt_bf16<<<8192, 256, 0, stream>>>(x, xbf);
  mask_pack<<<16384, 256, 0, stream>>>(slf, adj, mb_g, mb_l);
  transpose_w<<<dim3(64, 32), 256, 0, stream>>>(fcw, fcT, 2048, 1024, 0);
  transpose_qkv6<<<dim3(32, 16, 6), 256, 0, stream>>>(
      (const float*)d_in[4+0], (const float*)d_in[4+1], (const float*)d_in[4+2],
      (const float*)d_in[17+0], (const float*)d_in[17+1], (const float*)d_in[17+2],
      wqkvT0, wqkvT1);
  transpose_wo2<<<dim3(16, 32, 2), 256, 0, stream>>>(
      (const float*)d_in[4+3], (const float*)d_in[17+3], woT0, woT1);

  // Phase 1: both layers' QKV (full batch) + attention
  for (int L = 0; L < 2; ++L){
    const u16* wq = L ? wqkvT1 : wqkvT0;
    u16* attnb = L ? attnb1 : attnb0;
    gemm256<0,0,0><<<dim3(64, 6), 512, 0, stream>>>(
        xbf, xbf, 1024, 1024, wq, 1024, 16384, 1536, 1024, nullptr, qkv, 1536);
    attn_mfma<<<1024, 256, 0, stream>>>(qkv, L ? mb_l : mb_g, attnb);
  }

  // Phase 2a: both out-projections (frees d_out for hbuf)
  gemm256<0,0,0><<<dim3(64, 4), 512, 0, stream>>>(
      attnb0, attnb0, 512, 512, woT0, 512, 16384, 1024, 512,
      (const float*)d_in[4+4], tmp0, 1024);
  gemm256<0,0,0><<<dim3(64, 4), 512, 0, stream>>>(
      attnb1, attnb1, 512, 512, woT1, 512, 16384, 1024, 512,
      (const float*)d_in[17+4], tmp1, 1024);

  // Phase 2b: layer bodies (hbuf = full d_out; FFN unsplit)
  for (int L = 0; L < 2; ++L){
    const int bi = 4 + L*13;
    const float* l1s = (const float*)d_in[bi+5];
    const float* l1b = (const float*)d_in[bi+6];
    const float* b1  = (const float*)d_in[bi+8];
    const float* b2  = (const float*)d_in[bi+10];
    const float* l2s = (const float*)d_in[bi+11];
    const float* l2b = (const float*)d_in[bi+12];
    u16* tmpL = L ? tmp1 : tmp0;

    transpose_w<<<dim3(32, 64), 256, 0, stream>>>((const float*)d_in[bi+7], w1T, 1024, 2048, 0);
    transpose_w<<<dim3(64, 32), 256, 0, stream>>>((const float*)d_in[bi+9], w2T, 2048, 1024, 0);

    // ln1 = LN(tmpL + x) * npm -> R2
    ln_fused<1><<<4096, 256, 0, stream>>>(tmpL, x, l1s, l1b, npm, ln1);
    // hbuf = relu(ln1 @ w1T + b1)   [16384][2048]
    gemm256<1,0,0><<<dim3(64, 8), 512, 0, stream>>>(
        ln1, ln1, 1024, 1024, w1T, 1024, 16384, 2048, 1024, b1, hbuf, 2048);
    // tmpL = hbuf @ w2T + b2
    gemm256<0,0,0><<<dim3(64, 4), 512, 0, stream>>>(
        hbuf, hbuf, 2048, 2048, w2T, 2048, 16384, 1024, 2048, b2, tmpL, 1024);
    // xout = LN(tmpL + ln1) * npm, in-place -> tmpL (xg = R1 / xl = R3)
    ln_fused<0><<<4096, 256, 0, stream>>>(tmpL, ln1, l2s, l2b, npm, tmpL);
  }

  // final: [xg | xl] @ fcT + fc_b -> d_out (f32), K split at 1024
  gemm256<0,1,0><<<dim3(64, 4), 512, 0, stream>>>(
      tmp0, tmp1, 1024, 1024, fcT, 2048, 16384, 1024, 2048, fcb, d_out, 1024);
}

// Round 17
// 688.397 us; speedup vs baseline: 1.2521x; 1.0361x over previous
//
#include <hip/hip_runtime.h>

// GLAT: B=64, N=256, D=1024, H=8, DK=64, DI=2048.
// I/O dtype: float32. Internal: bf16 MFMA + f32 accum. adj/slf: int32.

typedef unsigned short u16;
typedef unsigned long long u64;
typedef __bf16 bf16_t;
typedef bf16_t bf16x8 __attribute__((ext_vector_type(8)));
typedef float  f32x4  __attribute__((ext_vector_type(4)));
typedef u16    u16x8  __attribute__((ext_vector_type(8)));
typedef u16    u16x4  __attribute__((ext_vector_type(4)));

__device__ __forceinline__ float bf2f(u16 u){
  union { unsigned int i; float f; } c; c.i = ((unsigned int)u) << 16; return c.f;
}
__device__ __forceinline__ u16 f2bf(float f){
  union { float f; unsigned int u; } c; c.f = f;
  unsigned int u = c.u;
  unsigned int r = (u + 0x7fffu + ((u >> 16) & 1u)) >> 16;  // RNE
  return (u16)r;
}

// async 16B global -> LDS (direct). LDS dest = wave-uniform base + lane*16.
__device__ __forceinline__ void gl16(const u16* g, u16* l){
  __builtin_amdgcn_global_load_lds(
      (const __attribute__((address_space(1))) void*)g,
      (__attribute__((address_space(3))) void*)l, 16, 0, 0);
}

// ---------------- diagnostic fallback: zero d_out (f32) ----------------------
__global__ __launch_bounds__(256) void zero_out(float* out, int n){
  for (int i = blockIdx.x * 256 + threadIdx.x; i < n; i += 256 * 4096) out[i] = 0.f;
}

// ---------------- f32 -> bf16 bulk convert (8 elems/thread) ------------------
__global__ __launch_bounds__(256) void cvt_bf16(
    const float* __restrict__ in, u16* __restrict__ out)
{
  const size_t i = ((size_t)blockIdx.x * 256 + threadIdx.x) * 8;
  f32x4 a = *(const f32x4*)&in[i];
  f32x4 b = *(const f32x4*)&in[i + 4];
  u16x8 o;
  #pragma unroll
  for (int j = 0; j < 4; ++j){ o[j] = f2bf(a[j]); o[4+j] = f2bf(b[j]); }
  *(u16x8*)&out[i] = o;
}

// -------- weight transpose+convert: src f32 [K][N] -> dst bf16 [(off+n)*K+k] --
__global__ __launch_bounds__(256) void transpose_w(
    const float* __restrict__ src, u16* __restrict__ dst, int K, int N, int dstOff)
{
  __shared__ u16 tile[32][33];
  const int bk = blockIdx.x * 32, bn = blockIdx.y * 32;
  const int t = threadIdx.x;
  const int r = t >> 5, c = t & 31;
  #pragma unroll
  for (int p = 0; p < 4; ++p)
    tile[r + p*8][c] = f2bf(src[(size_t)(bk + r + p*8) * N + bn + c]);
  __syncthreads();
  #pragma unroll
  for (int p = 0; p < 4; ++p)
    dst[(size_t)(dstOff + bn + r + p*8) * K + bk + c] = tile[c][r + p*8];
}

// -------- 6-source QKV transpose: both layers' wq/wk/wv (K=1024, N=512) ------
__global__ __launch_bounds__(256) void transpose_qkv6(
    const float* s0, const float* s1, const float* s2,
    const float* s3, const float* s4, const float* s5,
    u16* __restrict__ dst0, u16* __restrict__ dst1)
{
  __shared__ u16 tile[32][33];
  const int z = blockIdx.z;
  const float* src = z == 0 ? s0 : z == 1 ? s1 : z == 2 ? s2
                   : z == 3 ? s3 : z == 4 ? s4 : s5;
  u16* dst = (z < 3 ? dst0 : dst1);
  const int dstOff = (z % 3) * 512;
  const int K = 1024, N = 512;
  const int bk = blockIdx.x * 32, bn = blockIdx.y * 32;
  const int t = threadIdx.x;
  const int r = t >> 5, c = t & 31;
  #pragma unroll
  for (int p = 0; p < 4; ++p)
    tile[r + p*8][c] = f2bf(src[(size_t)(bk + r + p*8) * N + bn + c]);
  __syncthreads();
  #pragma unroll
  for (int p = 0; p < 4; ++p)
    dst[(size_t)(dstOff + bn + r + p*8) * K + bk + c] = tile[c][r + p*8];
}

// -------- 2-source wo transpose (K=512, N=1024) ------------------------------
__global__ __launch_bounds__(256) void transpose_wo2(
    const float* s0, const float* s1, u16* __restrict__ dst0, u16* __restrict__ dst1)
{
  __shared__ u16 tile[32][33];
  const float* src = blockIdx.z == 0 ? s0 : s1;
  u16* dst = blockIdx.z == 0 ? dst0 : dst1;
  const int K = 512, N = 1024;
  const int bk = blockIdx.x * 32, bn = blockIdx.y * 32;
  const int t = threadIdx.x;
  const int r = t >> 5, c = t & 31;
  #pragma unroll
  for (int p = 0; p < 4; ++p)
    tile[r + p*8][c] = f2bf(src[(size_t)(bk + r + p*8) * N + bn + c]);
  __syncthreads();
  #pragma unroll
  for (int p = 0; p < 4; ++p)
    dst[(size_t)(bn + r + p*8) * K + bk + c] = tile[c][r + p*8];
}

// ---- GEMM 256x256, BK=64, 8 waves, dbuf LDS, quadrant-phase schedule -------
// r10 schedule, FROZEN. C = A[M,K] @ BT[N,:]^T. A split at ksplit (A0/A1).
// BT row stride = Bld. ACC: out += result. OUT2: blocks with n0 >= ncut write
// out2v[row*out_ld + col-ncut] (per-block-uniform buffer select; 256 | ncut).
template<int RELU, int OF32, int ACC, int OUT2>
__global__ __launch_bounds__(512, 2) void gemm256(
    const u16* __restrict__ A0, const u16* __restrict__ A1,
    int Astride, int ksplit,
    const u16* __restrict__ BT, int Bld, int M, int N, int K,
    const float* __restrict__ bias, void* __restrict__ outv, int out_ld,
    u16* __restrict__ out2v, int ncut)
{
  __shared__ u16 lds[2*32768];           // 128 KiB
  const int tid  = threadIdx.x;
  const int lane = tid & 63;
  const int wid  = tid >> 6;             // 0..7
  const int wm = wid >> 2, wn = wid & 3; // 2M x 4N waves
  const int l15 = lane & 15, l4 = lane >> 4;
  const int m0 = blockIdx.x * 256, n0 = blockIdx.y * 256;

  f32x4 acc[8][4];
  #pragma unroll
  for (int i = 0; i < 8; ++i)
    #pragma unroll
    for (int j = 0; j < 4; ++j)
      acc[i][j] = (f32x4){0.f, 0.f, 0.f, 0.f};

  const int s0 = tid, s1 = tid + 512;
  const int r0 = s0 >> 3, g0 = (s0 & 7) ^ (r0 & 7);
  const int r1 = s1 >> 3, g1 = (s1 & 7) ^ (r1 & 7);

  const int nt = K >> 6;

  auto stageA = [&](int kt, int h, int buf){
    const int kb = kt * 64;
    const u16* Ab = A0; int kl = kb;
    if (kb >= ksplit){ Ab = A1; kl = kb - ksplit; }
    u16* dst = &lds[buf*32768 + h*8192];
    gl16(&Ab[(size_t)(m0 + h*128 + r0) * Astride + kl + g0*8], &dst[s0*8]);
    gl16(&Ab[(size_t)(m0 + h*128 + r1) * Astride + kl + g1*8], &dst[s1*8]);
  };
  auto stageB = [&](int kt, int h, int buf){
    const int kb = kt * 64;
    u16* dst = &lds[buf*32768 + 16384 + h*8192];
    gl16(&BT[(size_t)(n0 + h*128 + r0) * Bld + kb + g0*8], &dst[s0*8]);
    gl16(&BT[(size_t)(n0 + h*128 + r1) * Bld + kb + g1*8], &dst[s1*8]);
  };
  auto lda = [&](int i, int kc, int buf) -> bf16x8 {
    const int r = wm*128 + i*16 + l15;
    const int c = (kc*4 + l4) ^ (r & 7);
    return *(const bf16x8*)&lds[buf*32768 + r*64 + c*8];
  };
  auto ldb = [&](int j, int kc, int buf) -> bf16x8 {
    const int r = wn*64 + j*16 + l15;
    const int c = (kc*4 + l4) ^ (r & 7);
    return *(const bf16x8*)&lds[buf*32768 + 16384 + r*64 + c*8];
  };

  // prologue: stage tile 0 fully (8 loads)
  stageA(0, 0, 0); stageA(0, 1, 0); stageB(0, 0, 0); stageB(0, 1, 0);

  for (int t = 0; t < nt; ++t){
    const int buf = t & 1, nbuf = buf ^ 1;
    const bool pf = (t + 1 < nt);
    if (pf){
      stageA(t+1, 0, nbuf);
      asm volatile("s_waitcnt vmcnt(2)" ::: "memory");  // tile t's 8 landed
    } else {
      asm volatile("s_waitcnt vmcnt(0)" ::: "memory");
    }
    __builtin_amdgcn_sched_barrier(0);
    __builtin_amdgcn_s_barrier();          // all waves' tile-t loads landed
    __builtin_amdgcn_sched_barrier(0);

    bf16x8 a_[4][2], b_[2][2];
    // ---- Q0: A-lo x B-lo ----
    #pragma unroll
    for (int i = 0; i < 4; ++i){ a_[i][0] = lda(i, 0, buf); a_[i][1] = lda(i, 1, buf); }
    #pragma unroll
    for (int j = 0; j < 2; ++j){ b_[j][0] = ldb(j, 0, buf); b_[j][1] = ldb(j, 1, buf); }
    if (pf) stageA(t+1, 1, nbuf);
    __builtin_amdgcn_s_setprio(1);
    #pragma unroll
    for (int i = 0; i < 4; ++i)
      #pragma unroll
      for (int j = 0; j < 2; ++j){
        acc[i][j] = __builtin_amdgcn_mfma_f32_16x16x32_bf16(a_[i][0], b_[j][0], acc[i][j], 0,0,0);
        acc[i][j] = __builtin_amdgcn_mfma_f32_16x16x32_bf16(a_[i][1], b_[j][1], acc[i][j], 0,0,0);
      }
    __builtin_amdgcn_s_setprio(0);
    // ---- Q1: A-lo x B-hi ----
    #pragma unroll
    for (int j = 0; j < 2; ++j){ b_[j][0] = ldb(2+j, 0, buf); b_[j][1] = ldb(2+j, 1, buf); }
    if (pf) stageB(t+1, 0, nbuf);
    __builtin_amdgcn_s_setprio(1);
    #pragma unroll
    for (int i = 0; i < 4; ++i)
      #pragma unroll
      for (int j = 0; j < 2; ++j){
        acc[i][2+j] = __builtin_amdgcn_mfma_f32_16x16x32_bf16(a_[i][0], b_[j][0], acc[i][2+j], 0,0,0);
        acc[i][2+j] = __builtin_amdgcn_mfma_f32_16x16x32_bf16(a_[i][1], b_[j][1], acc[i][2+j], 0,0,0);
      }
    __builtin_amdgcn_s_setprio(0);
    // ---- Q2: A-hi x B-hi ----
    #pragma unroll
    for (int i = 0; i < 4; ++i){ a_[i][0] = lda(4+i, 0, buf); a_[i][1] = lda(4+i, 1, buf); }
    if (pf) stageB(t+1, 1, nbuf);
    __builtin_amdgcn_s_setprio(1);
    #pragma unroll
    for (int i = 0; i < 4; ++i)
      #pragma unroll
      for (int j = 0; j < 2; ++j){
        acc[4+i][2+j] = __builtin_amdgcn_mfma_f32_16x16x32_bf16(a_[i][0], b_[j][0], acc[4+i][2+j], 0,0,0);
        acc[4+i][2+j] = __builtin_amdgcn_mfma_f32_16x16x32_bf16(a_[i][1], b_[j][1], acc[4+i][2+j], 0,0,0);
      }
    __builtin_amdgcn_s_setprio(0);
    // ---- Q3: A-hi x B-lo (re-read b_lo) ----
    #pragma unroll
    for (int j = 0; j < 2; ++j){ b_[j][0] = ldb(j, 0, buf); b_[j][1] = ldb(j, 1, buf); }
    __builtin_amdgcn_s_setprio(1);
    #pragma unroll
    for (int i = 0; i < 4; ++i)
      #pragma unroll
      for (int j = 0; j < 2; ++j){
        acc[4+i][j] = __builtin_amdgcn_mfma_f32_16x16x32_bf16(a_[i][0], b_[j][0], acc[4+i][j], 0,0,0);
        acc[4+i][j] = __builtin_amdgcn_mfma_f32_16x16x32_bf16(a_[i][1], b_[j][1], acc[4+i][j], 0,0,0);
      }
    __builtin_amdgcn_s_setprio(0);

    __builtin_amdgcn_sched_barrier(0);
    __builtin_amdgcn_s_barrier();          // all reads of buf done
    __builtin_amdgcn_sched_barrier(0);
  }

  // epilogue: C[row][col], row=(lane>>4)*4+r, col=lane&15 (m89-verified)
  u16* outp = (u16*)outv;
  int cadj = 0;
  if (OUT2 && n0 >= ncut){ outp = out2v; cadj = ncut; }
  const int rb = m0 + wm*128 + l4*4;
  const int cb = n0 + wn*64 + l15;
  #pragma unroll
  for (int i = 0; i < 8; ++i){
    #pragma unroll
    for (int j = 0; j < 4; ++j){
      const int col = cb + j*16;
      const float badd = bias ? bias[col] : 0.f;
      #pragma unroll
      for (int r = 0; r < 4; ++r){
        const int row = rb + i*16 + r;
        float y = acc[i][j][r] + badd;
        if (RELU) y = y > 0.f ? y : 0.f;
        if (OF32){
          float* po = &((float*)outv)[(size_t)row * out_ld + col];
          if (ACC) y += *po;
          *po = y;
        } else {
          u16* po = &outp[(size_t)row * out_ld + col - cadj];
          if (ACC) y += bf2f(*po);
          *po = f2bf(y);
        }
      }
    }
  }
}

// -------- mask pack: bit k of mb[row][c] = mask(row, c*64+k) -----------------
__global__ __launch_bounds__(256) void mask_pack(
    const int* __restrict__ slf, const int* __restrict__ adj,
    u64* __restrict__ mb_g, u64* __restrict__ mb_l)
{
  const int idx  = blockIdx.x * 4 + (threadIdx.x >> 6);  // (row, c) pair
  const int lane = threadIdx.x & 63;
  const size_t mi = (size_t)(idx >> 2) * 256 + (size_t)(idx & 3) * 64 + lane;
  const bool g = slf[mi] != 0;
  const bool l = g || (adj[mi] == 0);
  const u64 bg = __ballot(g);
  const u64 bl = __ballot(l);
  if (lane == 0){ mb_g[idx] = bg; mb_l[idx] = bl; }
}

// ---------------- MFMA flash attention (T13 defer-max, full batch) -----------
// block = (b, h, qtile of 128 rows); grid 1024; 4 waves x 32 q-rows.
// qkv: full [16384][1536]; q @ h*64, k @ 512+h*64, v @ 1024+h*64.
__global__ __launch_bounds__(256) void attn_mfma(
    const u16* __restrict__ qkv, const u64* __restrict__ mb,
    u16* __restrict__ out)
{
  __shared__ u16 kbuf[64*64];     // [key][dim], swizzled col ^= (key&7)<<3
  __shared__ u16 vtbuf[64*64];    // [dim][key], swizzled col ^= (dim&7)<<3
  __shared__ u16 pbuf[4][32*64];  // per-wave P [row][key], swizzled

  const int b  = blockIdx.x >> 4;
  const int h  = (blockIdx.x >> 1) & 7;
  const int qt = blockIdx.x & 1;
  const int t  = threadIdx.x;
  const int w  = t >> 6, lane = t & 63;
  const int l15 = lane & 15, l4 = lane >> 4;

  bf16x8 qf[2][2];
  {
    const int rbase = b*256 + qt*128 + w*32;
    #pragma unroll
    for (int i = 0; i < 2; ++i)
      #pragma unroll
      for (int kc = 0; kc < 2; ++kc)
        qf[i][kc] = *(const bf16x8*)&qkv[(size_t)(rbase + i*16 + l15)*1536 + h*64 + kc*32 + l4*8];
  }

  f32x4 acc_o[2][4];
  float m_[2][4], l_[2][4];
  #pragma unroll
  for (int i = 0; i < 2; ++i){
    #pragma unroll
    for (int j = 0; j < 4; ++j) acc_o[i][j] = (f32x4){0.f,0.f,0.f,0.f};
    #pragma unroll
    for (int r = 0; r < 4; ++r){ m_[i][r] = -1e30f; l_[i][r] = 0.f; }
  }

  for (int c = 0; c < 4; ++c){
    __syncthreads();
    {   // stage K and V^T (swizzled); thread -> key row t>>2, dim group (t&3)*16
      const int kr = t >> 2, dg = (t & 3) * 16;
      const size_t rbase = (size_t)(b*256 + c*64 + kr)*1536 + h*64 + dg;
      u16x8 k0 = *(const u16x8*)&qkv[rbase + 512];
      u16x8 k1 = *(const u16x8*)&qkv[rbase + 512 + 8];
      u16x8 v0 = *(const u16x8*)&qkv[rbase + 1024];
      u16x8 v1 = *(const u16x8*)&qkv[rbase + 1024 + 8];
      const int sw = (kr & 7) << 3;
      *(u16x8*)&kbuf[kr*64 + (dg ^ sw)]       = k0;
      *(u16x8*)&kbuf[kr*64 + ((dg + 8) ^ sw)] = k1;
      #pragma unroll
      for (int e = 0; e < 8; ++e){
        const int d0 = dg + e, d1 = dg + 8 + e;
        vtbuf[d0*64 + (kr ^ ((d0 & 7) << 3))] = v0[e];
        vtbuf[d1*64 + (kr ^ ((d1 & 7) << 3))] = v1[e];
      }
    }
    __syncthreads();

    bf16x8 kfr[4][2];
    #pragma unroll
    for (int jb = 0; jb < 4; ++jb){
      const int key = jb*16 + l15;
      const int sw = (key & 7) << 3;
      #pragma unroll
      for (int kc = 0; kc < 2; ++kc)
        kfr[jb][kc] = *(const bf16x8*)&kbuf[key*64 + ((kc*32 + l4*8) ^ sw)];
    }
    f32x4 s_[2][4];
    #pragma unroll
    for (int i = 0; i < 2; ++i)
      #pragma unroll
      for (int jb = 0; jb < 4; ++jb){
        f32x4 a = (f32x4){0.f,0.f,0.f,0.f};
        a = __builtin_amdgcn_mfma_f32_16x16x32_bf16(qf[i][0], kfr[jb][0], a, 0,0,0);
        a = __builtin_amdgcn_mfma_f32_16x16x32_bf16(qf[i][1], kfr[jb][1], a, 0,0,0);
        s_[i][jb] = a;
      }

    // scale + mask in place
    #pragma unroll
    for (int i = 0; i < 2; ++i)
      #pragma unroll
      for (int r = 0; r < 4; ++r){
        const int qrow = qt*128 + w*32 + i*16 + l4*4 + r;
        const u64 bits = mb[((size_t)b*256 + qrow)*4 + c];
        #pragma unroll
        for (int jb = 0; jb < 4; ++jb){
          float xv = s_[i][jb][r] * 0.125f;
          if ((bits >> (jb*16 + l15)) & 1ull) xv = -1e9f;
          s_[i][jb][r] = xv;
        }
      }
    // row maxes + defer-max vote (T13, THR=8)
    float mxs[2][4];
    bool okall = true;
    #pragma unroll
    for (int i = 0; i < 2; ++i)
      #pragma unroll
      for (int r = 0; r < 4; ++r){
        float mx = fmaxf(fmaxf(s_[i][0][r], s_[i][1][r]),
                         fmaxf(s_[i][2][r], s_[i][3][r]));
        #pragma unroll
        for (int d = 1; d < 16; d <<= 1)
          mx = fmaxf(mx, __shfl_xor(mx, d, 64));
        mxs[i][r] = mx;
        okall = okall && (mx <= m_[i][r] + 8.f);
      }
    if (__all(okall)){
      // deferred: keep m_old, no O/l rescale (P bounded by e^8)
      #pragma unroll
      for (int i = 0; i < 2; ++i)
        #pragma unroll
        for (int r = 0; r < 4; ++r){
          const int prow = i*16 + l4*4 + r;
          const int swp = (prow & 7) << 3;
          float ps = 0.f;
          #pragma unroll
          for (int jb = 0; jb < 4; ++jb){
            const float p = __expf(s_[i][jb][r] - m_[i][r]);
            ps += p;
            pbuf[w][prow*64 + ((jb*16 + l15) ^ swp)] = f2bf(p);
          }
          #pragma unroll
          for (int d = 1; d < 16; d <<= 1)
            ps += __shfl_xor(ps, d, 64);
          l_[i][r] += ps;
        }
    } else {
      #pragma unroll
      for (int i = 0; i < 2; ++i)
        #pragma unroll
        for (int r = 0; r < 4; ++r){
          const int prow = i*16 + l4*4 + r;
          const float mnew = fmaxf(m_[i][r], mxs[i][r]);
          const float corr = __expf(m_[i][r] - mnew);
          m_[i][r] = mnew;
          float ps = 0.f;
          const int swp = (prow & 7) << 3;
          #pragma unroll
          for (int jb = 0; jb < 4; ++jb){
            const float p = __expf(s_[i][jb][r] - mnew);
            ps += p;
            pbuf[w][prow*64 + ((jb*16 + l15) ^ swp)] = f2bf(p);
          }
          #pragma unroll
          for (int d = 1; d < 16; d <<= 1)
            ps += __shfl_xor(ps, d, 64);
          l_[i][r] = l_[i][r] * corr + ps;
          #pragma unroll
          for (int j2 = 0; j2 < 4; ++j2) acc_o[i][j2][r] *= corr;
        }
    }

    bf16x8 vfr[4][2];
    #pragma unroll
    for (int j2 = 0; j2 < 4; ++j2){
      const int dim = j2*16 + l15;
      const int sw = (dim & 7) << 3;
      #pragma unroll
      for (int kc = 0; kc < 2; ++kc)
        vfr[j2][kc] = *(const bf16x8*)&vtbuf[dim*64 + ((kc*32 + l4*8) ^ sw)];
    }
    #pragma unroll
    for (int i = 0; i < 2; ++i){
      const int prow = i*16 + l15;
      const int swp = (prow & 7) << 3;
      bf16x8 pa0 = *(const bf16x8*)&pbuf[w][prow*64 + ((l4*8) ^ swp)];
      bf16x8 pa1 = *(const bf16x8*)&pbuf[w][prow*64 + ((32 + l4*8) ^ swp)];
      #pragma unroll
      for (int j2 = 0; j2 < 4; ++j2){
        acc_o[i][j2] = __builtin_amdgcn_mfma_f32_16x16x32_bf16(pa0, vfr[j2][0], acc_o[i][j2], 0,0,0);
        acc_o[i][j2] = __builtin_amdgcn_mfma_f32_16x16x32_bf16(pa1, vfr[j2][1], acc_o[i][j2], 0,0,0);
      }
    }
  }

  #pragma unroll
  for (int i = 0; i < 2; ++i){
    #pragma unroll
    for (int r = 0; r < 4; ++r){
      const int qrow = qt*128 + w*32 + i*16 + l4*4 + r;
      const float inv = 1.f / l_[i][r];
      const size_t ob = ((size_t)b*256 + qrow)*512 + h*64;
      #pragma unroll
      for (int j2 = 0; j2 < 4; ++j2)
        out[ob + j2*16 + l15] = f2bf(acc_o[i][j2][r] * inv);
    }
  }
}

// -------- fused residual + LayerNorm + npm (v2: wave-per-row, no LDS) --------
template<int RF32>
__global__ __launch_bounds__(256) void ln_fused(
    const u16* a, const void* __restrict__ res,
    const float* __restrict__ sc, const float* __restrict__ bs,
    const float* __restrict__ npm, u16* out)
{
  const int w = threadIdx.x >> 6, lane = threadIdx.x & 63;
  const int row = blockIdx.x * 4 + w;
  const size_t bse = (size_t)row * 1024 + lane * 16;

  u16x8 av0 = *(const u16x8*)&a[bse];
  u16x8 av1 = *(const u16x8*)&a[bse + 8];
  float rv[16];
  if (RF32){
    const float* rp = (const float*)res + bse;
    #pragma unroll
    for (int j = 0; j < 16; j += 4){
      f32x4 q = *(const f32x4*)&rp[j];
      rv[j] = q[0]; rv[j+1] = q[1]; rv[j+2] = q[2]; rv[j+3] = q[3];
    }
  } else {
    const u16* rp = (const u16*)res + bse;
    u16x8 q0 = *(const u16x8*)rp;
    u16x8 q1 = *(const u16x8*)(rp + 8);
    #pragma unroll
    for (int j = 0; j < 8; ++j){ rv[j] = bf2f(q0[j]); rv[8+j] = bf2f(q1[j]); }
  }

  float vv[16]; float s = 0.f, sq = 0.f;
  #pragma unroll
  for (int j = 0; j < 8; ++j){
    vv[j]   = bf2f(av0[j]) + rv[j];
    vv[8+j] = bf2f(av1[j]) + rv[8+j];
  }
  #pragma unroll
  for (int j = 0; j < 16; ++j){ s += vv[j]; sq += vv[j]*vv[j]; }
  #pragma unroll
  for (int i = 1; i < 64; i <<= 1){
    s  += __shfl_xor(s,  i, 64);
    sq += __shfl_xor(sq, i, 64);
  }
  const float mean = s * (1.f/1024.f);
  const float var  = sq * (1.f/1024.f) - mean*mean;
  const float rstd = rsqrtf(var + 1e-5f);
  const float nm   = npm[row];

  u16x8 o0, o1;
  #pragma unroll
  for (int j = 0; j < 8; ++j){
    const int c0 = lane*16 + j, c1 = c0 + 8;
    o0[j] = f2bf(((vv[j]   - mean) * rstd * sc[c0] + bs[c0]) * nm);
    o1[j] = f2bf(((vv[8+j] - mean) * rstd * sc[c1] + bs[c1]) * nm);
  }
  *(u16x8*)&out[bse]     = o0;
  *(u16x8*)&out[bse + 8] = o1;
}

// ---------------- launcher ---------------------------------------------------
extern "C" void kernel_launch(void* const* d_in, const int* in_sizes, int n_in,
                              void* d_out, int out_size, void* d_ws, size_t ws_size,
                              hipStream_t stream)
{
  // ws (u16 el), 112 MiB (proven):
  //  W  [0, 8388608): wqkvT0 @0 | wqkvT1 @1572864 (contiguous => B cat) |
  //                   woT0 @3145728 | woT1 @3670016 | fcT @4194304 |
  //                   masks @6291456 (ph1) -> w1T @6291456 (ph2b) |
  //                   w2T @0 (ph2b, wqkvT dead)
  //  R1 [8388608, 25165824):  xbf (ph1) -> tmp0 -> xg (in-place LN)
  //  R2R3 [25165824, 58720256): ph1: qkv1 [25165824,50331648)
  //       then attnb0 @25165824 (qkv1 dead) | tmp1/xl @41943040
  //       ph2b: ln1 @25165824
  // d_out (u16): ph1: qkv0 [0,25165824) | attnb1 [25165824,33554432)
  //              ph2b: hbuf = FULL d_out [16384][2048]
  const size_t NEED = 58720256ull * 2ull;
  if (ws_size < NEED){
    zero_out<<<4096, 256, 0, stream>>>((float*)d_out, out_size);
    return;
  }

  const float* x   = (const float*)d_in[0];
  const int*   adj = (const int*)d_in[1];
  const float* npm = (const float*)d_in[2];
  const int*   slf = (const int*)d_in[3];
  const float* fcw = (const float*)d_in[30];
  const float* fcb = (const float*)d_in[31];

  u16* ws     = (u16*)d_ws;
  u16* wqkvT0 = ws;                    // [3072][1024] cat starts here
  u16* wqkvT1 = ws + 1572864;
  u16* woT0   = ws + 3145728;
  u16* woT1   = ws + 3670016;
  u16* fcT    = ws + 4194304;
  u64* mb_g   = (u64*)(ws + 6291456);  // ph1 only (w1T slot)
  u64* mb_l   = mb_g + 65536;
  u16* w1T    = ws + 6291456;          // ph2b
  u16* w2T    = ws;                    // ph2b (wqkvT dead)
  u16* xbf    = ws + 8388608;          // R1: then tmp0/xg
  u16* tmp0   = ws + 8388608;
  u16* qkv1   = ws + 25165824;         // ph1: [16384][1536]
  u16* attnb0 = ws + 25165824;         // after attn L0 (qkv1 dead)
  u16* ln1    = ws + 25165824;         // ph2b
  u16* tmp1   = ws + 41943040;         // after attn L1/out-proj (qkv1 tail dead)

  u16* dout16 = (u16*)d_out;
  u16* qkv0   = dout16;                // [16384][1536] (ph1)
  u16* attnb1 = dout16 + 25165824;     // [16384][512] (ph1 tail)
  u16* hbuf   = dout16;                // [16384][2048] (ph2b)

  cvt_bf16<<<8192, 256, 0, stream>>>(x, xbf);
  mask_pack<<<16384, 256, 0, stream>>>(slf, adj, mb_g, mb_l);
  transpose_w<<<dim3(64, 32), 256, 0, stream>>>(fcw, fcT, 2048, 1024, 0);
  transpose_qkv6<<<dim3(32, 16, 6), 256, 0, stream>>>(
      (const float*)d_in[4+0], (const float*)d_in[4+1], (const float*)d_in[4+2],
      (const float*)d_in[17+0], (const float*)d_in[17+1], (const float*)d_in[17+2],
      wqkvT0, wqkvT1);
  transpose_wo2<<<dim3(16, 32, 2), 256, 0, stream>>>(
      (const float*)d_in[4+3], (const float*)d_in[17+3], woT0, woT1);

  // Phase 1: merged QKV for BOTH layers (768 blocks = 3 exact rounds),
  // N-split epilogue: cols [0,1536) -> qkv0 (d_out), [1536,3072) -> qkv1 (ws)
  gemm256<0,0,0,1><<<dim3(64, 12), 512, 0, stream>>>(
      xbf, xbf, 1024, 1024, wqkvT0, 1024, 16384, 3072, 1024,
      nullptr, qkv0, 1536, qkv1, 1536);
  // attn L1 first (reads qkv1 in ws, writes attnb1 to d_out tail),
  // then attn L0 (reads qkv0 in d_out, writes attnb0 over dead qkv1)
  attn_mfma<<<1024, 256, 0, stream>>>(qkv1, mb_l, attnb1);
  attn_mfma<<<1024, 256, 0, stream>>>(qkv0, mb_g, attnb0);

  // Phase 2a: both out-projections (frees d_out for hbuf)
  gemm256<0,0,0,0><<<dim3(64, 4), 512, 0, stream>>>(
      attnb0, attnb0, 512, 512, woT0, 512, 16384, 1024, 512,
      (const float*)d_in[4+4], tmp0, 1024, nullptr, 0);
  gemm256<0,0,0,0><<<dim3(64, 4), 512, 0, stream>>>(
      attnb1, attnb1, 512, 512, woT1, 512, 16384, 1024, 512,
      (const float*)d_in[17+4], tmp1, 1024, nullptr, 0);

  // Phase 2b: layer bodies (hbuf = full d_out; FFN unsplit)
  for (int L = 0; L < 2; ++L){
    const int bi = 4 + L*13;
    const float* l1s = (const float*)d_in[bi+5];
    const float* l1b = (const float*)d_in[bi+6];
    const float* b1  = (const float*)d_in[bi+8];
    const float* b2  = (const float*)d_in[bi+10];
    const float* l2s = (const float*)d_in[bi+11];
    const float* l2b = (const float*)d_in[bi+12];
    u16* tmpL = L ? tmp1 : tmp0;

    transpose_w<<<dim3(32, 64), 256, 0, stream>>>((const float*)d_in[bi+7], w1T, 1024, 2048, 0);
    transpose_w<<<dim3(64, 32), 256, 0, stream>>>((const float*)d_in[bi+9], w2T, 2048, 1024, 0);

    // ln1 = LN(tmpL + x) * npm -> R2
    ln_fused<1><<<4096, 256, 0, stream>>>(tmpL, x, l1s, l1b, npm, ln1);
    // hbuf = relu(ln1 @ w1T + b1)   [16384][2048]
    gemm256<1,0,0,0><<<dim3(64, 8), 512, 0, stream>>>(
        ln1, ln1, 1024, 1024, w1T, 1024, 16384, 2048, 1024, b1, hbuf, 2048,
        nullptr, 0);
    // tmpL = hbuf @ w2T + b2
    gemm256<0,0,0,0><<<dim3(64, 4), 512, 0, stream>>>(
        hbuf, hbuf, 2048, 2048, w2T, 2048, 16384, 1024, 2048, b2, tmpL, 1024,
        nullptr, 0);
    // xout = LN(tmpL + ln1) * npm, in-place -> tmpL (xg = R1 / xl = R3)
    ln_fused<0><<<4096, 256, 0, stream>>>(tmpL, ln1, l2s, l2b, npm, tmpL);
  }

  // final: [xg | xl] @ fcT + fc_b -> d_out (f32), K split at 1024
  gemm256<0,1,0,0><<<dim3(64, 4), 512, 0, stream>>>(
      tmp0, tmp1, 1024, 1024, fcT, 2048, 16384, 1024, 2048, fcb, d_out, 1024,
      nullptr, 0);
}

// Round 18
// 683.670 us; speedup vs baseline: 1.2608x; 1.0069x over previous
//
#include <hip/hip_runtime.h>

// GLAT: B=64, N=256, D=1024, H=8, DK=64, DI=2048.
// I/O dtype: float32. Internal: bf16 MFMA + f32 accum. adj/slf: int32.

typedef unsigned short u16;
typedef unsigned long long u64;
typedef __bf16 bf16_t;
typedef bf16_t bf16x8 __attribute__((ext_vector_type(8)));
typedef float  f32x4  __attribute__((ext_vector_type(4)));
typedef u16    u16x8  __attribute__((ext_vector_type(8)));
typedef u16    u16x4  __attribute__((ext_vector_type(4)));

__device__ __forceinline__ float bf2f(u16 u){
  union { unsigned int i; float f; } c; c.i = ((unsigned int)u) << 16; return c.f;
}
__device__ __forceinline__ u16 f2bf(float f){
  union { float f; unsigned int u; } c; c.f = f;
  unsigned int u = c.u;
  unsigned int r = (u + 0x7fffu + ((u >> 16) & 1u)) >> 16;  // RNE
  return (u16)r;
}

// async 16B global -> LDS (direct). LDS dest = wave-uniform base + lane*16.
__device__ __forceinline__ void gl16(const u16* g, u16* l){
  __builtin_amdgcn_global_load_lds(
      (const __attribute__((address_space(1))) void*)g,
      (__attribute__((address_space(3))) void*)l, 16, 0, 0);
}

// ---------------- diagnostic fallback: zero d_out (f32) ----------------------
__global__ __launch_bounds__(256) void zero_out(float* out, int n){
  for (int i = blockIdx.x * 256 + threadIdx.x; i < n; i += 256 * 4096) out[i] = 0.f;
}

// ---------------- f32 -> bf16 bulk convert (8 elems/thread) ------------------
__global__ __launch_bounds__(256) void cvt_bf16(
    const float* __restrict__ in, u16* __restrict__ out)
{
  const size_t i = ((size_t)blockIdx.x * 256 + threadIdx.x) * 8;
  f32x4 a = *(const f32x4*)&in[i];
  f32x4 b = *(const f32x4*)&in[i + 4];
  u16x8 o;
  #pragma unroll
  for (int j = 0; j < 4; ++j){ o[j] = f2bf(a[j]); o[4+j] = f2bf(b[j]); }
  *(u16x8*)&out[i] = o;
}

// -------- weight transpose+convert: src f32 [K][N] -> dst bf16 [(off+n)*K+k] --
__global__ __launch_bounds__(256) void transpose_w(
    const float* __restrict__ src, u16* __restrict__ dst, int K, int N, int dstOff)
{
  __shared__ u16 tile[32][33];
  const int bk = blockIdx.x * 32, bn = blockIdx.y * 32;
  const int t = threadIdx.x;
  const int r = t >> 5, c = t & 31;
  #pragma unroll
  for (int p = 0; p < 4; ++p)
    tile[r + p*8][c] = f2bf(src[(size_t)(bk + r + p*8) * N + bn + c]);
  __syncthreads();
  #pragma unroll
  for (int p = 0; p < 4; ++p)
    dst[(size_t)(dstOff + bn + r + p*8) * K + bk + c] = tile[c][r + p*8];
}

// -------- 6-source QKV transpose: both layers' wq/wk/wv (K=1024, N=512) ------
__global__ __launch_bounds__(256) void transpose_qkv6(
    const float* s0, const float* s1, const float* s2,
    const float* s3, const float* s4, const float* s5,
    u16* __restrict__ dst0, u16* __restrict__ dst1)
{
  __shared__ u16 tile[32][33];
  const int z = blockIdx.z;
  const float* src = z == 0 ? s0 : z == 1 ? s1 : z == 2 ? s2
                   : z == 3 ? s3 : z == 4 ? s4 : s5;
  u16* dst = (z < 3 ? dst0 : dst1);
  const int dstOff = (z % 3) * 512;
  const int K = 1024, N = 512;
  const int bk = blockIdx.x * 32, bn = blockIdx.y * 32;
  const int t = threadIdx.x;
  const int r = t >> 5, c = t & 31;
  #pragma unroll
  for (int p = 0; p < 4; ++p)
    tile[r + p*8][c] = f2bf(src[(size_t)(bk + r + p*8) * N + bn + c]);
  __syncthreads();
  #pragma unroll
  for (int p = 0; p < 4; ++p)
    dst[(size_t)(dstOff + bn + r + p*8) * K + bk + c] = tile[c][r + p*8];
}

// -------- 2-source wo transpose (K=512, N=1024) ------------------------------
__global__ __launch_bounds__(256) void transpose_wo2(
    const float* s0, const float* s1, u16* __restrict__ dst0, u16* __restrict__ dst1)
{
  __shared__ u16 tile[32][33];
  const float* src = blockIdx.z == 0 ? s0 : s1;
  u16* dst = blockIdx.z == 0 ? dst0 : dst1;
  const int K = 512, N = 1024;
  const int bk = blockIdx.x * 32, bn = blockIdx.y * 32;
  const int t = threadIdx.x;
  const int r = t >> 5, c = t & 31;
  #pragma unroll
  for (int p = 0; p < 4; ++p)
    tile[r + p*8][c] = f2bf(src[(size_t)(bk + r + p*8) * N + bn + c]);
  __syncthreads();
  #pragma unroll
  for (int p = 0; p < 4; ++p)
    dst[(size_t)(bn + r + p*8) * K + bk + c] = tile[c][r + p*8];
}

// ---- GEMM 256x256, BK=64, 8 waves, dbuf LDS, quadrant-phase schedule -------
// r10 schedule, FROZEN. (512,1): LDS already caps at 1 block/CU, so the old
// min-2-waves hint only capped VGPRs at 128 for nothing; let RA use more.
template<int RELU, int OF32, int ACC, int OUT2>
__global__ __launch_bounds__(512, 1) void gemm256(
    const u16* __restrict__ A0, const u16* __restrict__ A1,
    int Astride, int ksplit,
    const u16* __restrict__ BT, int Bld, int M, int N, int K,
    const float* __restrict__ bias, void* __restrict__ outv, int out_ld,
    u16* __restrict__ out2v, int ncut)
{
  __shared__ u16 lds[2*32768];           // 128 KiB
  const int tid  = threadIdx.x;
  const int lane = tid & 63;
  const int wid  = tid >> 6;             // 0..7
  const int wm = wid >> 2, wn = wid & 3; // 2M x 4N waves
  const int l15 = lane & 15, l4 = lane >> 4;
  const int m0 = blockIdx.x * 256, n0 = blockIdx.y * 256;

  f32x4 acc[8][4];
  #pragma unroll
  for (int i = 0; i < 8; ++i)
    #pragma unroll
    for (int j = 0; j < 4; ++j)
      acc[i][j] = (f32x4){0.f, 0.f, 0.f, 0.f};

  const int s0 = tid, s1 = tid + 512;
  const int r0 = s0 >> 3, g0 = (s0 & 7) ^ (r0 & 7);
  const int r1 = s1 >> 3, g1 = (s1 & 7) ^ (r1 & 7);

  const int nt = K >> 6;

  auto stageA = [&](int kt, int h, int buf){
    const int kb = kt * 64;
    const u16* Ab = A0; int kl = kb;
    if (kb >= ksplit){ Ab = A1; kl = kb - ksplit; }
    u16* dst = &lds[buf*32768 + h*8192];
    gl16(&Ab[(size_t)(m0 + h*128 + r0) * Astride + kl + g0*8], &dst[s0*8]);
    gl16(&Ab[(size_t)(m0 + h*128 + r1) * Astride + kl + g1*8], &dst[s1*8]);
  };
  auto stageB = [&](int kt, int h, int buf){
    const int kb = kt * 64;
    u16* dst = &lds[buf*32768 + 16384 + h*8192];
    gl16(&BT[(size_t)(n0 + h*128 + r0) * Bld + kb + g0*8], &dst[s0*8]);
    gl16(&BT[(size_t)(n0 + h*128 + r1) * Bld + kb + g1*8], &dst[s1*8]);
  };
  auto lda = [&](int i, int kc, int buf) -> bf16x8 {
    const int r = wm*128 + i*16 + l15;
    const int c = (kc*4 + l4) ^ (r & 7);
    return *(const bf16x8*)&lds[buf*32768 + r*64 + c*8];
  };
  auto ldb = [&](int j, int kc, int buf) -> bf16x8 {
    const int r = wn*64 + j*16 + l15;
    const int c = (kc*4 + l4) ^ (r & 7);
    return *(const bf16x8*)&lds[buf*32768 + 16384 + r*64 + c*8];
  };

  // prologue: stage tile 0 fully (8 loads)
  stageA(0, 0, 0); stageA(0, 1, 0); stageB(0, 0, 0); stageB(0, 1, 0);

  for (int t = 0; t < nt; ++t){
    const int buf = t & 1, nbuf = buf ^ 1;
    const bool pf = (t + 1 < nt);
    if (pf){
      stageA(t+1, 0, nbuf);
      asm volatile("s_waitcnt vmcnt(2)" ::: "memory");  // tile t's 8 landed
    } else {
      asm volatile("s_waitcnt vmcnt(0)" ::: "memory");
    }
    __builtin_amdgcn_sched_barrier(0);
    __builtin_amdgcn_s_barrier();          // all waves' tile-t loads landed
    __builtin_amdgcn_sched_barrier(0);

    bf16x8 a_[4][2], b_[2][2];
    // ---- Q0: A-lo x B-lo ----
    #pragma unroll
    for (int i = 0; i < 4; ++i){ a_[i][0] = lda(i, 0, buf); a_[i][1] = lda(i, 1, buf); }
    #pragma unroll
    for (int j = 0; j < 2; ++j){ b_[j][0] = ldb(j, 0, buf); b_[j][1] = ldb(j, 1, buf); }
    if (pf) stageA(t+1, 1, nbuf);
    __builtin_amdgcn_s_setprio(1);
    #pragma unroll
    for (int i = 0; i < 4; ++i)
      #pragma unroll
      for (int j = 0; j < 2; ++j){
        acc[i][j] = __builtin_amdgcn_mfma_f32_16x16x32_bf16(a_[i][0], b_[j][0], acc[i][j], 0,0,0);
        acc[i][j] = __builtin_amdgcn_mfma_f32_16x16x32_bf16(a_[i][1], b_[j][1], acc[i][j], 0,0,0);
      }
    __builtin_amdgcn_s_setprio(0);
    // ---- Q1: A-lo x B-hi ----
    #pragma unroll
    for (int j = 0; j < 2; ++j){ b_[j][0] = ldb(2+j, 0, buf); b_[j][1] = ldb(2+j, 1, buf); }
    if (pf) stageB(t+1, 0, nbuf);
    __builtin_amdgcn_s_setprio(1);
    #pragma unroll
    for (int i = 0; i < 4; ++i)
      #pragma unroll
      for (int j = 0; j < 2; ++j){
        acc[i][2+j] = __builtin_amdgcn_mfma_f32_16x16x32_bf16(a_[i][0], b_[j][0], acc[i][2+j], 0,0,0);
        acc[i][2+j] = __builtin_amdgcn_mfma_f32_16x16x32_bf16(a_[i][1], b_[j][1], acc[i][2+j], 0,0,0);
      }
    __builtin_amdgcn_s_setprio(0);
    // ---- Q2: A-hi x B-hi ----
    #pragma unroll
    for (int i = 0; i < 4; ++i){ a_[i][0] = lda(4+i, 0, buf); a_[i][1] = lda(4+i, 1, buf); }
    if (pf) stageB(t+1, 1, nbuf);
    __builtin_amdgcn_s_setprio(1);
    #pragma unroll
    for (int i = 0; i < 4; ++i)
      #pragma unroll
      for (int j = 0; j < 2; ++j){
        acc[4+i][2+j] = __builtin_amdgcn_mfma_f32_16x16x32_bf16(a_[i][0], b_[j][0], acc[4+i][2+j], 0,0,0);
        acc[4+i][2+j] = __builtin_amdgcn_mfma_f32_16x16x32_bf16(a_[i][1], b_[j][1], acc[4+i][2+j], 0,0,0);
      }
    __builtin_amdgcn_s_setprio(0);
    // ---- Q3: A-hi x B-lo (re-read b_lo) ----
    #pragma unroll
    for (int j = 0; j < 2; ++j){ b_[j][0] = ldb(j, 0, buf); b_[j][1] = ldb(j, 1, buf); }
    __builtin_amdgcn_s_setprio(1);
    #pragma unroll
    for (int i = 0; i < 4; ++i)
      #pragma unroll
      for (int j = 0; j < 2; ++j){
        acc[4+i][j] = __builtin_amdgcn_mfma_f32_16x16x32_bf16(a_[i][0], b_[j][0], acc[4+i][j], 0,0,0);
        acc[4+i][j] = __builtin_amdgcn_mfma_f32_16x16x32_bf16(a_[i][1], b_[j][1], acc[4+i][j], 0,0,0);
      }
    __builtin_amdgcn_s_setprio(0);

    __builtin_amdgcn_sched_barrier(0);
    __builtin_amdgcn_s_barrier();          // all reads of buf done
    __builtin_amdgcn_sched_barrier(0);
  }

  // epilogue: C[row][col], row=(lane>>4)*4+r, col=lane&15 (m89-verified)
  u16* outp = (u16*)outv;
  int cadj = 0;
  if (OUT2 && n0 >= ncut){ outp = out2v; cadj = ncut; }
  const int rb = m0 + wm*128 + l4*4;
  const int cb = n0 + wn*64 + l15;
  #pragma unroll
  for (int i = 0; i < 8; ++i){
    #pragma unroll
    for (int j = 0; j < 4; ++j){
      const int col = cb + j*16;
      const float badd = bias ? bias[col] : 0.f;
      #pragma unroll
      for (int r = 0; r < 4; ++r){
        const int row = rb + i*16 + r;
        float y = acc[i][j][r] + badd;
        if (RELU) y = y > 0.f ? y : 0.f;
        if (OF32){
          float* po = &((float*)outv)[(size_t)row * out_ld + col];
          if (ACC) y += *po;
          *po = y;
        } else {
          u16* po = &outp[(size_t)row * out_ld + col - cadj];
          if (ACC) y += bf2f(*po);
          *po = f2bf(y);
        }
      }
    }
  }
}

// -------- mask pack: bit k of mb[row][c] = mask(row, c*64+k) -----------------
__global__ __launch_bounds__(256) void mask_pack(
    const int* __restrict__ slf, const int* __restrict__ adj,
    u64* __restrict__ mb_g, u64* __restrict__ mb_l)
{
  const int idx  = blockIdx.x * 4 + (threadIdx.x >> 6);  // (row, c) pair
  const int lane = threadIdx.x & 63;
  const size_t mi = (size_t)(idx >> 2) * 256 + (size_t)(idx & 3) * 64 + lane;
  const bool g = slf[mi] != 0;
  const bool l = g || (adj[mi] == 0);
  const u64 bg = __ballot(g);
  const u64 bl = __ballot(l);
  if (lane == 0){ mb_g[idx] = bg; mb_l[idx] = bl; }
}

// ---------------- MFMA flash attention (T13 defer-max, both layers) ----------
// grid (1024, 2): blockIdx.y = layer; per-block-uniform pointer select.
// block = (b, h, qtile of 128 rows); 4 waves x 32 q-rows.
__global__ __launch_bounds__(256) void attn_mfma(
    const u16* __restrict__ qkv0, const u16* __restrict__ qkv1,
    const u64* __restrict__ mb0, const u64* __restrict__ mb1,
    u16* __restrict__ out0, u16* __restrict__ out1)
{
  __shared__ u16 kbuf[64*64];     // [key][dim], swizzled col ^= (key&7)<<3
  __shared__ u16 vtbuf[64*64];    // [dim][key], swizzled col ^= (dim&7)<<3
  __shared__ u16 pbuf[4][32*64];  // per-wave P [row][key], swizzled

  const int L  = blockIdx.y;
  const u16* qkv = L ? qkv1 : qkv0;
  const u64* mb  = L ? mb1  : mb0;
  u16*       out = L ? out1 : out0;

  const int b  = blockIdx.x >> 4;
  const int h  = (blockIdx.x >> 1) & 7;
  const int qt = blockIdx.x & 1;
  const int t  = threadIdx.x;
  const int w  = t >> 6, lane = t & 63;
  const int l15 = lane & 15, l4 = lane >> 4;

  bf16x8 qf[2][2];
  {
    const int rbase = b*256 + qt*128 + w*32;
    #pragma unroll
    for (int i = 0; i < 2; ++i)
      #pragma unroll
      for (int kc = 0; kc < 2; ++kc)
        qf[i][kc] = *(const bf16x8*)&qkv[(size_t)(rbase + i*16 + l15)*1536 + h*64 + kc*32 + l4*8];
  }

  f32x4 acc_o[2][4];
  float m_[2][4], l_[2][4];
  #pragma unroll
  for (int i = 0; i < 2; ++i){
    #pragma unroll
    for (int j = 0; j < 4; ++j) acc_o[i][j] = (f32x4){0.f,0.f,0.f,0.f};
    #pragma unroll
    for (int r = 0; r < 4; ++r){ m_[i][r] = -1e30f; l_[i][r] = 0.f; }
  }

  for (int c = 0; c < 4; ++c){
    __syncthreads();
    {   // stage K and V^T (swizzled); thread -> key row t>>2, dim group (t&3)*16
      const int kr = t >> 2, dg = (t & 3) * 16;
      const size_t rbase = (size_t)(b*256 + c*64 + kr)*1536 + h*64 + dg;
      u16x8 k0 = *(const u16x8*)&qkv[rbase + 512];
      u16x8 k1 = *(const u16x8*)&qkv[rbase + 512 + 8];
      u16x8 v0 = *(const u16x8*)&qkv[rbase + 1024];
      u16x8 v1 = *(const u16x8*)&qkv[rbase + 1024 + 8];
      const int sw = (kr & 7) << 3;
      *(u16x8*)&kbuf[kr*64 + (dg ^ sw)]       = k0;
      *(u16x8*)&kbuf[kr*64 + ((dg + 8) ^ sw)] = k1;
      #pragma unroll
      for (int e = 0; e < 8; ++e){
        const int d0 = dg + e, d1 = dg + 8 + e;
        vtbuf[d0*64 + (kr ^ ((d0 & 7) << 3))] = v0[e];
        vtbuf[d1*64 + (kr ^ ((d1 & 7) << 3))] = v1[e];
      }
    }
    __syncthreads();

    bf16x8 kfr[4][2];
    #pragma unroll
    for (int jb = 0; jb < 4; ++jb){
      const int key = jb*16 + l15;
      const int sw = (key & 7) << 3;
      #pragma unroll
      for (int kc = 0; kc < 2; ++kc)
        kfr[jb][kc] = *(const bf16x8*)&kbuf[key*64 + ((kc*32 + l4*8) ^ sw)];
    }
    f32x4 s_[2][4];
    #pragma unroll
    for (int i = 0; i < 2; ++i)
      #pragma unroll
      for (int jb = 0; jb < 4; ++jb){
        f32x4 a = (f32x4){0.f,0.f,0.f,0.f};
        a = __builtin_amdgcn_mfma_f32_16x16x32_bf16(qf[i][0], kfr[jb][0], a, 0,0,0);
        a = __builtin_amdgcn_mfma_f32_16x16x32_bf16(qf[i][1], kfr[jb][1], a, 0,0,0);
        s_[i][jb] = a;
      }

    // scale + mask in place
    #pragma unroll
    for (int i = 0; i < 2; ++i)
      #pragma unroll
      for (int r = 0; r < 4; ++r){
        const int qrow = qt*128 + w*32 + i*16 + l4*4 + r;
        const u64 bits = mb[((size_t)b*256 + qrow)*4 + c];
        #pragma unroll
        for (int jb = 0; jb < 4; ++jb){
          float xv = s_[i][jb][r] * 0.125f;
          if ((bits >> (jb*16 + l15)) & 1ull) xv = -1e9f;
          s_[i][jb][r] = xv;
        }
      }
    // row maxes + defer-max vote (T13, THR=8)
    float mxs[2][4];
    bool okall = true;
    #pragma unroll
    for (int i = 0; i < 2; ++i)
      #pragma unroll
      for (int r = 0; r < 4; ++r){
        float mx = fmaxf(fmaxf(s_[i][0][r], s_[i][1][r]),
                         fmaxf(s_[i][2][r], s_[i][3][r]));
        #pragma unroll
        for (int d = 1; d < 16; d <<= 1)
          mx = fmaxf(mx, __shfl_xor(mx, d, 64));
        mxs[i][r] = mx;
        okall = okall && (mx <= m_[i][r] + 8.f);
      }
    if (__all(okall)){
      // deferred: keep m_old, no O/l rescale (P bounded by e^8)
      #pragma unroll
      for (int i = 0; i < 2; ++i)
        #pragma unroll
        for (int r = 0; r < 4; ++r){
          const int prow = i*16 + l4*4 + r;
          const int swp = (prow & 7) << 3;
          float ps = 0.f;
          #pragma unroll
          for (int jb = 0; jb < 4; ++jb){
            const float p = __expf(s_[i][jb][r] - m_[i][r]);
            ps += p;
            pbuf[w][prow*64 + ((jb*16 + l15) ^ swp)] = f2bf(p);
          }
          #pragma unroll
          for (int d = 1; d < 16; d <<= 1)
            ps += __shfl_xor(ps, d, 64);
          l_[i][r] += ps;
        }
    } else {
      #pragma unroll
      for (int i = 0; i < 2; ++i)
        #pragma unroll
        for (int r = 0; r < 4; ++r){
          const int prow = i*16 + l4*4 + r;
          const float mnew = fmaxf(m_[i][r], mxs[i][r]);
          const float corr = __expf(m_[i][r] - mnew);
          m_[i][r] = mnew;
          float ps = 0.f;
          const int swp = (prow & 7) << 3;
          #pragma unroll
          for (int jb = 0; jb < 4; ++jb){
            const float p = __expf(s_[i][jb][r] - mnew);
            ps += p;
            pbuf[w][prow*64 + ((jb*16 + l15) ^ swp)] = f2bf(p);
          }
          #pragma unroll
          for (int d = 1; d < 16; d <<= 1)
            ps += __shfl_xor(ps, d, 64);
          l_[i][r] = l_[i][r] * corr + ps;
          #pragma unroll
          for (int j2 = 0; j2 < 4; ++j2) acc_o[i][j2][r] *= corr;
        }
    }

    bf16x8 vfr[4][2];
    #pragma unroll
    for (int j2 = 0; j2 < 4; ++j2){
      const int dim = j2*16 + l15;
      const int sw = (dim & 7) << 3;
      #pragma unroll
      for (int kc = 0; kc < 2; ++kc)
        vfr[j2][kc] = *(const bf16x8*)&vtbuf[dim*64 + ((kc*32 + l4*8) ^ sw)];
    }
    #pragma unroll
    for (int i = 0; i < 2; ++i){
      const int prow = i*16 + l15;
      const int swp = (prow & 7) << 3;
      bf16x8 pa0 = *(const bf16x8*)&pbuf[w][prow*64 + ((l4*8) ^ swp)];
      bf16x8 pa1 = *(const bf16x8*)&pbuf[w][prow*64 + ((32 + l4*8) ^ swp)];
      #pragma unroll
      for (int j2 = 0; j2 < 4; ++j2){
        acc_o[i][j2] = __builtin_amdgcn_mfma_f32_16x16x32_bf16(pa0, vfr[j2][0], acc_o[i][j2], 0,0,0);
        acc_o[i][j2] = __builtin_amdgcn_mfma_f32_16x16x32_bf16(pa1, vfr[j2][1], acc_o[i][j2], 0,0,0);
      }
    }
  }

  #pragma unroll
  for (int i = 0; i < 2; ++i){
    #pragma unroll
    for (int r = 0; r < 4; ++r){
      const int qrow = qt*128 + w*32 + i*16 + l4*4 + r;
      const float inv = 1.f / l_[i][r];
      const size_t ob = ((size_t)b*256 + qrow)*512 + h*64;
      #pragma unroll
      for (int j2 = 0; j2 < 4; ++j2)
        out[ob + j2*16 + l15] = f2bf(acc_o[i][j2][r] * inv);
    }
  }
}

// -------- fused residual + LayerNorm + npm (v2: wave-per-row, no LDS) --------
template<int RF32>
__global__ __launch_bounds__(256) void ln_fused(
    const u16* a, const void* __restrict__ res,
    const float* __restrict__ sc, const float* __restrict__ bs,
    const float* __restrict__ npm, u16* out)
{
  const int w = threadIdx.x >> 6, lane = threadIdx.x & 63;
  const int row = blockIdx.x * 4 + w;
  const size_t bse = (size_t)row * 1024 + lane * 16;

  u16x8 av0 = *(const u16x8*)&a[bse];
  u16x8 av1 = *(const u16x8*)&a[bse + 8];
  float rv[16];
  if (RF32){
    const float* rp = (const float*)res + bse;
    #pragma unroll
    for (int j = 0; j < 16; j += 4){
      f32x4 q = *(const f32x4*)&rp[j];
      rv[j] = q[0]; rv[j+1] = q[1]; rv[j+2] = q[2]; rv[j+3] = q[3];
    }
  } else {
    const u16* rp = (const u16*)res + bse;
    u16x8 q0 = *(const u16x8*)rp;
    u16x8 q1 = *(const u16x8*)(rp + 8);
    #pragma unroll
    for (int j = 0; j < 8; ++j){ rv[j] = bf2f(q0[j]); rv[8+j] = bf2f(q1[j]); }
  }

  float vv[16]; float s = 0.f, sq = 0.f;
  #pragma unroll
  for (int j = 0; j < 8; ++j){
    vv[j]   = bf2f(av0[j]) + rv[j];
    vv[8+j] = bf2f(av1[j]) + rv[8+j];
  }
  #pragma unroll
  for (int j = 0; j < 16; ++j){ s += vv[j]; sq += vv[j]*vv[j]; }
  #pragma unroll
  for (int i = 1; i < 64; i <<= 1){
    s  += __shfl_xor(s,  i, 64);
    sq += __shfl_xor(sq, i, 64);
  }
  const float mean = s * (1.f/1024.f);
  const float var  = sq * (1.f/1024.f) - mean*mean;
  const float rstd = rsqrtf(var + 1e-5f);
  const float nm   = npm[row];

  u16x8 o0, o1;
  #pragma unroll
  for (int j = 0; j < 8; ++j){
    const int c0 = lane*16 + j, c1 = c0 + 8;
    o0[j] = f2bf(((vv[j]   - mean) * rstd * sc[c0] + bs[c0]) * nm);
    o1[j] = f2bf(((vv[8+j] - mean) * rstd * sc[c1] + bs[c1]) * nm);
  }
  *(u16x8*)&out[bse]     = o0;
  *(u16x8*)&out[bse + 8] = o1;
}

// ---------------- launcher ---------------------------------------------------
extern "C" void kernel_launch(void* const* d_in, const int* in_sizes, int n_in,
                              void* d_out, int out_size, void* d_ws, size_t ws_size,
                              hipStream_t stream)
{
  // ws (u16 el), 112 MiB (proven):
  //  W  [0, 8388608): wqkvT0 @0 | wqkvT1 @1572864 | woT0 @3145728 |
  //                   woT1 @3670016 | fcT @4194304 |
  //                   masks @6291456 (ph1) -> w1T @6291456 (ph2b) |
  //                   w2T @0 (ph2b, wqkvT dead)
  //  R1 [8388608, 25165824):  xbf (ph1) -> tmp0 -> xg (in-place LN)
  //  [25165824, 50331648): qkv1 (ph1) -> ln1 @25165824 (ph2b) |
  //                        tmp1/xl @41943040 (after attn done with qkv1)
  //  [50331648, 58720256): attnb0 (ph1; disjoint from qkv1 => merged attn safe)
  // d_out (u16): ph1: qkv0 [0,25165824) | attnb1 [25165824,33554432)
  //              ph2b: hbuf = FULL d_out [16384][2048]
  const size_t NEED = 58720256ull * 2ull;
  if (ws_size < NEED){
    zero_out<<<4096, 256, 0, stream>>>((float*)d_out, out_size);
    return;
  }

  const float* x   = (const float*)d_in[0];
  const int*   adj = (const int*)d_in[1];
  const float* npm = (const float*)d_in[2];
  const int*   slf = (const int*)d_in[3];
  const float* fcw = (const float*)d_in[30];
  const float* fcb = (const float*)d_in[31];

  u16* ws     = (u16*)d_ws;
  u16* wqkvT0 = ws;                    // [3072][1024] cat starts here
  u16* wqkvT1 = ws + 1572864;
  u16* woT0   = ws + 3145728;
  u16* woT1   = ws + 3670016;
  u16* fcT    = ws + 4194304;
  u64* mb_g   = (u64*)(ws + 6291456);  // ph1 only (w1T slot)
  u64* mb_l   = mb_g + 65536;
  u16* w1T    = ws + 6291456;          // ph2b
  u16* w2T    = ws;                    // ph2b (wqkvT dead)
  u16* xbf    = ws + 8388608;          // R1: then tmp0/xg
  u16* tmp0   = ws + 8388608;
  u16* qkv1   = ws + 25165824;         // ph1: [16384][1536]
  u16* ln1    = ws + 25165824;         // ph2b
  u16* tmp1   = ws + 41943040;         // after attn (qkv1 tail dead)
  u16* attnb0 = ws + 50331648;         // [16384][512], disjoint from qkv1

  u16* dout16 = (u16*)d_out;
  u16* qkv0   = dout16;                // [16384][1536] (ph1)
  u16* attnb1 = dout16 + 25165824;     // [16384][512] (ph1 tail)
  u16* hbuf   = dout16;                // [16384][2048] (ph2b)

  cvt_bf16<<<8192, 256, 0, stream>>>(x, xbf);
  mask_pack<<<16384, 256, 0, stream>>>(slf, adj, mb_g, mb_l);
  transpose_w<<<dim3(64, 32), 256, 0, stream>>>(fcw, fcT, 2048, 1024, 0);
  transpose_qkv6<<<dim3(32, 16, 6), 256, 0, stream>>>(
      (const float*)d_in[4+0], (const float*)d_in[4+1], (const float*)d_in[4+2],
      (const float*)d_in[17+0], (const float*)d_in[17+1], (const float*)d_in[17+2],
      wqkvT0, wqkvT1);
  transpose_wo2<<<dim3(16, 32, 2), 256, 0, stream>>>(
      (const float*)d_in[4+3], (const float*)d_in[17+3], woT0, woT1);

  // Phase 1: merged QKV for BOTH layers (768 blocks = 3 exact rounds),
  // N-split epilogue: cols [0,1536) -> qkv0 (d_out), [1536,3072) -> qkv1 (ws)
  gemm256<0,0,0,1><<<dim3(64, 12), 512, 0, stream>>>(
      xbf, xbf, 1024, 1024, wqkvT0, 1024, 16384, 3072, 1024,
      nullptr, qkv0, 1536, qkv1, 1536);
  // merged attention: both layers in one dispatch (attnb0 disjoint from qkv1)
  attn_mfma<<<dim3(1024, 2), 256, 0, stream>>>(
      qkv0, qkv1, mb_g, mb_l, attnb0, attnb1);

  // Phase 2a: both out-projections (frees d_out for hbuf)
  gemm256<0,0,0,0><<<dim3(64, 4), 512, 0, stream>>>(
      attnb0, attnb0, 512, 512, woT0, 512, 16384, 1024, 512,
      (const float*)d_in[4+4], tmp0, 1024, nullptr, 0);
  gemm256<0,0,0,0><<<dim3(64, 4), 512, 0, stream>>>(
      attnb1, attnb1, 512, 512, woT1, 512, 16384, 1024, 512,
      (const float*)d_in[17+4], tmp1, 1024, nullptr, 0);

  // Phase 2b: layer bodies (hbuf = full d_out; FFN unsplit)
  for (int L = 0; L < 2; ++L){
    const int bi = 4 + L*13;
    const float* l1s = (const float*)d_in[bi+5];
    const float* l1b = (const float*)d_in[bi+6];
    const float* b1  = (const float*)d_in[bi+8];
    const float* b2  = (const float*)d_in[bi+10];
    const float* l2s = (const float*)d_in[bi+11];
    const float* l2b = (const float*)d_in[bi+12];
    u16* tmpL = L ? tmp1 : tmp0;

    transpose_w<<<dim3(32, 64), 256, 0, stream>>>((const float*)d_in[bi+7], w1T, 1024, 2048, 0);
    transpose_w<<<dim3(64, 32), 256, 0, stream>>>((const float*)d_in[bi+9], w2T, 2048, 1024, 0);

    // ln1 = LN(tmpL + x) * npm -> R2
    ln_fused<1><<<4096, 256, 0, stream>>>(tmpL, x, l1s, l1b, npm, ln1);
    // hbuf = relu(ln1 @ w1T + b1)   [16384][2048]
    gemm256<1,0,0,0><<<dim3(64, 8), 512, 0, stream>>>(
        ln1, ln1, 1024, 1024, w1T, 1024, 16384, 2048, 1024, b1, hbuf, 2048,
        nullptr, 0);
    // tmpL = hbuf @ w2T + b2
    gemm256<0,0,0,0><<<dim3(64, 4), 512, 0, stream>>>(
        hbuf, hbuf, 2048, 2048, w2T, 2048, 16384, 1024, 2048, b2, tmpL, 1024,
        nullptr, 0);
    // xout = LN(tmpL + ln1) * npm, in-place -> tmpL (xg = R1 / xl = R3)
    ln_fused<0><<<4096, 256, 0, stream>>>(tmpL, ln1, l2s, l2b, npm, tmpL);
  }

  // final: [xg | xl] @ fcT + fc_b -> d_out (f32), K split at 1024
  gemm256<0,1,0,0><<<dim3(64, 4), 512, 0, stream>>>(
      tmp0, tmp1, 1024, 1024, fcT, 2048, 16384, 1024, 2048, fcb, d_out, 1024,
      nullptr, 0);
}

// Round 19
// 677.012 us; speedup vs baseline: 1.2732x; 1.0098x over previous
//
#include <hip/hip_runtime.h>

// GLAT: B=64, N=256, D=1024, H=8, DK=64, DI=2048.
// I/O dtype: float32. Internal: bf16 MFMA + f32 accum. adj/slf: int32.

typedef unsigned short u16;
typedef unsigned long long u64;
typedef __bf16 bf16_t;
typedef bf16_t bf16x8 __attribute__((ext_vector_type(8)));
typedef float  f32x4  __attribute__((ext_vector_type(4)));
typedef u16    u16x8  __attribute__((ext_vector_type(8)));
typedef u16    u16x4  __attribute__((ext_vector_type(4)));

__device__ __forceinline__ float bf2f(u16 u){
  union { unsigned int i; float f; } c; c.i = ((unsigned int)u) << 16; return c.f;
}
__device__ __forceinline__ u16 f2bf(float f){
  union { float f; unsigned int u; } c; c.f = f;
  unsigned int u = c.u;
  unsigned int r = (u + 0x7fffu + ((u >> 16) & 1u)) >> 16;  // RNE
  return (u16)r;
}

// async 16B global -> LDS (direct). LDS dest = wave-uniform base + lane*16.
__device__ __forceinline__ void gl16(const u16* g, u16* l){
  __builtin_amdgcn_global_load_lds(
      (const __attribute__((address_space(1))) void*)g,
      (__attribute__((address_space(3))) void*)l, 16, 0, 0);
}

// ---------------- diagnostic fallback: zero d_out (f32) ----------------------
__global__ __launch_bounds__(256) void zero_out(float* out, int n){
  for (int i = blockIdx.x * 256 + threadIdx.x; i < n; i += 256 * 4096) out[i] = 0.f;
}

// ---------------- f32 -> bf16 bulk convert (8 elems/thread) ------------------
__global__ __launch_bounds__(256) void cvt_bf16(
    const float* __restrict__ in, u16* __restrict__ out)
{
  const size_t i = ((size_t)blockIdx.x * 256 + threadIdx.x) * 8;
  f32x4 a = *(const f32x4*)&in[i];
  f32x4 b = *(const f32x4*)&in[i + 4];
  u16x8 o;
  #pragma unroll
  for (int j = 0; j < 4; ++j){ o[j] = f2bf(a[j]); o[4+j] = f2bf(b[j]); }
  *(u16x8*)&out[i] = o;
}

// -------- weight transpose+convert: src f32 [K][N] -> dst bf16 [(off+n)*K+k] --
__global__ __launch_bounds__(256) void transpose_w(
    const float* __restrict__ src, u16* __restrict__ dst, int K, int N, int dstOff)
{
  __shared__ u16 tile[32][33];
  const int bk = blockIdx.x * 32, bn = blockIdx.y * 32;
  const int t = threadIdx.x;
  const int r = t >> 5, c = t & 31;
  #pragma unroll
  for (int p = 0; p < 4; ++p)
    tile[r + p*8][c] = f2bf(src[(size_t)(bk + r + p*8) * N + bn + c]);
  __syncthreads();
  #pragma unroll
  for (int p = 0; p < 4; ++p)
    dst[(size_t)(dstOff + bn + r + p*8) * K + bk + c] = tile[c][r + p*8];
}

// -------- generic 2-source transpose via blockIdx.z --------------------------
__global__ __launch_bounds__(256) void transpose_w2(
    const float* s0, const float* s1, u16* __restrict__ d0, u16* __restrict__ d1,
    int K, int N)
{
  __shared__ u16 tile[32][33];
  const float* src = blockIdx.z == 0 ? s0 : s1;
  u16* dst = blockIdx.z == 0 ? d0 : d1;
  const int bk = blockIdx.x * 32, bn = blockIdx.y * 32;
  const int t = threadIdx.x;
  const int r = t >> 5, c = t & 31;
  #pragma unroll
  for (int p = 0; p < 4; ++p)
    tile[r + p*8][c] = f2bf(src[(size_t)(bk + r + p*8) * N + bn + c]);
  __syncthreads();
  #pragma unroll
  for (int p = 0; p < 4; ++p)
    dst[(size_t)(bn + r + p*8) * K + bk + c] = tile[c][r + p*8];
}

// -------- 6-source QKV transpose: both layers' wq/wk/wv (K=1024, N=512) ------
__global__ __launch_bounds__(256) void transpose_qkv6(
    const float* s0, const float* s1, const float* s2,
    const float* s3, const float* s4, const float* s5,
    u16* __restrict__ dst0, u16* __restrict__ dst1)
{
  __shared__ u16 tile[32][33];
  const int z = blockIdx.z;
  const float* src = z == 0 ? s0 : z == 1 ? s1 : z == 2 ? s2
                   : z == 3 ? s3 : z == 4 ? s4 : s5;
  u16* dst = (z < 3 ? dst0 : dst1);
  const int dstOff = (z % 3) * 512;
  const int K = 1024, N = 512;
  const int bk = blockIdx.x * 32, bn = blockIdx.y * 32;
  const int t = threadIdx.x;
  const int r = t >> 5, c = t & 31;
  #pragma unroll
  for (int p = 0; p < 4; ++p)
    tile[r + p*8][c] = f2bf(src[(size_t)(bk + r + p*8) * N + bn + c]);
  __syncthreads();
  #pragma unroll
  for (int p = 0; p < 4; ++p)
    dst[(size_t)(dstOff + bn + r + p*8) * K + bk + c] = tile[c][r + p*8];
}

// ---- GEMM 256x256, BK=64, 8 waves, dbuf LDS, quadrant-phase schedule -------
// r10 schedule (frozen) + B-fragment residency (24 vs 28 ds_reads/wave/tile).
// C = A[M,K] @ BT[N,:]^T. A split at ksplit (A0/A1, K-direction).
// NSPLIT: blocks with n0 >= ncut read A1 (N-direction A select) and write
// out2v/bias2 (per-block-uniform). OUT2: N-split output only (A shared).
template<int RELU, int OF32, int ACC, int OUT2, int NSPLIT>
__global__ __launch_bounds__(512, 1) void gemm256(
    const u16* __restrict__ A0, const u16* __restrict__ A1,
    int Astride, int ksplit,
    const u16* __restrict__ BT, int Bld, int M, int N, int K,
    const float* __restrict__ bias, void* __restrict__ outv, int out_ld,
    u16* __restrict__ out2v, const float* __restrict__ bias2, int ncut)
{
  __shared__ u16 lds[2*32768];           // 128 KiB
  const int tid  = threadIdx.x;
  const int lane = tid & 63;
  const int wid  = tid >> 6;             // 0..7
  const int wm = wid >> 2, wn = wid & 3; // 2M x 4N waves
  const int l15 = lane & 15, l4 = lane >> 4;
  const int m0 = blockIdx.x * 256, n0 = blockIdx.y * 256;

  const bool hi = (OUT2 || NSPLIT) && (n0 >= ncut);
  const u16* Aeff = (NSPLIT && hi) ? A1 : A0;

  f32x4 acc[8][4];
  #pragma unroll
  for (int i = 0; i < 8; ++i)
    #pragma unroll
    for (int j = 0; j < 4; ++j)
      acc[i][j] = (f32x4){0.f, 0.f, 0.f, 0.f};

  const int s0 = tid, s1 = tid + 512;
  const int r0 = s0 >> 3, g0 = (s0 & 7) ^ (r0 & 7);
  const int r1 = s1 >> 3, g1 = (s1 & 7) ^ (r1 & 7);

  const int nt = K >> 6;

  auto stageA = [&](int kt, int h, int buf){
    const int kb = kt * 64;
    const u16* Ab = Aeff; int kl = kb;
    if (!NSPLIT && kb >= ksplit){ Ab = A1; kl = kb - ksplit; }
    u16* dst = &lds[buf*32768 + h*8192];
    gl16(&Ab[(size_t)(m0 + h*128 + r0) * Astride + kl + g0*8], &dst[s0*8]);
    gl16(&Ab[(size_t)(m0 + h*128 + r1) * Astride + kl + g1*8], &dst[s1*8]);
  };
  auto stageB = [&](int kt, int h, int buf){
    const int kb = kt * 64;
    u16* dst = &lds[buf*32768 + 16384 + h*8192];
    gl16(&BT[(size_t)(n0 + h*128 + r0) * Bld + kb + g0*8], &dst[s0*8]);
    gl16(&BT[(size_t)(n0 + h*128 + r1) * Bld + kb + g1*8], &dst[s1*8]);
  };
  auto lda = [&](int i, int kc, int buf) -> bf16x8 {
    const int r = wm*128 + i*16 + l15;
    const int c = (kc*4 + l4) ^ (r & 7);
    return *(const bf16x8*)&lds[buf*32768 + r*64 + c*8];
  };
  auto ldb = [&](int j, int kc, int buf) -> bf16x8 {
    const int r = wn*64 + j*16 + l15;
    const int c = (kc*4 + l4) ^ (r & 7);
    return *(const bf16x8*)&lds[buf*32768 + 16384 + r*64 + c*8];
  };

  // prologue: stage tile 0 fully (8 loads)
  stageA(0, 0, 0); stageA(0, 1, 0); stageB(0, 0, 0); stageB(0, 1, 0);

  for (int t = 0; t < nt; ++t){
    const int buf = t & 1, nbuf = buf ^ 1;
    const bool pf = (t + 1 < nt);
    if (pf){
      stageA(t+1, 0, nbuf);
      asm volatile("s_waitcnt vmcnt(2)" ::: "memory");  // tile t's 8 landed
    } else {
      asm volatile("s_waitcnt vmcnt(0)" ::: "memory");
    }
    __builtin_amdgcn_sched_barrier(0);
    __builtin_amdgcn_s_barrier();          // all waves' tile-t loads landed
    __builtin_amdgcn_sched_barrier(0);

    bf16x8 a_[4][2], b_[4][2];
    // ---- Q0: read ALL B (stays resident) + A-lo; MFMA A-lo x B-lo ----
    #pragma unroll
    for (int j = 0; j < 4; ++j){ b_[j][0] = ldb(j, 0, buf); b_[j][1] = ldb(j, 1, buf); }
    #pragma unroll
    for (int i = 0; i < 4; ++i){ a_[i][0] = lda(i, 0, buf); a_[i][1] = lda(i, 1, buf); }
    if (pf) stageA(t+1, 1, nbuf);
    __builtin_amdgcn_s_setprio(1);
    #pragma unroll
    for (int i = 0; i < 4; ++i)
      #pragma unroll
      for (int j = 0; j < 2; ++j){
        acc[i][j] = __builtin_amdgcn_mfma_f32_16x16x32_bf16(a_[i][0], b_[j][0], acc[i][j], 0,0,0);
        acc[i][j] = __builtin_amdgcn_mfma_f32_16x16x32_bf16(a_[i][1], b_[j][1], acc[i][j], 0,0,0);
      }
    __builtin_amdgcn_s_setprio(0);
    // ---- Q1: A-lo x B-hi (no reads) ----
    if (pf) stageB(t+1, 0, nbuf);
    __builtin_amdgcn_s_setprio(1);
    #pragma unroll
    for (int i = 0; i < 4; ++i)
      #pragma unroll
      for (int j = 0; j < 2; ++j){
        acc[i][2+j] = __builtin_amdgcn_mfma_f32_16x16x32_bf16(a_[i][0], b_[2+j][0], acc[i][2+j], 0,0,0);
        acc[i][2+j] = __builtin_amdgcn_mfma_f32_16x16x32_bf16(a_[i][1], b_[2+j][1], acc[i][2+j], 0,0,0);
      }
    __builtin_amdgcn_s_setprio(0);
    // ---- Q2: read A-hi; MFMA A-hi x B-hi ----
    #pragma unroll
    for (int i = 0; i < 4; ++i){ a_[i][0] = lda(4+i, 0, buf); a_[i][1] = lda(4+i, 1, buf); }
    if (pf) stageB(t+1, 1, nbuf);
    __builtin_amdgcn_s_setprio(1);
    #pragma unroll
    for (int i = 0; i < 4; ++i)
      #pragma unroll
      for (int j = 0; j < 2; ++j){
        acc[4+i][2+j] = __builtin_amdgcn_mfma_f32_16x16x32_bf16(a_[i][0], b_[2+j][0], acc[4+i][2+j], 0,0,0);
        acc[4+i][2+j] = __builtin_amdgcn_mfma_f32_16x16x32_bf16(a_[i][1], b_[2+j][1], acc[4+i][2+j], 0,0,0);
      }
    __builtin_amdgcn_s_setprio(0);
    // ---- Q3: A-hi x B-lo (no reads) ----
    __builtin_amdgcn_s_setprio(1);
    #pragma unroll
    for (int i = 0; i < 4; ++i)
      #pragma unroll
      for (int j = 0; j < 2; ++j){
        acc[4+i][j] = __builtin_amdgcn_mfma_f32_16x16x32_bf16(a_[i][0], b_[j][0], acc[4+i][j], 0,0,0);
        acc[4+i][j] = __builtin_amdgcn_mfma_f32_16x16x32_bf16(a_[i][1], b_[j][1], acc[4+i][j], 0,0,0);
      }
    __builtin_amdgcn_s_setprio(0);

    __builtin_amdgcn_sched_barrier(0);
    __builtin_amdgcn_s_barrier();          // all reads of buf done
    __builtin_amdgcn_sched_barrier(0);
  }

  // epilogue: C[row][col], row=(lane>>4)*4+r, col=lane&15 (m89-verified)
  u16* outp = (u16*)outv;
  const float* bp = bias;
  int cadj = 0;
  if (hi){ outp = out2v; bp = NSPLIT ? bias2 : bias; cadj = ncut; }
  const int rb = m0 + wm*128 + l4*4;
  const int cb = n0 + wn*64 + l15;
  #pragma unroll
  for (int i = 0; i < 8; ++i){
    #pragma unroll
    for (int j = 0; j < 4; ++j){
      const int col = cb + j*16;
      const float badd = bp ? bp[col - cadj] : 0.f;
      #pragma unroll
      for (int r = 0; r < 4; ++r){
        const int row = rb + i*16 + r;
        float y = acc[i][j][r] + badd;
        if (RELU) y = y > 0.f ? y : 0.f;
        if (OF32){
          float* po = &((float*)outv)[(size_t)row * out_ld + col];
          if (ACC) y += *po;
          *po = y;
        } else {
          u16* po = &outp[(size_t)row * out_ld + col - cadj];
          if (ACC) y += bf2f(*po);
          *po = f2bf(y);
        }
      }
    }
  }
}

// -------- mask pack: bit k of mb[row][c] = mask(row, c*64+k) -----------------
__global__ __launch_bounds__(256) void mask_pack(
    const int* __restrict__ slf, const int* __restrict__ adj,
    u64* __restrict__ mb_g, u64* __restrict__ mb_l)
{
  const int idx  = blockIdx.x * 4 + (threadIdx.x >> 6);  // (row, c) pair
  const int lane = threadIdx.x & 63;
  const size_t mi = (size_t)(idx >> 2) * 256 + (size_t)(idx & 3) * 64 + lane;
  const bool g = slf[mi] != 0;
  const bool l = g || (adj[mi] == 0);
  const u64 bg = __ballot(g);
  const u64 bl = __ballot(l);
  if (lane == 0){ mb_g[idx] = bg; mb_l[idx] = bl; }
}

// ---------------- MFMA flash attention (T13 defer-max, both layers) ----------
__global__ __launch_bounds__(256) void attn_mfma(
    const u16* __restrict__ qkv0, const u16* __restrict__ qkv1,
    const u64* __restrict__ mb0, const u64* __restrict__ mb1,
    u16* __restrict__ out0, u16* __restrict__ out1)
{
  __shared__ u16 kbuf[64*64];
  __shared__ u16 vtbuf[64*64];
  __shared__ u16 pbuf[4][32*64];

  const int L  = blockIdx.y;
  const u16* qkv = L ? qkv1 : qkv0;
  const u64* mb  = L ? mb1  : mb0;
  u16*       out = L ? out1 : out0;

  const int b  = blockIdx.x >> 4;
  const int h  = (blockIdx.x >> 1) & 7;
  const int qt = blockIdx.x & 1;
  const int t  = threadIdx.x;
  const int w  = t >> 6, lane = t & 63;
  const int l15 = lane & 15, l4 = lane >> 4;

  bf16x8 qf[2][2];
  {
    const int rbase = b*256 + qt*128 + w*32;
    #pragma unroll
    for (int i = 0; i < 2; ++i)
      #pragma unroll
      for (int kc = 0; kc < 2; ++kc)
        qf[i][kc] = *(const bf16x8*)&qkv[(size_t)(rbase + i*16 + l15)*1536 + h*64 + kc*32 + l4*8];
  }

  f32x4 acc_o[2][4];
  float m_[2][4], l_[2][4];
  #pragma unroll
  for (int i = 0; i < 2; ++i){
    #pragma unroll
    for (int j = 0; j < 4; ++j) acc_o[i][j] = (f32x4){0.f,0.f,0.f,0.f};
    #pragma unroll
    for (int r = 0; r < 4; ++r){ m_[i][r] = -1e30f; l_[i][r] = 0.f; }
  }

  for (int c = 0; c < 4; ++c){
    __syncthreads();
    {
      const int kr = t >> 2, dg = (t & 3) * 16;
      const size_t rbase = (size_t)(b*256 + c*64 + kr)*1536 + h*64 + dg;
      u16x8 k0 = *(const u16x8*)&qkv[rbase + 512];
      u16x8 k1 = *(const u16x8*)&qkv[rbase + 512 + 8];
      u16x8 v0 = *(const u16x8*)&qkv[rbase + 1024];
      u16x8 v1 = *(const u16x8*)&qkv[rbase + 1024 + 8];
      const int sw = (kr & 7) << 3;
      *(u16x8*)&kbuf[kr*64 + (dg ^ sw)]       = k0;
      *(u16x8*)&kbuf[kr*64 + ((dg + 8) ^ sw)] = k1;
      #pragma unroll
      for (int e = 0; e < 8; ++e){
        const int d0 = dg + e, d1 = dg + 8 + e;
        vtbuf[d0*64 + (kr ^ ((d0 & 7) << 3))] = v0[e];
        vtbuf[d1*64 + (kr ^ ((d1 & 7) << 3))] = v1[e];
      }
    }
    __syncthreads();

    bf16x8 kfr[4][2];
    #pragma unroll
    for (int jb = 0; jb < 4; ++jb){
      const int key = jb*16 + l15;
      const int sw = (key & 7) << 3;
      #pragma unroll
      for (int kc = 0; kc < 2; ++kc)
        kfr[jb][kc] = *(const bf16x8*)&kbuf[key*64 + ((kc*32 + l4*8) ^ sw)];
    }
    f32x4 s_[2][4];
    #pragma unroll
    for (int i = 0; i < 2; ++i)
      #pragma unroll
      for (int jb = 0; jb < 4; ++jb){
        f32x4 a = (f32x4){0.f,0.f,0.f,0.f};
        a = __builtin_amdgcn_mfma_f32_16x16x32_bf16(qf[i][0], kfr[jb][0], a, 0,0,0);
        a = __builtin_amdgcn_mfma_f32_16x16x32_bf16(qf[i][1], kfr[jb][1], a, 0,0,0);
        s_[i][jb] = a;
      }

    #pragma unroll
    for (int i = 0; i < 2; ++i)
      #pragma unroll
      for (int r = 0; r < 4; ++r){
        const int qrow = qt*128 + w*32 + i*16 + l4*4 + r;
        const u64 bits = mb[((size_t)b*256 + qrow)*4 + c];
        #pragma unroll
        for (int jb = 0; jb < 4; ++jb){
          float xv = s_[i][jb][r] * 0.125f;
          if ((bits >> (jb*16 + l15)) & 1ull) xv = -1e9f;
          s_[i][jb][r] = xv;
        }
      }
    float mxs[2][4];
    bool okall = true;
    #pragma unroll
    for (int i = 0; i < 2; ++i)
      #pragma unroll
      for (int r = 0; r < 4; ++r){
        float mx = fmaxf(fmaxf(s_[i][0][r], s_[i][1][r]),
                         fmaxf(s_[i][2][r], s_[i][3][r]));
        #pragma unroll
        for (int d = 1; d < 16; d <<= 1)
          mx = fmaxf(mx, __shfl_xor(mx, d, 64));
        mxs[i][r] = mx;
        okall = okall && (mx <= m_[i][r] + 8.f);
      }
    if (__all(okall)){
      #pragma unroll
      for (int i = 0; i < 2; ++i)
        #pragma unroll
        for (int r = 0; r < 4; ++r){
          const int prow = i*16 + l4*4 + r;
          const int swp = (prow & 7) << 3;
          float ps = 0.f;
          #pragma unroll
          for (int jb = 0; jb < 4; ++jb){
            const float p = __expf(s_[i][jb][r] - m_[i][r]);
            ps += p;
            pbuf[w][prow*64 + ((jb*16 + l15) ^ swp)] = f2bf(p);
          }
          #pragma unroll
          for (int d = 1; d < 16; d <<= 1)
            ps += __shfl_xor(ps, d, 64);
          l_[i][r] += ps;
        }
    } else {
      #pragma unroll
      for (int i = 0; i < 2; ++i)
        #pragma unroll
        for (int r = 0; r < 4; ++r){
          const int prow = i*16 + l4*4 + r;
          const float mnew = fmaxf(m_[i][r], mxs[i][r]);
          const float corr = __expf(m_[i][r] - mnew);
          m_[i][r] = mnew;
          float ps = 0.f;
          const int swp = (prow & 7) << 3;
          #pragma unroll
          for (int jb = 0; jb < 4; ++jb){
            const float p = __expf(s_[i][jb][r] - mnew);
            ps += p;
            pbuf[w][prow*64 + ((jb*16 + l15) ^ swp)] = f2bf(p);
          }
          #pragma unroll
          for (int d = 1; d < 16; d <<= 1)
            ps += __shfl_xor(ps, d, 64);
          l_[i][r] = l_[i][r] * corr + ps;
          #pragma unroll
          for (int j2 = 0; j2 < 4; ++j2) acc_o[i][j2][r] *= corr;
        }
    }

    bf16x8 vfr[4][2];
    #pragma unroll
    for (int j2 = 0; j2 < 4; ++j2){
      const int dim = j2*16 + l15;
      const int sw = (dim & 7) << 3;
      #pragma unroll
      for (int kc = 0; kc < 2; ++kc)
        vfr[j2][kc] = *(const bf16x8*)&vtbuf[dim*64 + ((kc*32 + l4*8) ^ sw)];
    }
    #pragma unroll
    for (int i = 0; i < 2; ++i){
      const int prow = i*16 + l15;
      const int swp = (prow & 7) << 3;
      bf16x8 pa0 = *(const bf16x8*)&pbuf[w][prow*64 + ((l4*8) ^ swp)];
      bf16x8 pa1 = *(const bf16x8*)&pbuf[w][prow*64 + ((32 + l4*8) ^ swp)];
      #pragma unroll
      for (int j2 = 0; j2 < 4; ++j2){
        acc_o[i][j2] = __builtin_amdgcn_mfma_f32_16x16x32_bf16(pa0, vfr[j2][0], acc_o[i][j2], 0,0,0);
        acc_o[i][j2] = __builtin_amdgcn_mfma_f32_16x16x32_bf16(pa1, vfr[j2][1], acc_o[i][j2], 0,0,0);
      }
    }
  }

  #pragma unroll
  for (int i = 0; i < 2; ++i){
    #pragma unroll
    for (int r = 0; r < 4; ++r){
      const int qrow = qt*128 + w*32 + i*16 + l4*4 + r;
      const float inv = 1.f / l_[i][r];
      const size_t ob = ((size_t)b*256 + qrow)*512 + h*64;
      #pragma unroll
      for (int j2 = 0; j2 < 4; ++j2)
        out[ob + j2*16 + l15] = f2bf(acc_o[i][j2][r] * inv);
    }
  }
}

// -------- fused residual + LayerNorm + npm (v2: wave-per-row, no LDS) --------
template<int RF32>
__global__ __launch_bounds__(256) void ln_fused(
    const u16* a, const void* __restrict__ res,
    const float* __restrict__ sc, const float* __restrict__ bs,
    const float* __restrict__ npm, u16* out)
{
  const int w = threadIdx.x >> 6, lane = threadIdx.x & 63;
  const int row = blockIdx.x * 4 + w;
  const size_t bse = (size_t)row * 1024 + lane * 16;

  u16x8 av0 = *(const u16x8*)&a[bse];
  u16x8 av1 = *(const u16x8*)&a[bse + 8];
  float rv[16];
  if (RF32){
    const float* rp = (const float*)res + bse;
    #pragma unroll
    for (int j = 0; j < 16; j += 4){
      f32x4 q = *(const f32x4*)&rp[j];
      rv[j] = q[0]; rv[j+1] = q[1]; rv[j+2] = q[2]; rv[j+3] = q[3];
    }
  } else {
    const u16* rp = (const u16*)res + bse;
    u16x8 q0 = *(const u16x8*)rp;
    u16x8 q1 = *(const u16x8*)(rp + 8);
    #pragma unroll
    for (int j = 0; j < 8; ++j){ rv[j] = bf2f(q0[j]); rv[8+j] = bf2f(q1[j]); }
  }

  float vv[16]; float s = 0.f, sq = 0.f;
  #pragma unroll
  for (int j = 0; j < 8; ++j){
    vv[j]   = bf2f(av0[j]) + rv[j];
    vv[8+j] = bf2f(av1[j]) + rv[8+j];
  }
  #pragma unroll
  for (int j = 0; j < 16; ++j){ s += vv[j]; sq += vv[j]*vv[j]; }
  #pragma unroll
  for (int i = 1; i < 64; i <<= 1){
    s  += __shfl_xor(s,  i, 64);
    sq += __shfl_xor(sq, i, 64);
  }
  const float mean = s * (1.f/1024.f);
  const float var  = sq * (1.f/1024.f) - mean*mean;
  const float rstd = rsqrtf(var + 1e-5f);
  const float nm   = npm[row];

  u16x8 o0, o1;
  #pragma unroll
  for (int j = 0; j < 8; ++j){
    const int c0 = lane*16 + j, c1 = c0 + 8;
    o0[j] = f2bf(((vv[j]   - mean) * rstd * sc[c0] + bs[c0]) * nm);
    o1[j] = f2bf(((vv[8+j] - mean) * rstd * sc[c1] + bs[c1]) * nm);
  }
  *(u16x8*)&out[bse]     = o0;
  *(u16x8*)&out[bse + 8] = o1;
}

// ---------------- launcher ---------------------------------------------------
extern "C" void kernel_launch(void* const* d_in, const int* in_sizes, int n_in,
                              void* d_out, int out_size, void* d_ws, size_t ws_size,
                              hipStream_t stream)
{
  // ws (u16 el), 112 MiB (proven):
  //  W [0, 8388608) timeline:
  //   prep/ph1: wqkvT0 @0 | wqkvT1 @1572864 | woT0 @3145728 | woT1 @3670016 |
  //             masks @6291456
  //   ph2b:     w1T0 @0 | w1T1 @2097152 | w2T0 @4194304 | w2T1 @6291456
  //             (overwrite dead wqkvT/woT/masks)
  //   final:    fcT @0 (over dead w1T0)
  //  R1 [8388608, 25165824):  xbf (ph1) -> tmp0 -> xg (in-place LN)
  //  [25165824, 50331648): qkv1 (ph1) -> ln1 @25165824 (ph2b) |
  //                        tmp1/xl @41943040 (after out-proj; over dead qkv1)
  //  [50331648, 58720256): attnb0 (ph1; disjoint from qkv1)
  // d_out (u16): ph1: qkv0 [0,25165824) | attnb1 [25165824,33554432)
  //              ph2b: hbuf = FULL d_out [16384][2048]
  const size_t NEED = 58720256ull * 2ull;
  if (ws_size < NEED){
    zero_out<<<4096, 256, 0, stream>>>((float*)d_out, out_size);
    return;
  }

  const float* x   = (const float*)d_in[0];
  const int*   adj = (const int*)d_in[1];
  const float* npm = (const float*)d_in[2];
  const int*   slf = (const int*)d_in[3];
  const float* fcw = (const float*)d_in[30];
  const float* fcb = (const float*)d_in[31];

  u16* ws     = (u16*)d_ws;
  u16* wqkvT0 = ws;                    // [3072][1024] cat starts here
  u16* wqkvT1 = ws + 1572864;
  u16* woT0   = ws + 3145728;          // [2048][512] cat (woT0|woT1 contiguous)
  u16* woT1   = ws + 3670016;
  u64* mb_g   = (u64*)(ws + 6291456);  // ph1 only
  u64* mb_l   = mb_g + 65536;
  u16* w1T0   = ws;                    // ph2b
  u16* w1T1   = ws + 2097152;
  u16* w2T0   = ws + 4194304;
  u16* w2T1   = ws + 6291456;
  u16* fcT    = ws;                    // final only (over dead w1T0)
  u16* xbf    = ws + 8388608;          // R1: then tmp0/xg
  u16* tmp0   = ws + 8388608;
  u16* qkv1   = ws + 25165824;         // ph1: [16384][1536]
  u16* ln1    = ws + 25165824;         // ph2b
  u16* tmp1   = ws + 41943040;
  u16* attnb0 = ws + 50331648;         // [16384][512], disjoint from qkv1

  u16* dout16 = (u16*)d_out;
  u16* qkv0   = dout16;                // [16384][1536] (ph1)
  u16* attnb1 = dout16 + 25165824;     // [16384][512] (ph1 tail)
  u16* hbuf   = dout16;                // [16384][2048] (ph2b)

  cvt_bf16<<<8192, 256, 0, stream>>>(x, xbf);
  mask_pack<<<16384, 256, 0, stream>>>(slf, adj, mb_g, mb_l);
  transpose_qkv6<<<dim3(32, 16, 6), 256, 0, stream>>>(
      (const float*)d_in[4+0], (const float*)d_in[4+1], (const float*)d_in[4+2],
      (const float*)d_in[17+0], (const float*)d_in[17+1], (const float*)d_in[17+2],
      wqkvT0, wqkvT1);
  transpose_w2<<<dim3(16, 32, 2), 256, 0, stream>>>(
      (const float*)d_in[4+3], (const float*)d_in[17+3], woT0, woT1, 512, 1024);

  // Phase 1: merged QKV for BOTH layers (768 blocks = 3 exact rounds)
  gemm256<0,0,0,1,0><<<dim3(64, 12), 512, 0, stream>>>(
      xbf, xbf, 1024, 1024, wqkvT0, 1024, 16384, 3072, 1024,
      nullptr, qkv0, 1536, qkv1, nullptr, 1536);
  // merged attention: both layers in one dispatch
  attn_mfma<<<dim3(1024, 2), 256, 0, stream>>>(
      qkv0, qkv1, mb_g, mb_l, attnb0, attnb1);

  // Phase 2a: merged out-projections (512 blocks = 2 exact rounds):
  // cols [0,1024): A=attnb0, bias=bo_g -> tmp0; [1024,2048): A=attnb1 -> tmp1
  gemm256<0,0,0,0,1><<<dim3(64, 8), 512, 0, stream>>>(
      attnb0, attnb1, 512, 512, woT0, 512, 16384, 2048, 512,
      (const float*)d_in[4+4], tmp0, 1024, tmp1, (const float*)d_in[17+4], 1024);

  // ph2b weight prep: both layers' w1/w2 (2 launches)
  transpose_w2<<<dim3(32, 64, 2), 256, 0, stream>>>(
      (const float*)d_in[4+7], (const float*)d_in[17+7], w1T0, w1T1, 1024, 2048);
  transpose_w2<<<dim3(64, 32, 2), 256, 0, stream>>>(
      (const float*)d_in[4+9], (const float*)d_in[17+9], w2T0, w2T1, 2048, 1024);

  // Phase 2b: layer bodies (hbuf = full d_out; FFN unsplit)
  for (int L = 0; L < 2; ++L){
    const int bi = 4 + L*13;
    const float* l1s = (const float*)d_in[bi+5];
    const float* l1b = (const float*)d_in[bi+6];
    const float* b1  = (const float*)d_in[bi+8];
    const float* b2  = (const float*)d_in[bi+10];
    const float* l2s = (const float*)d_in[bi+11];
    const float* l2b = (const float*)d_in[bi+12];
    u16* tmpL = L ? tmp1 : tmp0;
    u16* w1TL = L ? w1T1 : w1T0;
    u16* w2TL = L ? w2T1 : w2T0;

    // ln1 = LN(tmpL + x) * npm -> R2
    ln_fused<1><<<4096, 256, 0, stream>>>(tmpL, x, l1s, l1b, npm, ln1);
    // hbuf = relu(ln1 @ w1T + b1)   [16384][2048]
    gemm256<1,0,0,0,0><<<dim3(64, 8), 512, 0, stream>>>(
        ln1, ln1, 1024, 1024, w1TL, 1024, 16384, 2048, 1024, b1, hbuf, 2048,
        nullptr, nullptr, 0);
    // tmpL = hbuf @ w2T + b2
    gemm256<0,0,0,0,0><<<dim3(64, 4), 512, 0, stream>>>(
        hbuf, hbuf, 2048, 2048, w2TL, 2048, 16384, 1024, 2048, b2, tmpL, 1024,
        nullptr, nullptr, 0);
    // xout = LN(tmpL + ln1) * npm, in-place -> tmpL (xg = R1 / xl = R3)
    ln_fused<0><<<4096, 256, 0, stream>>>(tmpL, ln1, l2s, l2b, npm, tmpL);
  }

  // final: fcT transpose (over dead w1T0), then [xg|xl] @ fcT + fc_b -> d_out
  transpose_w<<<dim3(64, 32), 256, 0, stream>>>(fcw, fcT, 2048, 1024, 0);
  gemm256<0,1,0,0,0><<<dim3(64, 4), 512, 0, stream>>>(
      tmp0, tmp1, 1024, 1024, fcT, 2048, 16384, 1024, 2048, fcb, d_out, 1024,
      nullptr, nullptr, 0);
}